// Round 1
// 1660.504 us; speedup vs baseline: 1.2266x; 1.2266x over previous
//
#include <hip/hip_runtime.h>

#define B_SZ 32
#define N_TOK 3136
#define C_DIM 512
#define H_IMG 56
#define NUM_HEADS 8
#define HEAD_DIM 64
#define AGENT_NUM 49
#define SCALE 0.125f
#define M_ROWS (B_SZ * N_TOK)        // 100352
#define N_SPLIT 7                    // agent-attn n-splits (448 tokens each)

typedef __bf16 bf16x8 __attribute__((ext_vector_type(8)));
typedef float f32x4 __attribute__((ext_vector_type(4)));

static __device__ __forceinline__ unsigned short f2bf(float f) {
    unsigned int u = __float_as_uint(f);
    unsigned int r = (u + 0x7fffu + ((u >> 16) & 1u)) >> 16;   // RNE
    return (unsigned short)r;
}
static __device__ __forceinline__ float bf2f(unsigned short u) {
    return __uint_as_float(((unsigned int)u) << 16);
}
// async global->LDS, 16B per lane; lds dest must be wave-uniform (HW: base + lane*16)
static __device__ __forceinline__ void load_lds16(const unsigned short* g, unsigned short* l) {
    __builtin_amdgcn_global_load_lds(
        (const __attribute__((address_space(1))) unsigned int*)g,
        (__attribute__((address_space(3))) unsigned int*)l, 16, 0, 0);
}

// generic fp32 -> bf16 cast, count must be multiple of 1024
__global__ __launch_bounds__(256) void cast_f32_bf16(
    const float* __restrict__ in, unsigned short* __restrict__ out)
{
    long i = (long)blockIdx.x * 256 + threadIdx.x;   // float4 index
    float4 f = ((const float4*)in)[i];
    ushort4 u;
    u.x = f2bf(f.x); u.y = f2bf(f.y); u.z = f2bf(f.z); u.w = f2bf(f.w);
    ((ushort4*)out)[i] = u;
}

// ---------------------------------------------------------------------------
// QKV MFMA GEMM (bf16 A path): [M,1536] = xb[M,512](bf16) @ qkv_wb[1536,512]^T
// 128x128 tile, BK=32, 4 waves. Grid (12, M/128): n-block fastest so the 12
// blocks sharing one A-tile are adjacent -> A fetched ~once from HBM.
// q (cols 0:512) -> fp32 d_out;  k,v -> bf16 ws.
// ---------------------------------------------------------------------------
__global__ __launch_bounds__(256) void mfma_qkv_bf(
    const unsigned short* __restrict__ Ab, const unsigned short* __restrict__ Wb,
    float* __restrict__ qO, unsigned short* __restrict__ kO,
    unsigned short* __restrict__ vO)
{
    __shared__ __align__(16) unsigned short Asm[128 * 32];
    __shared__ __align__(16) unsigned short Bsm[128 * 32];

    const int n0 = blockIdx.x * 128, m0 = blockIdx.y * 128;
    const int tid = threadIdx.x;
    const int lane = tid & 63, wave = tid >> 6;
    const int wm = wave >> 1, wn = wave & 1;

    f32x4 acc[4][4];
#pragma unroll
    for (int i = 0; i < 4; i++)
#pragma unroll
        for (int j = 0; j < 4; j++) {
            f32x4 z = {0.f, 0.f, 0.f, 0.f};
            acc[i][j] = z;
        }

    const unsigned short* aP0 = Ab + (long)(m0 + (tid >> 2)) * 512 + (tid & 3) * 8;
    const unsigned short* aP1 = aP0 + (long)64 * 512;
    const unsigned short* bP0 = Wb + (long)(n0 + (tid >> 2)) * 512 + (tid & 3) * 8;
    const unsigned short* bP1 = bP0 + (long)64 * 512;
    unsigned short* aD0 = Asm + (tid >> 6) * 512;   // wave-uniform
    unsigned short* aD1 = aD0 + 4 * 512;
    unsigned short* bD0 = Bsm + (tid >> 6) * 512;
    unsigned short* bD1 = bD0 + 4 * 512;

    const int fr = lane & 15, fq = lane >> 4;
    const unsigned short* aF = Asm + (wm * 64 + fr) * 32 + fq * 8;
    const unsigned short* bF = Bsm + (wn * 64 + fr) * 32 + fq * 8;

    for (int k0 = 0; k0 < 512; k0 += 32) {
        load_lds16(aP0 + k0, aD0);
        load_lds16(aP1 + k0, aD1);
        load_lds16(bP0 + k0, bD0);
        load_lds16(bP1 + k0, bD1);
        __syncthreads();

        bf16x8 af[4], bfr[4];
#pragma unroll
        for (int i = 0; i < 4; i++) af[i]  = *(const bf16x8*)(aF + i * 16 * 32);
#pragma unroll
        for (int j = 0; j < 4; j++) bfr[j] = *(const bf16x8*)(bF + j * 16 * 32);
#pragma unroll
        for (int i = 0; i < 4; i++)
#pragma unroll
            for (int j = 0; j < 4; j++)
                acc[i][j] = __builtin_amdgcn_mfma_f32_16x16x32_bf16(
                    af[i], bfr[j], acc[i][j], 0, 0, 0);
        __syncthreads();
    }

    // epilogue: C/D layout col=lane&15, row=(lane>>4)*4+reg
    const int seg = n0 >> 9;   // 0=q,1=k,2=v (block never straddles: 128|512)
#pragma unroll
    for (int i = 0; i < 4; i++) {
        int rbase = m0 + wm * 64 + i * 16 + fq * 4;
#pragma unroll
        for (int j = 0; j < 4; j++) {
            int col  = n0 + wn * 64 + j * 16 + fr;
            int nloc = col - seg * 512;
#pragma unroll
            for (int r = 0; r < 4; r++) {
                long m = rbase + r;
                float val = acc[i][j][r];
                if (seg == 0)      qO[m * 512 + nloc] = val;
                else if (seg == 1) kO[m * 512 + nloc] = f2bf(val);
                else               vO[m * 512 + nloc] = f2bf(val);
            }
        }
    }
}

// ---------------------------------------------------------------------------
// Fallback QKV GEMM (fp32 A, cast in staging) — used if workspace too small
// for the bf16 x copy. Identical to previous session's kernel.
// ---------------------------------------------------------------------------
__global__ __launch_bounds__(256) void mfma_qkv(
    const float* __restrict__ A, const unsigned short* __restrict__ Wb,
    float* __restrict__ qO, unsigned short* __restrict__ kO,
    unsigned short* __restrict__ vO)
{
    __shared__ __align__(16) unsigned short Asm[128 * 32];
    __shared__ __align__(16) unsigned short Bsm[128 * 32];

    const int m0 = blockIdx.x * 128, n0 = blockIdx.y * 128;
    const int tid = threadIdx.x;
    const int lane = tid & 63, wave = tid >> 6;
    const int wm = wave >> 1, wn = wave & 1;

    f32x4 acc[4][4];
#pragma unroll
    for (int i = 0; i < 4; i++)
#pragma unroll
        for (int j = 0; j < 4; j++) {
            f32x4 z = {0.f, 0.f, 0.f, 0.f};
            acc[i][j] = z;
        }

    const int arow = tid >> 1, acol = (tid & 1) * 16;
    const float* aP = A + (long)(m0 + arow) * 512 + acol;
    unsigned short* aD = Asm + arow * 32 + acol;

    const unsigned short* bP0 = Wb + (long)(n0 + (tid >> 2)) * 512 + (tid & 3) * 8;
    const unsigned short* bP1 = bP0 + (long)64 * 512;
    unsigned short* bD0 = Bsm + (tid >> 6) * 512;
    unsigned short* bD1 = bD0 + 4 * 512;

    const int fr = lane & 15, fq = lane >> 4;
    const unsigned short* aF = Asm + (wm * 64 + fr) * 32 + fq * 8;
    const unsigned short* bF = Bsm + (wn * 64 + fr) * 32 + fq * 8;

    for (int k0 = 0; k0 < 512; k0 += 32) {
        load_lds16(bP0 + k0, bD0);
        load_lds16(bP1 + k0, bD1);
        float4 f0 = *(const float4*)(aP + k0 + 0);
        float4 f1 = *(const float4*)(aP + k0 + 4);
        float4 f2 = *(const float4*)(aP + k0 + 8);
        float4 f3 = *(const float4*)(aP + k0 + 12);
        ushort4 u0, u1, u2, u3;
        u0.x = f2bf(f0.x); u0.y = f2bf(f0.y); u0.z = f2bf(f0.z); u0.w = f2bf(f0.w);
        u1.x = f2bf(f1.x); u1.y = f2bf(f1.y); u1.z = f2bf(f1.z); u1.w = f2bf(f1.w);
        u2.x = f2bf(f2.x); u2.y = f2bf(f2.y); u2.z = f2bf(f2.z); u2.w = f2bf(f2.w);
        u3.x = f2bf(f3.x); u3.y = f2bf(f3.y); u3.z = f2bf(f3.z); u3.w = f2bf(f3.w);
        *(ushort4*)(aD + 0)  = u0;
        *(ushort4*)(aD + 4)  = u1;
        *(ushort4*)(aD + 8)  = u2;
        *(ushort4*)(aD + 12) = u3;
        __syncthreads();

        bf16x8 af[4], bfr[4];
#pragma unroll
        for (int i = 0; i < 4; i++) af[i]  = *(const bf16x8*)(aF + i * 16 * 32);
#pragma unroll
        for (int j = 0; j < 4; j++) bfr[j] = *(const bf16x8*)(bF + j * 16 * 32);
#pragma unroll
        for (int i = 0; i < 4; i++)
#pragma unroll
            for (int j = 0; j < 4; j++)
                acc[i][j] = __builtin_amdgcn_mfma_f32_16x16x32_bf16(
                    af[i], bfr[j], acc[i][j], 0, 0, 0);
        __syncthreads();
    }

    const int seg = n0 >> 9;
#pragma unroll
    for (int i = 0; i < 4; i++) {
        int rbase = m0 + wm * 64 + i * 16 + fq * 4;
#pragma unroll
        for (int j = 0; j < 4; j++) {
            int col  = n0 + wn * 64 + j * 16 + fr;
            int nloc = col - seg * 512;
#pragma unroll
            for (int r = 0; r < 4; r++) {
                long m = rbase + r;
                float val = acc[i][j][r];
                if (seg == 0)      qO[m * 512 + nloc] = val;
                else if (seg == 1) kO[m * 512 + nloc] = f2bf(val);
                else               vO[m * 512 + nloc] = f2bf(val);
            }
        }
    }
}

// ---------------------------------------------------------------------------
// Proj MFMA GEMM: d_out[M,512] = Ab[M,512](bf16) @ proj_wb[512,512]^T + bias
// Grid (4, M/128): n-block fastest for A-tile L2 reuse.
// ---------------------------------------------------------------------------
__global__ __launch_bounds__(256) void mfma_proj(
    const unsigned short* __restrict__ Ab, const unsigned short* __restrict__ Wb,
    const float* __restrict__ bias, float* __restrict__ C)
{
    __shared__ __align__(16) unsigned short Asm[128 * 32];
    __shared__ __align__(16) unsigned short Bsm[128 * 32];

    const int n0 = blockIdx.x * 128, m0 = blockIdx.y * 128;
    const int tid = threadIdx.x;
    const int lane = tid & 63, wave = tid >> 6;
    const int wm = wave >> 1, wn = wave & 1;

    f32x4 acc[4][4];
#pragma unroll
    for (int i = 0; i < 4; i++)
#pragma unroll
        for (int j = 0; j < 4; j++) {
            f32x4 z = {0.f, 0.f, 0.f, 0.f};
            acc[i][j] = z;
        }

    const unsigned short* aP0 = Ab + (long)(m0 + (tid >> 2)) * 512 + (tid & 3) * 8;
    const unsigned short* aP1 = aP0 + (long)64 * 512;
    const unsigned short* bP0 = Wb + (long)(n0 + (tid >> 2)) * 512 + (tid & 3) * 8;
    const unsigned short* bP1 = bP0 + (long)64 * 512;
    unsigned short* aD0 = Asm + (tid >> 6) * 512;   // wave-uniform
    unsigned short* aD1 = aD0 + 4 * 512;
    unsigned short* bD0 = Bsm + (tid >> 6) * 512;
    unsigned short* bD1 = bD0 + 4 * 512;

    const int fr = lane & 15, fq = lane >> 4;
    const unsigned short* aF = Asm + (wm * 64 + fr) * 32 + fq * 8;
    const unsigned short* bF = Bsm + (wn * 64 + fr) * 32 + fq * 8;

    for (int k0 = 0; k0 < 512; k0 += 32) {
        load_lds16(aP0 + k0, aD0);
        load_lds16(aP1 + k0, aD1);
        load_lds16(bP0 + k0, bD0);
        load_lds16(bP1 + k0, bD1);
        __syncthreads();

        bf16x8 af[4], bfr[4];
#pragma unroll
        for (int i = 0; i < 4; i++) af[i]  = *(const bf16x8*)(aF + i * 16 * 32);
#pragma unroll
        for (int j = 0; j < 4; j++) bfr[j] = *(const bf16x8*)(bF + j * 16 * 32);
#pragma unroll
        for (int i = 0; i < 4; i++)
#pragma unroll
            for (int j = 0; j < 4; j++)
                acc[i][j] = __builtin_amdgcn_mfma_f32_16x16x32_bf16(
                    af[i], bfr[j], acc[i][j], 0, 0, 0);
        __syncthreads();
    }

#pragma unroll
    for (int i = 0; i < 4; i++) {
        int rbase = m0 + wm * 64 + i * 16 + fq * 4;
#pragma unroll
        for (int j = 0; j < 4; j++) {
            int col = n0 + wn * 64 + j * 16 + fr;
            float bv = bias[col];
#pragma unroll
            for (int r = 0; r < 4; r++)
                C[(long)(rbase + r) * 512 + col] = acc[i][j][r] + bv;
        }
    }
}

// ---------------------------------------------------------------------------
// agent[b,a,c] = mean over 8x8 spatial block of q (q fp32, stride 512)
// ---------------------------------------------------------------------------
__global__ __launch_bounds__(256) void pool_q(
    const float* __restrict__ q, float* __restrict__ agent)
{
    int blk = blockIdx.x;
    int half = blk & 1;
    int a = (blk >> 1) % AGENT_NUM;
    int b = blk / (2 * AGENT_NUM);
    int c = half * 256 + threadIdx.x;
    int pa = a / 7, pb = a % 7;
    const float* base = q + (long)b * N_TOK * 512 + c;
    float s = 0.f;
#pragma unroll
    for (int i = 0; i < 8; i++) {
        int rowbase = (pa * 8 + i) * H_IMG + pb * 8;
#pragma unroll
        for (int j = 0; j < 8; j++)
            s += base[(long)(rowbase + j) * 512];
    }
    agent[((long)b * AGENT_NUM + a) * 512 + c] = s * (1.f / 64.f);
}

// ---------------------------------------------------------------------------
// Agent attention, split over n: each block = 448 tokens (14 tiles of 32),
// writes partial (acc, m, l). Flash-style online softmax.
// ---------------------------------------------------------------------------
__global__ __launch_bounds__(256) void agent_attn_partial(
    const unsigned short* __restrict__ kO, const unsigned short* __restrict__ vO,
    const float* __restrict__ agent,
    float* __restrict__ macc, float* __restrict__ mpart, float* __restrict__ lpart)
{
    int blk = blockIdx.x;              // (b*8+h)*7 + s
    int s = blk % N_SPLIT;
    int bh = blk / N_SPLIT;
    int b = bh >> 3, h = bh & 7;
    int tid = threadIdx.x;

    __shared__ float ah[AGENT_NUM * 64];
    __shared__ float kt[32 * 65];
    __shared__ float vt[32 * 65];
    __shared__ float sS[AGENT_NUM * 33];
    __shared__ float accL[AGENT_NUM * 65];
    __shared__ float alphaS[AGENT_NUM];

    for (int idx = tid; idx < AGENT_NUM * 64; idx += 256) {
        int a = idx >> 6, d = idx & 63;
        ah[idx] = agent[((long)b * AGENT_NUM + a) * 512 + h * 64 + d] * SCALE;
        accL[a * 65 + d] = 0.f;
    }
    float m_a = -1e30f, l_a = 0.f;
    __syncthreads();

    const unsigned short* kbase = kO + (long)b * N_TOK * 512 + h * 64;
    const unsigned short* vbase = vO + (long)b * N_TOK * 512 + h * 64;

    int nstart = s * (N_TOK / N_SPLIT);
    int nend = nstart + (N_TOK / N_SPLIT);
    for (int n0 = nstart; n0 < nend; n0 += 32) {
        for (int f = tid; f < 32 * 16; f += 256) {
            int i = f >> 4, d4 = (f & 15) << 2;
            ushort4 ku = *(const ushort4*)(kbase + (long)(n0 + i) * 512 + d4);
            ushort4 vu = *(const ushort4*)(vbase + (long)(n0 + i) * 512 + d4);
            int o = i * 65 + d4;
            kt[o + 0] = bf2f(ku.x); kt[o + 1] = bf2f(ku.y);
            kt[o + 2] = bf2f(ku.z); kt[o + 3] = bf2f(ku.w);
            vt[o + 0] = bf2f(vu.x); vt[o + 1] = bf2f(vu.y);
            vt[o + 2] = bf2f(vu.z); vt[o + 3] = bf2f(vu.w);
        }
        __syncthreads();

        for (int idx = tid; idx < AGENT_NUM * 32; idx += 256) {
            int a = idx >> 5, i = idx & 31;
            const float* ap = ah + a * 64;
            const float* kp = kt + i * 65;
            float sum = 0.f;
#pragma unroll
            for (int d = 0; d < 64; d++) sum += ap[d] * kp[d];
            sS[a * 33 + i] = sum;
        }
        __syncthreads();

        if (tid < AGENT_NUM) {
            float* sp = sS + tid * 33;
            float mx = m_a;
            for (int i = 0; i < 32; i++) mx = fmaxf(mx, sp[i]);
            float alpha = __expf(m_a - mx);
            float sum = 0.f;
            for (int i = 0; i < 32; i++) {
                float p = __expf(sp[i] - mx);
                sp[i] = p;
                sum += p;
            }
            l_a = l_a * alpha + sum;
            m_a = mx;
            alphaS[tid] = alpha;
        }
        __syncthreads();

        for (int idx = tid; idx < AGENT_NUM * 64; idx += 256) {
            int a = idx >> 6, d = idx & 63;
            const float* pp = sS + a * 33;
            float acc = accL[a * 65 + d] * alphaS[a];
#pragma unroll
            for (int i = 0; i < 32; i++) acc += pp[i] * vt[i * 65 + d];
            accL[a * 65 + d] = acc;
        }
        __syncthreads();
    }

    if (tid < AGENT_NUM) {
        mpart[(long)blk * AGENT_NUM + tid] = m_a;
        lpart[(long)blk * AGENT_NUM + tid] = l_a;
    }
    for (int idx = tid; idx < AGENT_NUM * 64; idx += 256)
        macc[(long)blk * (AGENT_NUM * 64) + idx] = accL[(idx >> 6) * 65 + (idx & 63)];
}

// Combine the N_SPLIT partials -> agent_v[b,h,a,d]
__global__ __launch_bounds__(256) void agent_attn_combine(
    const float* __restrict__ macc, const float* __restrict__ mpart,
    const float* __restrict__ lpart, float* __restrict__ agent_v)
{
    int bh = blockIdx.x;               // 0..255
    int tid = threadIdx.x;
    __shared__ float E[AGENT_NUM * N_SPLIT];
    __shared__ float Linv[AGENT_NUM];

    if (tid < AGENT_NUM) {
        float mx = -1e30f;
        for (int s = 0; s < N_SPLIT; s++)
            mx = fmaxf(mx, mpart[((long)bh * N_SPLIT + s) * AGENT_NUM + tid]);
        float l = 0.f;
        for (int s = 0; s < N_SPLIT; s++) {
            float e = __expf(mpart[((long)bh * N_SPLIT + s) * AGENT_NUM + tid] - mx);
            E[tid * N_SPLIT + s] = e;
            l += e * lpart[((long)bh * N_SPLIT + s) * AGENT_NUM + tid];
        }
        Linv[tid] = 1.f / l;
    }
    __syncthreads();

    for (int idx = tid; idx < AGENT_NUM * 64; idx += 256) {
        int a = idx >> 6;
        float acc = 0.f;
        for (int s = 0; s < N_SPLIT; s++)
            acc += E[a * N_SPLIT + s] *
                   macc[((long)bh * N_SPLIT + s) * (AGENT_NUM * 64) + idx];
        agent_v[(long)bh * (AGENT_NUM * 64) + idx] = acc * Linv[a];
    }
}

// ---------------------------------------------------------------------------
// q attention, IN-PLACE on d_out (q fp32): each (n, h-slice) owned by 1 thread
// ---------------------------------------------------------------------------
__global__ __launch_bounds__(256) void q_attn(
    float* __restrict__ q, const float* __restrict__ agent,
    const float* __restrict__ agent_v)
{
    int chunk = blockIdx.x, h = blockIdx.y, b = blockIdx.z;
    int tid = threadIdx.x;

    __shared__ float ah[AGENT_NUM * 64];
    __shared__ float av[AGENT_NUM * 64];
    for (int idx = tid; idx < AGENT_NUM * 64; idx += 256) {
        int a = idx >> 6, d = idx & 63;
        ah[idx] = agent[((long)b * AGENT_NUM + a) * 512 + h * 64 + d];
        av[idx] = agent_v[((long)b * 8 + h) * (AGENT_NUM * 64) + idx];
    }
    __syncthreads();

    int n = chunk * 256 + tid;
    if (n >= N_TOK) return;

    float* qrow = q + ((long)b * N_TOK + n) * 512 + h * 64;
    float4 q4[16];
#pragma unroll
    for (int i = 0; i < 16; i++) q4[i] = *(float4*)(qrow + i * 4);

    float sc[AGENT_NUM];
#pragma unroll
    for (int a = 0; a < AGENT_NUM; a++) {
        const float* ap = ah + a * 64;
        float s = 0.f;
#pragma unroll
        for (int i = 0; i < 16; i++) {
            s += q4[i].x * ap[i * 4 + 0] + q4[i].y * ap[i * 4 + 1]
               + q4[i].z * ap[i * 4 + 2] + q4[i].w * ap[i * 4 + 3];
        }
        sc[a] = s * SCALE;
    }
    float mx = sc[0];
#pragma unroll
    for (int a = 1; a < AGENT_NUM; a++) mx = fmaxf(mx, sc[a]);
    float sum = 0.f;
#pragma unroll
    for (int a = 0; a < AGENT_NUM; a++) { sc[a] = __expf(sc[a] - mx); sum += sc[a]; }
    float inv = 1.f / sum;

#pragma unroll
    for (int d4 = 0; d4 < 16; d4++) {
        float4 o = make_float4(0.f, 0.f, 0.f, 0.f);
#pragma unroll
        for (int a = 0; a < AGENT_NUM; a++) {
            float p = sc[a];
            const float* vp = av + a * 64 + d4 * 4;
            o.x += p * vp[0]; o.y += p * vp[1];
            o.z += p * vp[2]; o.w += p * vp[3];
        }
        o.x *= inv; o.y *= inv; o.z *= inv; o.w *= inv;
        *(float4*)(qrow + d4 * 4) = o;
    }
}

// ---------------------------------------------------------------------------
// Fused: depthwise 3x3 conv on v (bf16) + bias + attn(d_out fp32) add,
// RNE-cast to bf16 proj input. One thread = 8 contiguous channels.
// All 64 lanes of a wave share one pixel -> edge branches are wave-uniform.
// w staged in LDS, pad-73 layout: lane stride 73 == 9 (mod 32) -> conflict-free.
// ---------------------------------------------------------------------------
__global__ __launch_bounds__(256) void dwc_fuse(
    const unsigned short* __restrict__ vO, const float* __restrict__ w,
    const float* __restrict__ bias, const float* __restrict__ attn,
    unsigned short* __restrict__ outb)
{
    __shared__ float ws2[64 * 73];
    for (int i = threadIdx.x; i < 512 * 9; i += 256) {
        int c = i / 9, k = i - c * 9;
        ws2[(c >> 3) * 73 + k * 8 + (c & 7)] = w[i];
    }
    __syncthreads();

    long flat = (long)blockIdx.x * 256 + threadIdx.x;  // over M_ROWS*64
    int cg = (int)(flat & 63);
    int c8 = cg << 3;
    long row = flat >> 6;                              // b*N_TOK + n
    int n = (int)(row % N_TOK);
    int b = (int)(row / N_TOK);
    int y = n / H_IMG, x = n - y * H_IMG;

    const unsigned short* vb = vO + (long)b * N_TOK * 512 + c8;
    const float* wb = ws2 + cg * 73;

    float acc[8];
    float4 bv0 = *(const float4*)(bias + c8);
    float4 bv1 = *(const float4*)(bias + c8 + 4);
    acc[0] = bv0.x; acc[1] = bv0.y; acc[2] = bv0.z; acc[3] = bv0.w;
    acc[4] = bv1.x; acc[5] = bv1.y; acc[6] = bv1.z; acc[7] = bv1.w;

#pragma unroll
    for (int dy = 0; dy < 3; dy++) {
        int yy = y + dy - 1;
        if (yy < 0 || yy >= H_IMG) continue;
#pragma unroll
        for (int dx = 0; dx < 3; dx++) {
            int xx = x + dx - 1;
            if (xx < 0 || xx >= H_IMG) continue;
            const unsigned short* vp = vb + (long)(yy * H_IMG + xx) * 512;
            ushort4 u0 = *(const ushort4*)(vp);
            ushort4 u1 = *(const ushort4*)(vp + 4);
            const float* wk = wb + (dy * 3 + dx) * 8;
            acc[0] += wk[0] * bf2f(u0.x);
            acc[1] += wk[1] * bf2f(u0.y);
            acc[2] += wk[2] * bf2f(u0.z);
            acc[3] += wk[3] * bf2f(u0.w);
            acc[4] += wk[4] * bf2f(u1.x);
            acc[5] += wk[5] * bf2f(u1.y);
            acc[6] += wk[6] * bf2f(u1.z);
            acc[7] += wk[7] * bf2f(u1.w);
        }
    }

    const float* ap = attn + row * 512 + c8;
    float4 a0 = *(const float4*)(ap);
    float4 a1 = *(const float4*)(ap + 4);
    ushort4 o0, o1;
    o0.x = f2bf(a0.x + acc[0]); o0.y = f2bf(a0.y + acc[1]);
    o0.z = f2bf(a0.z + acc[2]); o0.w = f2bf(a0.w + acc[3]);
    o1.x = f2bf(a1.x + acc[4]); o1.y = f2bf(a1.y + acc[5]);
    o1.z = f2bf(a1.z + acc[6]); o1.w = f2bf(a1.w + acc[7]);

    unsigned short* op = outb + row * 512 + c8;
    *(ushort4*)(op)     = o0;
    *(ushort4*)(op + 4) = o1;
}

// ---------------------------------------------------------------------------
extern "C" void kernel_launch(void* const* d_in, const int* in_sizes, int n_in,
                              void* d_out, int out_size, void* d_ws, size_t ws_size,
                              hipStream_t stream)
{
    const float* x      = (const float*)d_in[0];
    const float* qkv_w  = (const float*)d_in[1];
    const float* proj_w = (const float*)d_in[2];
    const float* proj_b = (const float*)d_in[3];
    const float* dwc_w  = (const float*)d_in[4];
    const float* dwc_b  = (const float*)d_in[5];
    float* out = (float*)d_out;

    const long KV_ELEMS    = (long)M_ROWS * 512;                  // 51,380,224
    const long QKVW_ELEMS  = 1536L * 512;                         // 786,432
    const long PROJW_ELEMS = 512L * 512;                          // 262,144
    const long AGENT_ELEMS = (long)B_SZ * AGENT_NUM * 512;
    const long AV_ELEMS    = (long)B_SZ * 8 * AGENT_NUM * 64;
    const long MACC_ELEMS  = (long)B_SZ * 8 * N_SPLIT * AGENT_NUM * 64;
    const long ML_ELEMS    = (long)B_SZ * 8 * N_SPLIT * AGENT_NUM;

    unsigned short* kbuf    = (unsigned short*)d_ws;   // reused as proj-A later
    unsigned short* vbuf    = kbuf + KV_ELEMS;
    unsigned short* qkv_wb  = vbuf + KV_ELEMS;
    unsigned short* proj_wb = qkv_wb + QKVW_ELEMS;
    float* agent   = (float*)(proj_wb + PROJW_ELEMS);
    float* agent_v = agent + AGENT_ELEMS;
    float* macc    = agent_v + AV_ELEMS;
    float* mpart   = macc + MACC_ELEMS;
    float* lpart   = mpart + ML_ELEMS;
    unsigned short* xb = (unsigned short*)(lpart + ML_ELEMS);   // bf16 copy of x

    size_t need_old = (size_t)(2 * KV_ELEMS + QKVW_ELEMS + PROJW_ELEMS) * 2
                    + (size_t)(AGENT_ELEMS + AV_ELEMS + MACC_ELEMS + 2 * ML_ELEMS) * 4;
    size_t need_new = need_old + (size_t)KV_ELEMS * 2;
    if (ws_size < need_old) return;
    const bool precast = (ws_size >= need_new);

    // 0. cast weights to bf16
    cast_f32_bf16<<<(unsigned)(QKVW_ELEMS / 1024), 256, 0, stream>>>(qkv_w, qkv_wb);
    cast_f32_bf16<<<(unsigned)(PROJW_ELEMS / 1024), 256, 0, stream>>>(proj_w, proj_wb);

    // 1. qkv GEMM: q -> d_out (fp32), k,v -> ws (bf16)
    if (precast) {
        cast_f32_bf16<<<(unsigned)(KV_ELEMS / 1024), 256, 0, stream>>>(x, xb);
        mfma_qkv_bf<<<dim3(12, M_ROWS / 128), 256, 0, stream>>>(
            xb, qkv_wb, out, kbuf, vbuf);
    } else {
        mfma_qkv<<<dim3(M_ROWS / 128, 12), 256, 0, stream>>>(
            x, qkv_wb, out, kbuf, vbuf);
    }

    // 2. agent = 7x7 pool of q
    pool_q<<<B_SZ * AGENT_NUM * 2, 256, 0, stream>>>(out, agent);

    // 3. agent attention (split + combine) -> agent_v
    agent_attn_partial<<<B_SZ * 8 * N_SPLIT, 256, 0, stream>>>(
        kbuf, vbuf, agent, macc, mpart, lpart);
    agent_attn_combine<<<B_SZ * 8, 256, 0, stream>>>(macc, mpart, lpart, agent_v);

    // 4. q attention, in-place on d_out
    q_attn<<<dim3((N_TOK + 255) / 256, 8, B_SZ), 256, 0, stream>>>(out, agent, agent_v);

    // 5. fused dwc + attn-add + bf16 cast -> kbuf (k dead now); replaces
    //    old dwc_kernel + final cast pass
    dwc_fuse<<<(unsigned)((long)M_ROWS * 64 / 256), 256, 0, stream>>>(
        vbuf, dwc_w, dwc_b, out, kbuf);

    // 6. final projection (bf16 MFMA, fp32 epilogue + bias)
    mfma_proj<<<dim3(4, M_ROWS / 128), 256, 0, stream>>>(kbuf, proj_wb, proj_b, out);
}

// Round 2
// 1357.207 us; speedup vs baseline: 1.5007x; 1.2235x over previous
//
#include <hip/hip_runtime.h>

#define B_SZ 32
#define N_TOK 3136
#define C_DIM 512
#define H_IMG 56
#define NUM_HEADS 8
#define HEAD_DIM 64
#define AGENT_NUM 49
#define SCALE 0.125f
#define M_ROWS (B_SZ * N_TOK)        // 100352
#define N_SPLIT 7                    // agent-attn n-splits (448 tokens each)

typedef __bf16 bf16x8 __attribute__((ext_vector_type(8)));
typedef float f32x4 __attribute__((ext_vector_type(4)));
typedef unsigned short u16x8 __attribute__((ext_vector_type(8)));
typedef unsigned int u32x4 __attribute__((ext_vector_type(4)));

static __device__ __forceinline__ unsigned short f2bf(float f) {
    unsigned int u = __float_as_uint(f);
    unsigned int r = (u + 0x7fffu + ((u >> 16) & 1u)) >> 16;   // RNE
    return (unsigned short)r;
}
static __device__ __forceinline__ float bf2f(unsigned short u) {
    return __uint_as_float(((unsigned int)u) << 16);
}
// async global->LDS, 16B per lane; lds dest must be wave-uniform (HW: base + lane*16)
static __device__ __forceinline__ void load_lds16(const unsigned short* g, unsigned short* l) {
    __builtin_amdgcn_global_load_lds(
        (const __attribute__((address_space(1))) unsigned int*)g,
        (__attribute__((address_space(3))) unsigned int*)l, 16, 0, 0);
}

// generic fp32 -> bf16 cast, count must be multiple of 1024
__global__ __launch_bounds__(256) void cast_f32_bf16(
    const float* __restrict__ in, unsigned short* __restrict__ out)
{
    long i = (long)blockIdx.x * 256 + threadIdx.x;   // float4 index
    float4 f = ((const float4*)in)[i];
    ushort4 u;
    u.x = f2bf(f.x); u.y = f2bf(f.y); u.z = f2bf(f.z); u.w = f2bf(f.w);
    ((ushort4*)out)[i] = u;
}

// ---------------------------------------------------------------------------
// QKV MFMA GEMM (bf16 A path): [M,1536] = xb[M,512](bf16) @ qkv_wb[1536,512]^T
// 128x128 tile, BK=32, 4 waves. Grid (12, M/128): n-block fastest so the 12
// blocks sharing one A-tile are adjacent -> A fetched ~once from HBM.
// q (cols 0:512) -> fp32 d_out;  k,v -> bf16 ws.
// ---------------------------------------------------------------------------
__global__ __launch_bounds__(256) void mfma_qkv_bf(
    const unsigned short* __restrict__ Ab, const unsigned short* __restrict__ Wb,
    float* __restrict__ qO, unsigned short* __restrict__ kO,
    unsigned short* __restrict__ vO)
{
    __shared__ __align__(16) unsigned short Asm[128 * 32];
    __shared__ __align__(16) unsigned short Bsm[128 * 32];

    const int n0 = blockIdx.x * 128, m0 = blockIdx.y * 128;
    const int tid = threadIdx.x;
    const int lane = tid & 63, wave = tid >> 6;
    const int wm = wave >> 1, wn = wave & 1;

    f32x4 acc[4][4];
#pragma unroll
    for (int i = 0; i < 4; i++)
#pragma unroll
        for (int j = 0; j < 4; j++) {
            f32x4 z = {0.f, 0.f, 0.f, 0.f};
            acc[i][j] = z;
        }

    const unsigned short* aP0 = Ab + (long)(m0 + (tid >> 2)) * 512 + (tid & 3) * 8;
    const unsigned short* aP1 = aP0 + (long)64 * 512;
    const unsigned short* bP0 = Wb + (long)(n0 + (tid >> 2)) * 512 + (tid & 3) * 8;
    const unsigned short* bP1 = bP0 + (long)64 * 512;
    unsigned short* aD0 = Asm + (tid >> 6) * 512;   // wave-uniform
    unsigned short* aD1 = aD0 + 4 * 512;
    unsigned short* bD0 = Bsm + (tid >> 6) * 512;
    unsigned short* bD1 = bD0 + 4 * 512;

    const int fr = lane & 15, fq = lane >> 4;
    const unsigned short* aF = Asm + (wm * 64 + fr) * 32 + fq * 8;
    const unsigned short* bF = Bsm + (wn * 64 + fr) * 32 + fq * 8;

    for (int k0 = 0; k0 < 512; k0 += 32) {
        load_lds16(aP0 + k0, aD0);
        load_lds16(aP1 + k0, aD1);
        load_lds16(bP0 + k0, bD0);
        load_lds16(bP1 + k0, bD1);
        __syncthreads();

        bf16x8 af[4], bfr[4];
#pragma unroll
        for (int i = 0; i < 4; i++) af[i]  = *(const bf16x8*)(aF + i * 16 * 32);
#pragma unroll
        for (int j = 0; j < 4; j++) bfr[j] = *(const bf16x8*)(bF + j * 16 * 32);
#pragma unroll
        for (int i = 0; i < 4; i++)
#pragma unroll
            for (int j = 0; j < 4; j++)
                acc[i][j] = __builtin_amdgcn_mfma_f32_16x16x32_bf16(
                    af[i], bfr[j], acc[i][j], 0, 0, 0);
        __syncthreads();
    }

    // epilogue: C/D layout col=lane&15, row=(lane>>4)*4+reg
    const int seg = n0 >> 9;   // 0=q,1=k,2=v (block never straddles: 128|512)
#pragma unroll
    for (int i = 0; i < 4; i++) {
        int rbase = m0 + wm * 64 + i * 16 + fq * 4;
#pragma unroll
        for (int j = 0; j < 4; j++) {
            int col  = n0 + wn * 64 + j * 16 + fr;
            int nloc = col - seg * 512;
#pragma unroll
            for (int r = 0; r < 4; r++) {
                long m = rbase + r;
                float val = acc[i][j][r];
                if (seg == 0)      qO[m * 512 + nloc] = val;
                else if (seg == 1) kO[m * 512 + nloc] = f2bf(val);
                else               vO[m * 512 + nloc] = f2bf(val);
            }
        }
    }
}

// ---------------------------------------------------------------------------
// Fallback QKV GEMM (fp32 A, cast in staging) — used if workspace too small
// for the bf16 x copy.
// ---------------------------------------------------------------------------
__global__ __launch_bounds__(256) void mfma_qkv(
    const float* __restrict__ A, const unsigned short* __restrict__ Wb,
    float* __restrict__ qO, unsigned short* __restrict__ kO,
    unsigned short* __restrict__ vO)
{
    __shared__ __align__(16) unsigned short Asm[128 * 32];
    __shared__ __align__(16) unsigned short Bsm[128 * 32];

    const int m0 = blockIdx.x * 128, n0 = blockIdx.y * 128;
    const int tid = threadIdx.x;
    const int lane = tid & 63, wave = tid >> 6;
    const int wm = wave >> 1, wn = wave & 1;

    f32x4 acc[4][4];
#pragma unroll
    for (int i = 0; i < 4; i++)
#pragma unroll
        for (int j = 0; j < 4; j++) {
            f32x4 z = {0.f, 0.f, 0.f, 0.f};
            acc[i][j] = z;
        }

    const int arow = tid >> 1, acol = (tid & 1) * 16;
    const float* aP = A + (long)(m0 + arow) * 512 + acol;
    unsigned short* aD = Asm + arow * 32 + acol;

    const unsigned short* bP0 = Wb + (long)(n0 + (tid >> 2)) * 512 + (tid & 3) * 8;
    const unsigned short* bP1 = bP0 + (long)64 * 512;
    unsigned short* bD0 = Bsm + (tid >> 6) * 512;
    unsigned short* bD1 = bD0 + 4 * 512;

    const int fr = lane & 15, fq = lane >> 4;
    const unsigned short* aF = Asm + (wm * 64 + fr) * 32 + fq * 8;
    const unsigned short* bF = Bsm + (wn * 64 + fr) * 32 + fq * 8;

    for (int k0 = 0; k0 < 512; k0 += 32) {
        load_lds16(bP0 + k0, bD0);
        load_lds16(bP1 + k0, bD1);
        float4 f0 = *(const float4*)(aP + k0 + 0);
        float4 f1 = *(const float4*)(aP + k0 + 4);
        float4 f2 = *(const float4*)(aP + k0 + 8);
        float4 f3 = *(const float4*)(aP + k0 + 12);
        ushort4 u0, u1, u2, u3;
        u0.x = f2bf(f0.x); u0.y = f2bf(f0.y); u0.z = f2bf(f0.z); u0.w = f2bf(f0.w);
        u1.x = f2bf(f1.x); u1.y = f2bf(f1.y); u1.z = f2bf(f1.z); u1.w = f2bf(f1.w);
        u2.x = f2bf(f2.x); u2.y = f2bf(f2.y); u2.z = f2bf(f2.z); u2.w = f2bf(f2.w);
        u3.x = f2bf(f3.x); u3.y = f2bf(f3.y); u3.z = f2bf(f3.z); u3.w = f2bf(f3.w);
        *(ushort4*)(aD + 0)  = u0;
        *(ushort4*)(aD + 4)  = u1;
        *(ushort4*)(aD + 8)  = u2;
        *(ushort4*)(aD + 12) = u3;
        __syncthreads();

        bf16x8 af[4], bfr[4];
#pragma unroll
        for (int i = 0; i < 4; i++) af[i]  = *(const bf16x8*)(aF + i * 16 * 32);
#pragma unroll
        for (int j = 0; j < 4; j++) bfr[j] = *(const bf16x8*)(bF + j * 16 * 32);
#pragma unroll
        for (int i = 0; i < 4; i++)
#pragma unroll
            for (int j = 0; j < 4; j++)
                acc[i][j] = __builtin_amdgcn_mfma_f32_16x16x32_bf16(
                    af[i], bfr[j], acc[i][j], 0, 0, 0);
        __syncthreads();
    }

    const int seg = n0 >> 9;
#pragma unroll
    for (int i = 0; i < 4; i++) {
        int rbase = m0 + wm * 64 + i * 16 + fq * 4;
#pragma unroll
        for (int j = 0; j < 4; j++) {
            int col  = n0 + wn * 64 + j * 16 + fr;
            int nloc = col - seg * 512;
#pragma unroll
            for (int r = 0; r < 4; r++) {
                long m = rbase + r;
                float val = acc[i][j][r];
                if (seg == 0)      qO[m * 512 + nloc] = val;
                else if (seg == 1) kO[m * 512 + nloc] = f2bf(val);
                else               vO[m * 512 + nloc] = f2bf(val);
            }
        }
    }
}

// ---------------------------------------------------------------------------
// Proj MFMA GEMM: d_out[M,512] = Ab[M,512](bf16) @ proj_wb[512,512]^T + bias
// Grid (4, M/128): n-block fastest for A-tile L2 reuse.
// ---------------------------------------------------------------------------
__global__ __launch_bounds__(256) void mfma_proj(
    const unsigned short* __restrict__ Ab, const unsigned short* __restrict__ Wb,
    const float* __restrict__ bias, float* __restrict__ C)
{
    __shared__ __align__(16) unsigned short Asm[128 * 32];
    __shared__ __align__(16) unsigned short Bsm[128 * 32];

    const int n0 = blockIdx.x * 128, m0 = blockIdx.y * 128;
    const int tid = threadIdx.x;
    const int lane = tid & 63, wave = tid >> 6;
    const int wm = wave >> 1, wn = wave & 1;

    f32x4 acc[4][4];
#pragma unroll
    for (int i = 0; i < 4; i++)
#pragma unroll
        for (int j = 0; j < 4; j++) {
            f32x4 z = {0.f, 0.f, 0.f, 0.f};
            acc[i][j] = z;
        }

    const unsigned short* aP0 = Ab + (long)(m0 + (tid >> 2)) * 512 + (tid & 3) * 8;
    const unsigned short* aP1 = aP0 + (long)64 * 512;
    const unsigned short* bP0 = Wb + (long)(n0 + (tid >> 2)) * 512 + (tid & 3) * 8;
    const unsigned short* bP1 = bP0 + (long)64 * 512;
    unsigned short* aD0 = Asm + (tid >> 6) * 512;   // wave-uniform
    unsigned short* aD1 = aD0 + 4 * 512;
    unsigned short* bD0 = Bsm + (tid >> 6) * 512;
    unsigned short* bD1 = bD0 + 4 * 512;

    const int fr = lane & 15, fq = lane >> 4;
    const unsigned short* aF = Asm + (wm * 64 + fr) * 32 + fq * 8;
    const unsigned short* bF = Bsm + (wn * 64 + fr) * 32 + fq * 8;

    for (int k0 = 0; k0 < 512; k0 += 32) {
        load_lds16(aP0 + k0, aD0);
        load_lds16(aP1 + k0, aD1);
        load_lds16(bP0 + k0, bD0);
        load_lds16(bP1 + k0, bD1);
        __syncthreads();

        bf16x8 af[4], bfr[4];
#pragma unroll
        for (int i = 0; i < 4; i++) af[i]  = *(const bf16x8*)(aF + i * 16 * 32);
#pragma unroll
        for (int j = 0; j < 4; j++) bfr[j] = *(const bf16x8*)(bF + j * 16 * 32);
#pragma unroll
        for (int i = 0; i < 4; i++)
#pragma unroll
            for (int j = 0; j < 4; j++)
                acc[i][j] = __builtin_amdgcn_mfma_f32_16x16x32_bf16(
                    af[i], bfr[j], acc[i][j], 0, 0, 0);
        __syncthreads();
    }

#pragma unroll
    for (int i = 0; i < 4; i++) {
        int rbase = m0 + wm * 64 + i * 16 + fq * 4;
#pragma unroll
        for (int j = 0; j < 4; j++) {
            int col = n0 + wn * 64 + j * 16 + fr;
            float bv = bias[col];
#pragma unroll
            for (int r = 0; r < 4; r++)
                C[(long)(rbase + r) * 512 + col] = acc[i][j][r] + bv;
        }
    }
}

// ---------------------------------------------------------------------------
// agent[b,a,c] = mean over 8x8 spatial block of q (q fp32, stride 512)
// ---------------------------------------------------------------------------
__global__ __launch_bounds__(256) void pool_q(
    const float* __restrict__ q, float* __restrict__ agent)
{
    int blk = blockIdx.x;
    int half = blk & 1;
    int a = (blk >> 1) % AGENT_NUM;
    int b = blk / (2 * AGENT_NUM);
    int c = half * 256 + threadIdx.x;
    int pa = a / 7, pb = a % 7;
    const float* base = q + (long)b * N_TOK * 512 + c;
    float s = 0.f;
#pragma unroll
    for (int i = 0; i < 8; i++) {
        int rowbase = (pa * 8 + i) * H_IMG + pb * 8;
#pragma unroll
        for (int j = 0; j < 8; j++)
            s += base[(long)(rowbase + j) * 512];
    }
    agent[((long)b * AGENT_NUM + a) * 512 + c] = s * (1.f / 64.f);
}

// ---------------------------------------------------------------------------
// Agent attention via MFMA, split over n (7 x 448 tokens), flash-style.
// Swapped orientation: S^T[tok,agent] = K·A^T so softmax rows are lane-local
// per agent (col = lane&15). Per 64-token tile:
//   K staged [64][64] bf16 with 16B-chunk XOR swizzle (write+read sides)
//   V staged transposed Vt[d][tok] same swizzle (b32 pair-writes, conflict-free)
//   P -> per-wave 2KB swizzled LDS (same-wave write/read, no barrier)
// Writes partial (macc, m, l); combine kernel unchanged.
// ---------------------------------------------------------------------------
__global__ __launch_bounds__(256) void agent_attn_mfma(
    const unsigned short* __restrict__ kO, const unsigned short* __restrict__ vO,
    const float* __restrict__ agent,
    float* __restrict__ macc, float* __restrict__ mpart, float* __restrict__ lpart)
{
    __shared__ __align__(16) unsigned short Ksm[64 * 64];
    __shared__ __align__(16) unsigned short Vsm[64 * 64];
    __shared__ __align__(16) unsigned short Psm[4 * 16 * 64];

    const int blk = blockIdx.x;            // (b*8+h)*7 + s
    const int s = blk % N_SPLIT;
    const int bh = blk / N_SPLIT;
    const int b = bh >> 3, h = bh & 7;
    const int tid = threadIdx.x;
    const int lane = tid & 63, w = tid >> 6;
    const int fr = lane & 15, fq = lane >> 4;

    // A-fragment in registers: agents 16w+fr (zero-padded), scale folded in.
    bf16x8 afA[2];
    {
        int a = w * 16 + fr;
        const float* ap = agent + ((long)b * AGENT_NUM + a) * 512 + h * 64 + fq * 8;
#pragma unroll
        for (int kk = 0; kk < 2; kk++) {
            union { bf16x8 v; unsigned short u[8]; } cv;
#pragma unroll
            for (int e = 0; e < 8; e++) cv.u[e] = 0;
            if (a < AGENT_NUM) {
                float4 f0 = *(const float4*)(ap + kk * 32);
                float4 f1 = *(const float4*)(ap + kk * 32 + 4);
                cv.u[0] = f2bf(f0.x * SCALE); cv.u[1] = f2bf(f0.y * SCALE);
                cv.u[2] = f2bf(f0.z * SCALE); cv.u[3] = f2bf(f0.w * SCALE);
                cv.u[4] = f2bf(f1.x * SCALE); cv.u[5] = f2bf(f1.y * SCALE);
                cv.u[6] = f2bf(f1.z * SCALE); cv.u[7] = f2bf(f1.w * SCALE);
            }
            afA[kk] = cv.v;
        }
    }

    // staging addresses
    const unsigned short* kg = kO + (long)b * N_TOK * 512 + h * 64;
    const unsigned short* vg = vO + (long)b * N_TOK * 512 + h * 64;
    const int krow = tid >> 2, kcc = tid & 3;
    char* kdst0 = (char*)Ksm + krow * 128 + (((kcc * 2)     ^ (krow & 7)) * 16);
    char* kdst1 = (char*)Ksm + krow * 128 + (((kcc * 2 + 1) ^ (krow & 7)) * 16);
    const int vtp = tid & 31, vd0 = (tid >> 5) * 8;

    // fragment-read swizzled chunk offsets (chunk = kk*4+fq, XOR fr&7)
    const int cs0 = ((fq)     ^ (fr & 7)) * 16;
    const int cs1 = ((4 + fq) ^ (fr & 7)) * 16;
    char* plb = (char*)Psm + w * 2048;     // per-wave P region [16][64] bf16

    f32x4 accO[4];
#pragma unroll
    for (int dj = 0; dj < 4; dj++) {
        f32x4 z = {0.f, 0.f, 0.f, 0.f};
        accO[dj] = z;
    }
    float m_a = -1e30f, l_a = 0.f;

    const int nstart = s * (N_TOK / N_SPLIT);
    for (int t = 0; t < 7; t++) {
        const int n0 = nstart + t * 64;
        __syncthreads();   // previous tile fully consumed
        {   // stage K: [64 tok][64 d], swizzled chunks
            const unsigned short* src = kg + (long)(n0 + krow) * 512 + kcc * 16;
            u32x4 d0 = *(const u32x4*)(src);
            u32x4 d1 = *(const u32x4*)(src + 8);
            *(u32x4*)kdst0 = d0;
            *(u32x4*)kdst1 = d1;
        }
        {   // stage V transposed: Vt[d][tok], b32 holds tok pair (2tp,2tp+1)
            const unsigned short* sv = vg + (long)(n0 + vtp * 2) * 512 + vd0;
            u16x8 v0 = *(const u16x8*)(sv);
            u16x8 v1 = *(const u16x8*)(sv + 512);
#pragma unroll
            for (int j = 0; j < 8; j++) {
                unsigned int val = (unsigned int)v0[j] | ((unsigned int)v1[j] << 16);
                *(unsigned int*)((char*)Vsm + (vd0 + j) * 128
                                 + (((vtp >> 2) ^ j) * 16) + (vtp & 3) * 4) = val;
            }
        }
        __syncthreads();

        // S^T = K·A^T : rows = toks (it*16 + fq*4 + r), col = agent 16w+fr
        f32x4 sacc[4];
#pragma unroll
        for (int it = 0; it < 4; it++) {
            f32x4 z = {0.f, 0.f, 0.f, 0.f};
            sacc[it] = z;
        }
#pragma unroll
        for (int it = 0; it < 4; it++) {
            bf16x8 kf0 = *(const bf16x8*)((char*)Ksm + it * 2048 + fr * 128 + cs0);
            bf16x8 kf1 = *(const bf16x8*)((char*)Ksm + it * 2048 + fr * 128 + cs1);
            sacc[it] = __builtin_amdgcn_mfma_f32_16x16x32_bf16(kf0, afA[0], sacc[it], 0, 0, 0);
            sacc[it] = __builtin_amdgcn_mfma_f32_16x16x32_bf16(kf1, afA[1], sacc[it], 0, 0, 0);
        }

        // online softmax per agent (lane-local col; reduce across fq groups)
        float mloc = -1e30f;
#pragma unroll
        for (int it = 0; it < 4; it++)
#pragma unroll
            for (int r = 0; r < 4; r++) mloc = fmaxf(mloc, sacc[it][r]);
        mloc = fmaxf(mloc, __shfl_xor(mloc, 16));
        mloc = fmaxf(mloc, __shfl_xor(mloc, 32));
        float mnew = fmaxf(m_a, mloc);
        float alpha = __expf(m_a - mnew);
        float p[4][4];
        float ss = 0.f;
#pragma unroll
        for (int it = 0; it < 4; it++)
#pragma unroll
            for (int r = 0; r < 4; r++) {
                float pv = __expf(sacc[it][r] - mnew);
                p[it][r] = pv;
                ss += pv;
            }
        ss += __shfl_xor(ss, 16);
        ss += __shfl_xor(ss, 32);
        l_a = l_a * alpha + ss;
        m_a = mnew;

        // P^T -> bf16 per-wave LDS: row = agent fr, tok = it*16 + fq*4 + 2pr+{0,1}
#pragma unroll
        for (int it = 0; it < 4; it++)
#pragma unroll
            for (int pr = 0; pr < 2; pr++) {
                unsigned int u = (unsigned int)f2bf(p[it][pr * 2])
                               | ((unsigned int)f2bf(p[it][pr * 2 + 1]) << 16);
                *(unsigned int*)(plb + fr * 128
                    + (((it * 2 + (fq >> 1)) ^ (fr & 7)) * 16)
                    + (fq & 1) * 8 + pr * 4) = u;
            }

        // rescale O: O rows are agents fq*4+r; alpha lives at lane fr=fq*4+r
        float alr[4];
#pragma unroll
        for (int r = 0; r < 4; r++)
            alr[r] = __shfl(alpha, ((lane >> 4) << 2) + r);
#pragma unroll
        for (int dj = 0; dj < 4; dj++)
#pragma unroll
            for (int r = 0; r < 4; r++) accO[dj][r] *= alr[r];

        // PV: O[agent, d] += P[agent, tok] · Vt[d, tok]
        bf16x8 pf0 = *(const bf16x8*)(plb + fr * 128 + cs0);
        bf16x8 pf1 = *(const bf16x8*)(plb + fr * 128 + cs1);
#pragma unroll
        for (int dj = 0; dj < 4; dj++) {
            bf16x8 vf0 = *(const bf16x8*)((char*)Vsm + dj * 2048 + fr * 128 + cs0);
            bf16x8 vf1 = *(const bf16x8*)((char*)Vsm + dj * 2048 + fr * 128 + cs1);
            accO[dj] = __builtin_amdgcn_mfma_f32_16x16x32_bf16(pf0, vf0, accO[dj], 0, 0, 0);
            accO[dj] = __builtin_amdgcn_mfma_f32_16x16x32_bf16(pf1, vf1, accO[dj], 0, 0, 0);
        }
    }

    // epilogue: partials (unnormalized acc + m,l per agent)
    float* mob = macc + (long)blk * (AGENT_NUM * 64);
#pragma unroll
    for (int dj = 0; dj < 4; dj++)
#pragma unroll
        for (int r = 0; r < 4; r++) {
            int a = w * 16 + fq * 4 + r;
            if (a < AGENT_NUM)
                mob[a * 64 + dj * 16 + fr] = accO[dj][r];
        }
    if (fq == 0) {
        int a = w * 16 + fr;
        if (a < AGENT_NUM) {
            mpart[(long)blk * AGENT_NUM + a] = m_a;
            lpart[(long)blk * AGENT_NUM + a] = l_a;
        }
    }
}

// Combine the N_SPLIT partials -> agent_v[b,h,a,d]
__global__ __launch_bounds__(256) void agent_attn_combine(
    const float* __restrict__ macc, const float* __restrict__ mpart,
    const float* __restrict__ lpart, float* __restrict__ agent_v)
{
    int bh = blockIdx.x;               // 0..255
    int tid = threadIdx.x;
    __shared__ float E[AGENT_NUM * N_SPLIT];
    __shared__ float Linv[AGENT_NUM];

    if (tid < AGENT_NUM) {
        float mx = -1e30f;
        for (int s = 0; s < N_SPLIT; s++)
            mx = fmaxf(mx, mpart[((long)bh * N_SPLIT + s) * AGENT_NUM + tid]);
        float l = 0.f;
        for (int s = 0; s < N_SPLIT; s++) {
            float e = __expf(mpart[((long)bh * N_SPLIT + s) * AGENT_NUM + tid] - mx);
            E[tid * N_SPLIT + s] = e;
            l += e * lpart[((long)bh * N_SPLIT + s) * AGENT_NUM + tid];
        }
        Linv[tid] = 1.f / l;
    }
    __syncthreads();

    for (int idx = tid; idx < AGENT_NUM * 64; idx += 256) {
        int a = idx >> 6;
        float acc = 0.f;
        for (int s = 0; s < N_SPLIT; s++)
            acc += E[a * N_SPLIT + s] *
                   macc[((long)bh * N_SPLIT + s) * (AGENT_NUM * 64) + idx];
        agent_v[(long)bh * (AGENT_NUM * 64) + idx] = acc * Linv[a];
    }
}

// ---------------------------------------------------------------------------
// q attention, IN-PLACE on d_out (q fp32): each (n, h-slice) owned by 1 thread
// ---------------------------------------------------------------------------
__global__ __launch_bounds__(256) void q_attn(
    float* __restrict__ q, const float* __restrict__ agent,
    const float* __restrict__ agent_v)
{
    int chunk = blockIdx.x, h = blockIdx.y, b = blockIdx.z;
    int tid = threadIdx.x;

    __shared__ float ah[AGENT_NUM * 64];
    __shared__ float av[AGENT_NUM * 64];
    for (int idx = tid; idx < AGENT_NUM * 64; idx += 256) {
        int a = idx >> 6, d = idx & 63;
        ah[idx] = agent[((long)b * AGENT_NUM + a) * 512 + h * 64 + d];
        av[idx] = agent_v[((long)b * 8 + h) * (AGENT_NUM * 64) + idx];
    }
    __syncthreads();

    int n = chunk * 256 + tid;
    if (n >= N_TOK) return;

    float* qrow = q + ((long)b * N_TOK + n) * 512 + h * 64;
    float4 q4[16];
#pragma unroll
    for (int i = 0; i < 16; i++) q4[i] = *(float4*)(qrow + i * 4);

    float sc[AGENT_NUM];
#pragma unroll
    for (int a = 0; a < AGENT_NUM; a++) {
        const float* ap = ah + a * 64;
        float s = 0.f;
#pragma unroll
        for (int i = 0; i < 16; i++) {
            s += q4[i].x * ap[i * 4 + 0] + q4[i].y * ap[i * 4 + 1]
               + q4[i].z * ap[i * 4 + 2] + q4[i].w * ap[i * 4 + 3];
        }
        sc[a] = s * SCALE;
    }
    float mx = sc[0];
#pragma unroll
    for (int a = 1; a < AGENT_NUM; a++) mx = fmaxf(mx, sc[a]);
    float sum = 0.f;
#pragma unroll
    for (int a = 0; a < AGENT_NUM; a++) { sc[a] = __expf(sc[a] - mx); sum += sc[a]; }
    float inv = 1.f / sum;

#pragma unroll
    for (int d4 = 0; d4 < 16; d4++) {
        float4 o = make_float4(0.f, 0.f, 0.f, 0.f);
#pragma unroll
        for (int a = 0; a < AGENT_NUM; a++) {
            float p = sc[a];
            const float* vp = av + a * 64 + d4 * 4;
            o.x += p * vp[0]; o.y += p * vp[1];
            o.z += p * vp[2]; o.w += p * vp[3];
        }
        o.x *= inv; o.y *= inv; o.z *= inv; o.w *= inv;
        *(float4*)(qrow + d4 * 4) = o;
    }
}

// ---------------------------------------------------------------------------
// Fused: depthwise 3x3 conv on v (bf16) + bias + attn(d_out fp32) add,
// RNE-cast to bf16 proj input. One thread = 8 contiguous channels.
// ---------------------------------------------------------------------------
__global__ __launch_bounds__(256) void dwc_fuse(
    const unsigned short* __restrict__ vO, const float* __restrict__ w,
    const float* __restrict__ bias, const float* __restrict__ attn,
    unsigned short* __restrict__ outb)
{
    __shared__ float ws2[64 * 73];
    for (int i = threadIdx.x; i < 512 * 9; i += 256) {
        int c = i / 9, k = i - c * 9;
        ws2[(c >> 3) * 73 + k * 8 + (c & 7)] = w[i];
    }
    __syncthreads();

    long flat = (long)blockIdx.x * 256 + threadIdx.x;  // over M_ROWS*64
    int cg = (int)(flat & 63);
    int c8 = cg << 3;
    long row = flat >> 6;                              // b*N_TOK + n
    int n = (int)(row % N_TOK);
    int b = (int)(row / N_TOK);
    int y = n / H_IMG, x = n - y * H_IMG;

    const unsigned short* vb = vO + (long)b * N_TOK * 512 + c8;
    const float* wb = ws2 + cg * 73;

    float acc[8];
    float4 bv0 = *(const float4*)(bias + c8);
    float4 bv1 = *(const float4*)(bias + c8 + 4);
    acc[0] = bv0.x; acc[1] = bv0.y; acc[2] = bv0.z; acc[3] = bv0.w;
    acc[4] = bv1.x; acc[5] = bv1.y; acc[6] = bv1.z; acc[7] = bv1.w;

#pragma unroll
    for (int dy = 0; dy < 3; dy++) {
        int yy = y + dy - 1;
        if (yy < 0 || yy >= H_IMG) continue;
#pragma unroll
        for (int dx = 0; dx < 3; dx++) {
            int xx = x + dx - 1;
            if (xx < 0 || xx >= H_IMG) continue;
            const unsigned short* vp = vb + (long)(yy * H_IMG + xx) * 512;
            ushort4 u0 = *(const ushort4*)(vp);
            ushort4 u1 = *(const ushort4*)(vp + 4);
            const float* wk = wb + (dy * 3 + dx) * 8;
            acc[0] += wk[0] * bf2f(u0.x);
            acc[1] += wk[1] * bf2f(u0.y);
            acc[2] += wk[2] * bf2f(u0.z);
            acc[3] += wk[3] * bf2f(u0.w);
            acc[4] += wk[4] * bf2f(u1.x);
            acc[5] += wk[5] * bf2f(u1.y);
            acc[6] += wk[6] * bf2f(u1.z);
            acc[7] += wk[7] * bf2f(u1.w);
        }
    }

    const float* ap = attn + row * 512 + c8;
    float4 a0 = *(const float4*)(ap);
    float4 a1 = *(const float4*)(ap + 4);
    ushort4 o0, o1;
    o0.x = f2bf(a0.x + acc[0]); o0.y = f2bf(a0.y + acc[1]);
    o0.z = f2bf(a0.z + acc[2]); o0.w = f2bf(a0.w + acc[3]);
    o1.x = f2bf(a1.x + acc[4]); o1.y = f2bf(a1.y + acc[5]);
    o1.z = f2bf(a1.z + acc[6]); o1.w = f2bf(a1.w + acc[7]);

    unsigned short* op = outb + row * 512 + c8;
    *(ushort4*)(op)     = o0;
    *(ushort4*)(op + 4) = o1;
}

// ---------------------------------------------------------------------------
extern "C" void kernel_launch(void* const* d_in, const int* in_sizes, int n_in,
                              void* d_out, int out_size, void* d_ws, size_t ws_size,
                              hipStream_t stream)
{
    const float* x      = (const float*)d_in[0];
    const float* qkv_w  = (const float*)d_in[1];
    const float* proj_w = (const float*)d_in[2];
    const float* proj_b = (const float*)d_in[3];
    const float* dwc_w  = (const float*)d_in[4];
    const float* dwc_b  = (const float*)d_in[5];
    float* out = (float*)d_out;

    const long KV_ELEMS    = (long)M_ROWS * 512;                  // 51,380,224
    const long QKVW_ELEMS  = 1536L * 512;                         // 786,432
    const long PROJW_ELEMS = 512L * 512;                          // 262,144
    const long AGENT_ELEMS = (long)B_SZ * AGENT_NUM * 512;
    const long AV_ELEMS    = (long)B_SZ * 8 * AGENT_NUM * 64;
    const long MACC_ELEMS  = (long)B_SZ * 8 * N_SPLIT * AGENT_NUM * 64;
    const long ML_ELEMS    = (long)B_SZ * 8 * N_SPLIT * AGENT_NUM;

    unsigned short* kbuf    = (unsigned short*)d_ws;   // reused as proj-A later
    unsigned short* vbuf    = kbuf + KV_ELEMS;
    unsigned short* qkv_wb  = vbuf + KV_ELEMS;
    unsigned short* proj_wb = qkv_wb + QKVW_ELEMS;
    float* agent   = (float*)(proj_wb + PROJW_ELEMS);
    float* agent_v = agent + AGENT_ELEMS;
    float* macc    = agent_v + AV_ELEMS;
    float* mpart   = macc + MACC_ELEMS;
    float* lpart   = mpart + ML_ELEMS;
    unsigned short* xb = (unsigned short*)(lpart + ML_ELEMS);   // bf16 copy of x

    size_t need_old = (size_t)(2 * KV_ELEMS + QKVW_ELEMS + PROJW_ELEMS) * 2
                    + (size_t)(AGENT_ELEMS + AV_ELEMS + MACC_ELEMS + 2 * ML_ELEMS) * 4;
    size_t need_new = need_old + (size_t)KV_ELEMS * 2;
    if (ws_size < need_old) return;
    const bool precast = (ws_size >= need_new);

    // 0. cast weights to bf16
    cast_f32_bf16<<<(unsigned)(QKVW_ELEMS / 1024), 256, 0, stream>>>(qkv_w, qkv_wb);
    cast_f32_bf16<<<(unsigned)(PROJW_ELEMS / 1024), 256, 0, stream>>>(proj_w, proj_wb);

    // 1. qkv GEMM: q -> d_out (fp32), k,v -> ws (bf16)
    if (precast) {
        cast_f32_bf16<<<(unsigned)(KV_ELEMS / 1024), 256, 0, stream>>>(x, xb);
        mfma_qkv_bf<<<dim3(12, M_ROWS / 128), 256, 0, stream>>>(
            xb, qkv_wb, out, kbuf, vbuf);
    } else {
        mfma_qkv<<<dim3(M_ROWS / 128, 12), 256, 0, stream>>>(
            x, qkv_wb, out, kbuf, vbuf);
    }

    // 2. agent = 7x7 pool of q
    pool_q<<<B_SZ * AGENT_NUM * 2, 256, 0, stream>>>(out, agent);

    // 3. agent attention (MFMA split + combine) -> agent_v
    agent_attn_mfma<<<B_SZ * 8 * N_SPLIT, 256, 0, stream>>>(
        kbuf, vbuf, agent, macc, mpart, lpart);
    agent_attn_combine<<<B_SZ * 8, 256, 0, stream>>>(macc, mpart, lpart, agent_v);

    // 4. q attention, in-place on d_out
    q_attn<<<dim3((N_TOK + 255) / 256, 8, B_SZ), 256, 0, stream>>>(out, agent, agent_v);

    // 5. fused dwc + attn-add + bf16 cast -> kbuf (k dead now)
    dwc_fuse<<<(unsigned)((long)M_ROWS * 64 / 256), 256, 0, stream>>>(
        vbuf, dwc_w, dwc_b, out, kbuf);

    // 6. final projection (bf16 MFMA, fp32 epilogue + bias)
    mfma_proj<<<dim3(4, M_ROWS / 128), 256, 0, stream>>>(kbuf, proj_wb, proj_b, out);
}

// Round 3
// 1270.447 us; speedup vs baseline: 1.6032x; 1.0683x over previous
//
#include <hip/hip_runtime.h>

#define B_SZ 32
#define N_TOK 3136
#define C_DIM 512
#define H_IMG 56
#define NUM_HEADS 8
#define HEAD_DIM 64
#define AGENT_NUM 49
#define SCALE 0.125f
#define M_ROWS (B_SZ * N_TOK)        // 100352
#define N_SPLIT 7                    // agent-attn n-splits (448 tokens each)

typedef __bf16 bf16x8 __attribute__((ext_vector_type(8)));
typedef float f32x4 __attribute__((ext_vector_type(4)));
typedef unsigned short u16x8 __attribute__((ext_vector_type(8)));
typedef unsigned int u32x4 __attribute__((ext_vector_type(4)));

static __device__ __forceinline__ unsigned short f2bf(float f) {
    unsigned int u = __float_as_uint(f);
    unsigned int r = (u + 0x7fffu + ((u >> 16) & 1u)) >> 16;   // RNE
    return (unsigned short)r;
}
static __device__ __forceinline__ float bf2f(unsigned short u) {
    return __uint_as_float(((unsigned int)u) << 16);
}
// async global->LDS, 16B per lane; lds dest must be wave-uniform (HW: base + lane*16)
static __device__ __forceinline__ void load_lds16(const unsigned short* g, unsigned short* l) {
    __builtin_amdgcn_global_load_lds(
        (const __attribute__((address_space(1))) unsigned int*)g,
        (__attribute__((address_space(3))) unsigned int*)l, 16, 0, 0);
}

// generic fp32 -> bf16 cast, count must be multiple of 1024
__global__ __launch_bounds__(256) void cast_f32_bf16(
    const float* __restrict__ in, unsigned short* __restrict__ out)
{
    long i = (long)blockIdx.x * 256 + threadIdx.x;   // float4 index
    float4 f = ((const float4*)in)[i];
    ushort4 u;
    u.x = f2bf(f.x); u.y = f2bf(f.y); u.z = f2bf(f.z); u.w = f2bf(f.w);
    ((ushort4*)out)[i] = u;
}

// ---------------------------------------------------------------------------
// QKV MFMA GEMM (bf16): [M,1536] = xb[M,512] @ qkv_wb[1536,512]^T
// 128x128 tile, BK=32, 4 waves. 1D grid 9408 with bijective XCD swizzle so
// the 12 n-blocks sharing an A-tile run on ONE XCD (A fetched ~once).
// T3-min double-buffer: stage(next) -> compute(cur) -> one barrier per step.
// q (cols 0:512) -> fp32 d_out;  k,v -> bf16 ws.
// ---------------------------------------------------------------------------
__global__ __launch_bounds__(256) void mfma_qkv_bf(
    const unsigned short* __restrict__ Ab, const unsigned short* __restrict__ Wb,
    float* __restrict__ qO, unsigned short* __restrict__ kO,
    unsigned short* __restrict__ vO)
{
    __shared__ __align__(16) unsigned short Asm[2][128 * 32];
    __shared__ __align__(16) unsigned short Bsm[2][128 * 32];

    const int NWG  = (M_ROWS / 128) * 12;   // 9408, % 8 == 0
    const int PERX = NWG >> 3;              // 1176 (= 98 full A-tile groups)
    const int bid = blockIdx.x;
    const int l = (bid & 7) * PERX + (bid >> 3);   // bijective XCD swizzle
    const int m0 = (l / 12) * 128, n0 = (l % 12) * 128;

    const int tid = threadIdx.x;
    const int lane = tid & 63, wave = tid >> 6;
    const int wm = wave >> 1, wn = wave & 1;

    f32x4 acc[4][4];
#pragma unroll
    for (int i = 0; i < 4; i++)
#pragma unroll
        for (int j = 0; j < 4; j++) {
            f32x4 z = {0.f, 0.f, 0.f, 0.f};
            acc[i][j] = z;
        }

    const unsigned short* aP0 = Ab + (long)(m0 + (tid >> 2)) * 512 + (tid & 3) * 8;
    const unsigned short* aP1 = aP0 + (long)64 * 512;
    const unsigned short* bP0 = Wb + (long)(n0 + (tid >> 2)) * 512 + (tid & 3) * 8;
    const unsigned short* bP1 = bP0 + (long)64 * 512;
    const int stA0 = wave * 512;            // wave-uniform stage offsets
    const int stA1 = wave * 512 + 2048;

    const int fr = lane & 15, fq = lane >> 4;
    const int fOff = fq * 8;

    // prologue: stage K-step 0 into buf 0
    load_lds16(aP0, Asm[0] + stA0);
    load_lds16(aP1, Asm[0] + stA1);
    load_lds16(bP0, Bsm[0] + stA0);
    load_lds16(bP1, Bsm[0] + stA1);
    __syncthreads();

    int cur = 0;
    for (int step = 0; step < 16; ++step) {
        if (step < 15) {                    // issue next tile early (flies under MFMA)
            const int k0 = (step + 1) * 32;
            load_lds16(aP0 + k0, Asm[cur ^ 1] + stA0);
            load_lds16(aP1 + k0, Asm[cur ^ 1] + stA1);
            load_lds16(bP0 + k0, Bsm[cur ^ 1] + stA0);
            load_lds16(bP1 + k0, Bsm[cur ^ 1] + stA1);
        }
        const unsigned short* aF = Asm[cur] + (wm * 64 + fr) * 32 + fOff;
        const unsigned short* bF = Bsm[cur] + (wn * 64 + fr) * 32 + fOff;
        bf16x8 af[4], bfr[4];
#pragma unroll
        for (int i = 0; i < 4; i++) af[i]  = *(const bf16x8*)(aF + i * 16 * 32);
#pragma unroll
        for (int j = 0; j < 4; j++) bfr[j] = *(const bf16x8*)(bF + j * 16 * 32);
#pragma unroll
        for (int i = 0; i < 4; i++)
#pragma unroll
            for (int j = 0; j < 4; j++)
                acc[i][j] = __builtin_amdgcn_mfma_f32_16x16x32_bf16(
                    af[i], bfr[j], acc[i][j], 0, 0, 0);
        __syncthreads();                    // drains vmcnt(0)+lgkmcnt(0): next buf ready
        cur ^= 1;
    }

    // epilogue: C/D layout col=lane&15, row=(lane>>4)*4+reg
    const int seg = n0 >> 9;   // 0=q,1=k,2=v (block never straddles: 128|512)
#pragma unroll
    for (int i = 0; i < 4; i++) {
        int rbase = m0 + wm * 64 + i * 16 + fq * 4;
#pragma unroll
        for (int j = 0; j < 4; j++) {
            int col  = n0 + wn * 64 + j * 16 + fr;
            int nloc = col - seg * 512;
#pragma unroll
            for (int r = 0; r < 4; r++) {
                long m = rbase + r;
                float val = acc[i][j][r];
                if (seg == 0)      qO[m * 512 + nloc] = val;
                else if (seg == 1) kO[m * 512 + nloc] = f2bf(val);
                else               vO[m * 512 + nloc] = f2bf(val);
            }
        }
    }
}

// ---------------------------------------------------------------------------
// Fallback QKV GEMM (fp32 A, cast in staging) — used if workspace too small
// for the bf16 x copy.
// ---------------------------------------------------------------------------
__global__ __launch_bounds__(256) void mfma_qkv(
    const float* __restrict__ A, const unsigned short* __restrict__ Wb,
    float* __restrict__ qO, unsigned short* __restrict__ kO,
    unsigned short* __restrict__ vO)
{
    __shared__ __align__(16) unsigned short Asm[128 * 32];
    __shared__ __align__(16) unsigned short Bsm[128 * 32];

    const int m0 = blockIdx.x * 128, n0 = blockIdx.y * 128;
    const int tid = threadIdx.x;
    const int lane = tid & 63, wave = tid >> 6;
    const int wm = wave >> 1, wn = wave & 1;

    f32x4 acc[4][4];
#pragma unroll
    for (int i = 0; i < 4; i++)
#pragma unroll
        for (int j = 0; j < 4; j++) {
            f32x4 z = {0.f, 0.f, 0.f, 0.f};
            acc[i][j] = z;
        }

    const int arow = tid >> 1, acol = (tid & 1) * 16;
    const float* aP = A + (long)(m0 + arow) * 512 + acol;
    unsigned short* aD = Asm + arow * 32 + acol;

    const unsigned short* bP0 = Wb + (long)(n0 + (tid >> 2)) * 512 + (tid & 3) * 8;
    const unsigned short* bP1 = bP0 + (long)64 * 512;
    unsigned short* bD0 = Bsm + (tid >> 6) * 512;
    unsigned short* bD1 = bD0 + 4 * 512;

    const int fr = lane & 15, fq = lane >> 4;
    const unsigned short* aF = Asm + (wm * 64 + fr) * 32 + fq * 8;
    const unsigned short* bF = Bsm + (wn * 64 + fr) * 32 + fq * 8;

    for (int k0 = 0; k0 < 512; k0 += 32) {
        load_lds16(bP0 + k0, bD0);
        load_lds16(bP1 + k0, bD1);
        float4 f0 = *(const float4*)(aP + k0 + 0);
        float4 f1 = *(const float4*)(aP + k0 + 4);
        float4 f2 = *(const float4*)(aP + k0 + 8);
        float4 f3 = *(const float4*)(aP + k0 + 12);
        ushort4 u0, u1, u2, u3;
        u0.x = f2bf(f0.x); u0.y = f2bf(f0.y); u0.z = f2bf(f0.z); u0.w = f2bf(f0.w);
        u1.x = f2bf(f1.x); u1.y = f2bf(f1.y); u1.z = f2bf(f1.z); u1.w = f2bf(f1.w);
        u2.x = f2bf(f2.x); u2.y = f2bf(f2.y); u2.z = f2bf(f2.z); u2.w = f2bf(f2.w);
        u3.x = f2bf(f3.x); u3.y = f2bf(f3.y); u3.z = f2bf(f3.z); u3.w = f2bf(f3.w);
        *(ushort4*)(aD + 0)  = u0;
        *(ushort4*)(aD + 4)  = u1;
        *(ushort4*)(aD + 8)  = u2;
        *(ushort4*)(aD + 12) = u3;
        __syncthreads();

        bf16x8 af[4], bfr[4];
#pragma unroll
        for (int i = 0; i < 4; i++) af[i]  = *(const bf16x8*)(aF + i * 16 * 32);
#pragma unroll
        for (int j = 0; j < 4; j++) bfr[j] = *(const bf16x8*)(bF + j * 16 * 32);
#pragma unroll
        for (int i = 0; i < 4; i++)
#pragma unroll
            for (int j = 0; j < 4; j++)
                acc[i][j] = __builtin_amdgcn_mfma_f32_16x16x32_bf16(
                    af[i], bfr[j], acc[i][j], 0, 0, 0);
        __syncthreads();
    }

    const int seg = n0 >> 9;
#pragma unroll
    for (int i = 0; i < 4; i++) {
        int rbase = m0 + wm * 64 + i * 16 + fq * 4;
#pragma unroll
        for (int j = 0; j < 4; j++) {
            int col  = n0 + wn * 64 + j * 16 + fr;
            int nloc = col - seg * 512;
#pragma unroll
            for (int r = 0; r < 4; r++) {
                long m = rbase + r;
                float val = acc[i][j][r];
                if (seg == 0)      qO[m * 512 + nloc] = val;
                else if (seg == 1) kO[m * 512 + nloc] = f2bf(val);
                else               vO[m * 512 + nloc] = f2bf(val);
            }
        }
    }
}

// ---------------------------------------------------------------------------
// Proj MFMA GEMM: d_out[M,512] = Ab[M,512](bf16) @ proj_wb[512,512]^T + bias
// 1D grid 3136 with XCD swizzle; T3-min double-buffer, one barrier per step.
// ---------------------------------------------------------------------------
__global__ __launch_bounds__(256) void mfma_proj(
    const unsigned short* __restrict__ Ab, const unsigned short* __restrict__ Wb,
    const float* __restrict__ bias, float* __restrict__ C)
{
    __shared__ __align__(16) unsigned short Asm[2][128 * 32];
    __shared__ __align__(16) unsigned short Bsm[2][128 * 32];

    const int NWG  = (M_ROWS / 128) * 4;    // 3136, % 8 == 0
    const int PERX = NWG >> 3;              // 392 (= 98 full A-tile groups)
    const int bid = blockIdx.x;
    const int l = (bid & 7) * PERX + (bid >> 3);
    const int m0 = (l >> 2) * 128, n0 = (l & 3) * 128;

    const int tid = threadIdx.x;
    const int lane = tid & 63, wave = tid >> 6;
    const int wm = wave >> 1, wn = wave & 1;

    f32x4 acc[4][4];
#pragma unroll
    for (int i = 0; i < 4; i++)
#pragma unroll
        for (int j = 0; j < 4; j++) {
            f32x4 z = {0.f, 0.f, 0.f, 0.f};
            acc[i][j] = z;
        }

    const unsigned short* aP0 = Ab + (long)(m0 + (tid >> 2)) * 512 + (tid & 3) * 8;
    const unsigned short* aP1 = aP0 + (long)64 * 512;
    const unsigned short* bP0 = Wb + (long)(n0 + (tid >> 2)) * 512 + (tid & 3) * 8;
    const unsigned short* bP1 = bP0 + (long)64 * 512;
    const int stA0 = wave * 512;
    const int stA1 = wave * 512 + 2048;

    const int fr = lane & 15, fq = lane >> 4;
    const int fOff = fq * 8;

    load_lds16(aP0, Asm[0] + stA0);
    load_lds16(aP1, Asm[0] + stA1);
    load_lds16(bP0, Bsm[0] + stA0);
    load_lds16(bP1, Bsm[0] + stA1);
    __syncthreads();

    int cur = 0;
    for (int step = 0; step < 16; ++step) {
        if (step < 15) {
            const int k0 = (step + 1) * 32;
            load_lds16(aP0 + k0, Asm[cur ^ 1] + stA0);
            load_lds16(aP1 + k0, Asm[cur ^ 1] + stA1);
            load_lds16(bP0 + k0, Bsm[cur ^ 1] + stA0);
            load_lds16(bP1 + k0, Bsm[cur ^ 1] + stA1);
        }
        const unsigned short* aF = Asm[cur] + (wm * 64 + fr) * 32 + fOff;
        const unsigned short* bF = Bsm[cur] + (wn * 64 + fr) * 32 + fOff;
        bf16x8 af[4], bfr[4];
#pragma unroll
        for (int i = 0; i < 4; i++) af[i]  = *(const bf16x8*)(aF + i * 16 * 32);
#pragma unroll
        for (int j = 0; j < 4; j++) bfr[j] = *(const bf16x8*)(bF + j * 16 * 32);
#pragma unroll
        for (int i = 0; i < 4; i++)
#pragma unroll
            for (int j = 0; j < 4; j++)
                acc[i][j] = __builtin_amdgcn_mfma_f32_16x16x32_bf16(
                    af[i], bfr[j], acc[i][j], 0, 0, 0);
        __syncthreads();
        cur ^= 1;
    }

#pragma unroll
    for (int i = 0; i < 4; i++) {
        int rbase = m0 + wm * 64 + i * 16 + fq * 4;
#pragma unroll
        for (int j = 0; j < 4; j++) {
            int col = n0 + wn * 64 + j * 16 + fr;
            float bv = bias[col];
#pragma unroll
            for (int r = 0; r < 4; r++)
                C[(long)(rbase + r) * 512 + col] = acc[i][j][r] + bv;
        }
    }
}

// ---------------------------------------------------------------------------
// agent[b,a,c] = mean over 8x8 spatial block of q (q fp32, stride 512)
// ---------------------------------------------------------------------------
__global__ __launch_bounds__(256) void pool_q(
    const float* __restrict__ q, float* __restrict__ agent)
{
    int blk = blockIdx.x;
    int half = blk & 1;
    int a = (blk >> 1) % AGENT_NUM;
    int b = blk / (2 * AGENT_NUM);
    int c = half * 256 + threadIdx.x;
    int pa = a / 7, pb = a % 7;
    const float* base = q + (long)b * N_TOK * 512 + c;
    float s = 0.f;
#pragma unroll
    for (int i = 0; i < 8; i++) {
        int rowbase = (pa * 8 + i) * H_IMG + pb * 8;
#pragma unroll
        for (int j = 0; j < 8; j++)
            s += base[(long)(rowbase + j) * 512];
    }
    agent[((long)b * AGENT_NUM + a) * 512 + c] = s * (1.f / 64.f);
}

// ---------------------------------------------------------------------------
// Agent attention via MFMA, split over n (7 x 448 tokens), flash-style.
// ---------------------------------------------------------------------------
__global__ __launch_bounds__(256) void agent_attn_mfma(
    const unsigned short* __restrict__ kO, const unsigned short* __restrict__ vO,
    const float* __restrict__ agent,
    float* __restrict__ macc, float* __restrict__ mpart, float* __restrict__ lpart)
{
    __shared__ __align__(16) unsigned short Ksm[64 * 64];
    __shared__ __align__(16) unsigned short Vsm[64 * 64];
    __shared__ __align__(16) unsigned short Psm[4 * 16 * 64];

    const int blk = blockIdx.x;            // (b*8+h)*7 + s
    const int s = blk % N_SPLIT;
    const int bh = blk / N_SPLIT;
    const int b = bh >> 3, h = bh & 7;
    const int tid = threadIdx.x;
    const int lane = tid & 63, w = tid >> 6;
    const int fr = lane & 15, fq = lane >> 4;

    // A-fragment in registers: agents 16w+fr (zero-padded), scale folded in.
    bf16x8 afA[2];
    {
        int a = w * 16 + fr;
        const float* ap = agent + ((long)b * AGENT_NUM + a) * 512 + h * 64 + fq * 8;
#pragma unroll
        for (int kk = 0; kk < 2; kk++) {
            union { bf16x8 v; unsigned short u[8]; } cv;
#pragma unroll
            for (int e = 0; e < 8; e++) cv.u[e] = 0;
            if (a < AGENT_NUM) {
                float4 f0 = *(const float4*)(ap + kk * 32);
                float4 f1 = *(const float4*)(ap + kk * 32 + 4);
                cv.u[0] = f2bf(f0.x * SCALE); cv.u[1] = f2bf(f0.y * SCALE);
                cv.u[2] = f2bf(f0.z * SCALE); cv.u[3] = f2bf(f0.w * SCALE);
                cv.u[4] = f2bf(f1.x * SCALE); cv.u[5] = f2bf(f1.y * SCALE);
                cv.u[6] = f2bf(f1.z * SCALE); cv.u[7] = f2bf(f1.w * SCALE);
            }
            afA[kk] = cv.v;
        }
    }

    // staging addresses
    const unsigned short* kg = kO + (long)b * N_TOK * 512 + h * 64;
    const unsigned short* vg = vO + (long)b * N_TOK * 512 + h * 64;
    const int krow = tid >> 2, kcc = tid & 3;
    char* kdst0 = (char*)Ksm + krow * 128 + (((kcc * 2)     ^ (krow & 7)) * 16);
    char* kdst1 = (char*)Ksm + krow * 128 + (((kcc * 2 + 1) ^ (krow & 7)) * 16);
    const int vtp = tid & 31, vd0 = (tid >> 5) * 8;

    // fragment-read swizzled chunk offsets (chunk = kk*4+fq, XOR fr&7)
    const int cs0 = ((fq)     ^ (fr & 7)) * 16;
    const int cs1 = ((4 + fq) ^ (fr & 7)) * 16;
    char* plb = (char*)Psm + w * 2048;     // per-wave P region [16][64] bf16

    f32x4 accO[4];
#pragma unroll
    for (int dj = 0; dj < 4; dj++) {
        f32x4 z = {0.f, 0.f, 0.f, 0.f};
        accO[dj] = z;
    }
    float m_a = -1e30f, l_a = 0.f;

    const int nstart = s * (N_TOK / N_SPLIT);
    for (int t = 0; t < 7; t++) {
        const int n0 = nstart + t * 64;
        __syncthreads();   // previous tile fully consumed
        {   // stage K: [64 tok][64 d], swizzled chunks
            const unsigned short* src = kg + (long)(n0 + krow) * 512 + kcc * 16;
            u32x4 d0 = *(const u32x4*)(src);
            u32x4 d1 = *(const u32x4*)(src + 8);
            *(u32x4*)kdst0 = d0;
            *(u32x4*)kdst1 = d1;
        }
        {   // stage V transposed: Vt[d][tok], b32 holds tok pair (2tp,2tp+1)
            const unsigned short* sv = vg + (long)(n0 + vtp * 2) * 512 + vd0;
            u16x8 v0 = *(const u16x8*)(sv);
            u16x8 v1 = *(const u16x8*)(sv + 512);
#pragma unroll
            for (int j = 0; j < 8; j++) {
                unsigned int val = (unsigned int)v0[j] | ((unsigned int)v1[j] << 16);
                *(unsigned int*)((char*)Vsm + (vd0 + j) * 128
                                 + (((vtp >> 2) ^ j) * 16) + (vtp & 3) * 4) = val;
            }
        }
        __syncthreads();

        // S^T = K·A^T : rows = toks (it*16 + fq*4 + r), col = agent 16w+fr
        f32x4 sacc[4];
#pragma unroll
        for (int it = 0; it < 4; it++) {
            f32x4 z = {0.f, 0.f, 0.f, 0.f};
            sacc[it] = z;
        }
#pragma unroll
        for (int it = 0; it < 4; it++) {
            bf16x8 kf0 = *(const bf16x8*)((char*)Ksm + it * 2048 + fr * 128 + cs0);
            bf16x8 kf1 = *(const bf16x8*)((char*)Ksm + it * 2048 + fr * 128 + cs1);
            sacc[it] = __builtin_amdgcn_mfma_f32_16x16x32_bf16(kf0, afA[0], sacc[it], 0, 0, 0);
            sacc[it] = __builtin_amdgcn_mfma_f32_16x16x32_bf16(kf1, afA[1], sacc[it], 0, 0, 0);
        }

        // online softmax per agent (lane-local col; reduce across fq groups)
        float mloc = -1e30f;
#pragma unroll
        for (int it = 0; it < 4; it++)
#pragma unroll
            for (int r = 0; r < 4; r++) mloc = fmaxf(mloc, sacc[it][r]);
        mloc = fmaxf(mloc, __shfl_xor(mloc, 16));
        mloc = fmaxf(mloc, __shfl_xor(mloc, 32));
        float mnew = fmaxf(m_a, mloc);
        float alpha = __expf(m_a - mnew);
        float p[4][4];
        float ss = 0.f;
#pragma unroll
        for (int it = 0; it < 4; it++)
#pragma unroll
            for (int r = 0; r < 4; r++) {
                float pv = __expf(sacc[it][r] - mnew);
                p[it][r] = pv;
                ss += pv;
            }
        ss += __shfl_xor(ss, 16);
        ss += __shfl_xor(ss, 32);
        l_a = l_a * alpha + ss;
        m_a = mnew;

        // P^T -> bf16 per-wave LDS: row = agent fr, tok = it*16 + fq*4 + 2pr+{0,1}
#pragma unroll
        for (int it = 0; it < 4; it++)
#pragma unroll
            for (int pr = 0; pr < 2; pr++) {
                unsigned int u = (unsigned int)f2bf(p[it][pr * 2])
                               | ((unsigned int)f2bf(p[it][pr * 2 + 1]) << 16);
                *(unsigned int*)(plb + fr * 128
                    + (((it * 2 + (fq >> 1)) ^ (fr & 7)) * 16)
                    + (fq & 1) * 8 + pr * 4) = u;
            }

        // rescale O: O rows are agents fq*4+r; alpha lives at lane fr=fq*4+r
        float alr[4];
#pragma unroll
        for (int r = 0; r < 4; r++)
            alr[r] = __shfl(alpha, ((lane >> 4) << 2) + r);
#pragma unroll
        for (int dj = 0; dj < 4; dj++)
#pragma unroll
            for (int r = 0; r < 4; r++) accO[dj][r] *= alr[r];

        // PV: O[agent, d] += P[agent, tok] · Vt[d, tok]
        bf16x8 pf0 = *(const bf16x8*)(plb + fr * 128 + cs0);
        bf16x8 pf1 = *(const bf16x8*)(plb + fr * 128 + cs1);
#pragma unroll
        for (int dj = 0; dj < 4; dj++) {
            bf16x8 vf0 = *(const bf16x8*)((char*)Vsm + dj * 2048 + fr * 128 + cs0);
            bf16x8 vf1 = *(const bf16x8*)((char*)Vsm + dj * 2048 + fr * 128 + cs1);
            accO[dj] = __builtin_amdgcn_mfma_f32_16x16x32_bf16(pf0, vf0, accO[dj], 0, 0, 0);
            accO[dj] = __builtin_amdgcn_mfma_f32_16x16x32_bf16(pf1, vf1, accO[dj], 0, 0, 0);
        }
    }

    // epilogue: partials (unnormalized acc + m,l per agent)
    float* mob = macc + (long)blk * (AGENT_NUM * 64);
#pragma unroll
    for (int dj = 0; dj < 4; dj++)
#pragma unroll
        for (int r = 0; r < 4; r++) {
            int a = w * 16 + fq * 4 + r;
            if (a < AGENT_NUM)
                mob[a * 64 + dj * 16 + fr] = accO[dj][r];
        }
    if (fq == 0) {
        int a = w * 16 + fr;
        if (a < AGENT_NUM) {
            mpart[(long)blk * AGENT_NUM + a] = m_a;
            lpart[(long)blk * AGENT_NUM + a] = l_a;
        }
    }
}

// Combine the N_SPLIT partials -> agent_v[b,h,a,d]
__global__ __launch_bounds__(256) void agent_attn_combine(
    const float* __restrict__ macc, const float* __restrict__ mpart,
    const float* __restrict__ lpart, float* __restrict__ agent_v)
{
    int bh = blockIdx.x;               // 0..255
    int tid = threadIdx.x;
    __shared__ float E[AGENT_NUM * N_SPLIT];
    __shared__ float Linv[AGENT_NUM];

    if (tid < AGENT_NUM) {
        float mx = -1e30f;
        for (int s = 0; s < N_SPLIT; s++)
            mx = fmaxf(mx, mpart[((long)bh * N_SPLIT + s) * AGENT_NUM + tid]);
        float l = 0.f;
        for (int s = 0; s < N_SPLIT; s++) {
            float e = __expf(mpart[((long)bh * N_SPLIT + s) * AGENT_NUM + tid] - mx);
            E[tid * N_SPLIT + s] = e;
            l += e * lpart[((long)bh * N_SPLIT + s) * AGENT_NUM + tid];
        }
        Linv[tid] = 1.f / l;
    }
    __syncthreads();

    for (int idx = tid; idx < AGENT_NUM * 64; idx += 256) {
        int a = idx >> 6;
        float acc = 0.f;
        for (int s = 0; s < N_SPLIT; s++)
            acc += E[a * N_SPLIT + s] *
                   macc[((long)bh * N_SPLIT + s) * (AGENT_NUM * 64) + idx];
        agent_v[(long)bh * (AGENT_NUM * 64) + idx] = acc * Linv[a];
    }
}

// ---------------------------------------------------------------------------
// q attention, IN-PLACE on d_out (q fp32): each (n, h-slice) owned by 1 thread
// ---------------------------------------------------------------------------
__global__ __launch_bounds__(256) void q_attn(
    float* __restrict__ q, const float* __restrict__ agent,
    const float* __restrict__ agent_v)
{
    int chunk = blockIdx.x, h = blockIdx.y, b = blockIdx.z;
    int tid = threadIdx.x;

    __shared__ float ah[AGENT_NUM * 64];
    __shared__ float av[AGENT_NUM * 64];
    for (int idx = tid; idx < AGENT_NUM * 64; idx += 256) {
        int a = idx >> 6, d = idx & 63;
        ah[idx] = agent[((long)b * AGENT_NUM + a) * 512 + h * 64 + d];
        av[idx] = agent_v[((long)b * 8 + h) * (AGENT_NUM * 64) + idx];
    }
    __syncthreads();

    int n = chunk * 256 + tid;
    if (n >= N_TOK) return;

    float* qrow = q + ((long)b * N_TOK + n) * 512 + h * 64;
    float4 q4[16];
#pragma unroll
    for (int i = 0; i < 16; i++) q4[i] = *(float4*)(qrow + i * 4);

    float sc[AGENT_NUM];
#pragma unroll
    for (int a = 0; a < AGENT_NUM; a++) {
        const float* ap = ah + a * 64;
        float s = 0.f;
#pragma unroll
        for (int i = 0; i < 16; i++) {
            s += q4[i].x * ap[i * 4 + 0] + q4[i].y * ap[i * 4 + 1]
               + q4[i].z * ap[i * 4 + 2] + q4[i].w * ap[i * 4 + 3];
        }
        sc[a] = s * SCALE;
    }
    float mx = sc[0];
#pragma unroll
    for (int a = 1; a < AGENT_NUM; a++) mx = fmaxf(mx, sc[a]);
    float sum = 0.f;
#pragma unroll
    for (int a = 0; a < AGENT_NUM; a++) { sc[a] = __expf(sc[a] - mx); sum += sc[a]; }
    float inv = 1.f / sum;

#pragma unroll
    for (int d4 = 0; d4 < 16; d4++) {
        float4 o = make_float4(0.f, 0.f, 0.f, 0.f);
#pragma unroll
        for (int a = 0; a < AGENT_NUM; a++) {
            float p = sc[a];
            const float* vp = av + a * 64 + d4 * 4;
            o.x += p * vp[0]; o.y += p * vp[1];
            o.z += p * vp[2]; o.w += p * vp[3];
        }
        o.x *= inv; o.y *= inv; o.z *= inv; o.w *= inv;
        *(float4*)(qrow + d4 * 4) = o;
    }
}

// ---------------------------------------------------------------------------
// Fused: depthwise 3x3 conv on v (bf16) + bias + attn(d_out fp32) add,
// RNE-cast to bf16 proj input. One thread = 8 contiguous channels.
// ---------------------------------------------------------------------------
__global__ __launch_bounds__(256) void dwc_fuse(
    const unsigned short* __restrict__ vO, const float* __restrict__ w,
    const float* __restrict__ bias, const float* __restrict__ attn,
    unsigned short* __restrict__ outb)
{
    __shared__ float ws2[64 * 73];
    for (int i = threadIdx.x; i < 512 * 9; i += 256) {
        int c = i / 9, k = i - c * 9;
        ws2[(c >> 3) * 73 + k * 8 + (c & 7)] = w[i];
    }
    __syncthreads();

    long flat = (long)blockIdx.x * 256 + threadIdx.x;  // over M_ROWS*64
    int cg = (int)(flat & 63);
    int c8 = cg << 3;
    long row = flat >> 6;                              // b*N_TOK + n
    int n = (int)(row % N_TOK);
    int b = (int)(row / N_TOK);
    int y = n / H_IMG, x = n - y * H_IMG;

    const unsigned short* vb = vO + (long)b * N_TOK * 512 + c8;
    const float* wb = ws2 + cg * 73;

    float acc[8];
    float4 bv0 = *(const float4*)(bias + c8);
    float4 bv1 = *(const float4*)(bias + c8 + 4);
    acc[0] = bv0.x; acc[1] = bv0.y; acc[2] = bv0.z; acc[3] = bv0.w;
    acc[4] = bv1.x; acc[5] = bv1.y; acc[6] = bv1.z; acc[7] = bv1.w;

#pragma unroll
    for (int dy = 0; dy < 3; dy++) {
        int yy = y + dy - 1;
        if (yy < 0 || yy >= H_IMG) continue;
#pragma unroll
        for (int dx = 0; dx < 3; dx++) {
            int xx = x + dx - 1;
            if (xx < 0 || xx >= H_IMG) continue;
            const unsigned short* vp = vb + (long)(yy * H_IMG + xx) * 512;
            ushort4 u0 = *(const ushort4*)(vp);
            ushort4 u1 = *(const ushort4*)(vp + 4);
            const float* wk = wb + (dy * 3 + dx) * 8;
            acc[0] += wk[0] * bf2f(u0.x);
            acc[1] += wk[1] * bf2f(u0.y);
            acc[2] += wk[2] * bf2f(u0.z);
            acc[3] += wk[3] * bf2f(u0.w);
            acc[4] += wk[4] * bf2f(u1.x);
            acc[5] += wk[5] * bf2f(u1.y);
            acc[6] += wk[6] * bf2f(u1.z);
            acc[7] += wk[7] * bf2f(u1.w);
        }
    }

    const float* ap = attn + row * 512 + c8;
    float4 a0 = *(const float4*)(ap);
    float4 a1 = *(const float4*)(ap + 4);
    ushort4 o0, o1;
    o0.x = f2bf(a0.x + acc[0]); o0.y = f2bf(a0.y + acc[1]);
    o0.z = f2bf(a0.z + acc[2]); o0.w = f2bf(a0.w + acc[3]);
    o1.x = f2bf(a1.x + acc[4]); o1.y = f2bf(a1.y + acc[5]);
    o1.z = f2bf(a1.z + acc[6]); o1.w = f2bf(a1.w + acc[7]);

    unsigned short* op = outb + row * 512 + c8;
    *(ushort4*)(op)     = o0;
    *(ushort4*)(op + 4) = o1;
}

// ---------------------------------------------------------------------------
extern "C" void kernel_launch(void* const* d_in, const int* in_sizes, int n_in,
                              void* d_out, int out_size, void* d_ws, size_t ws_size,
                              hipStream_t stream)
{
    const float* x      = (const float*)d_in[0];
    const float* qkv_w  = (const float*)d_in[1];
    const float* proj_w = (const float*)d_in[2];
    const float* proj_b = (const float*)d_in[3];
    const float* dwc_w  = (const float*)d_in[4];
    const float* dwc_b  = (const float*)d_in[5];
    float* out = (float*)d_out;

    const long KV_ELEMS    = (long)M_ROWS * 512;                  // 51,380,224
    const long QKVW_ELEMS  = 1536L * 512;                         // 786,432
    const long PROJW_ELEMS = 512L * 512;                          // 262,144
    const long AGENT_ELEMS = (long)B_SZ * AGENT_NUM * 512;
    const long AV_ELEMS    = (long)B_SZ * 8 * AGENT_NUM * 64;
    const long MACC_ELEMS  = (long)B_SZ * 8 * N_SPLIT * AGENT_NUM * 64;
    const long ML_ELEMS    = (long)B_SZ * 8 * N_SPLIT * AGENT_NUM;

    unsigned short* kbuf    = (unsigned short*)d_ws;   // reused as proj-A later
    unsigned short* vbuf    = kbuf + KV_ELEMS;
    unsigned short* qkv_wb  = vbuf + KV_ELEMS;
    unsigned short* proj_wb = qkv_wb + QKVW_ELEMS;
    float* agent   = (float*)(proj_wb + PROJW_ELEMS);
    float* agent_v = agent + AGENT_ELEMS;
    float* macc    = agent_v + AV_ELEMS;
    float* mpart   = macc + MACC_ELEMS;
    float* lpart   = mpart + ML_ELEMS;
    unsigned short* xb = (unsigned short*)(lpart + ML_ELEMS);   // bf16 copy of x

    size_t need_old = (size_t)(2 * KV_ELEMS + QKVW_ELEMS + PROJW_ELEMS) * 2
                    + (size_t)(AGENT_ELEMS + AV_ELEMS + MACC_ELEMS + 2 * ML_ELEMS) * 4;
    size_t need_new = need_old + (size_t)KV_ELEMS * 2;
    if (ws_size < need_old) return;
    const bool precast = (ws_size >= need_new);

    // 0. cast weights to bf16
    cast_f32_bf16<<<(unsigned)(QKVW_ELEMS / 1024), 256, 0, stream>>>(qkv_w, qkv_wb);
    cast_f32_bf16<<<(unsigned)(PROJW_ELEMS / 1024), 256, 0, stream>>>(proj_w, proj_wb);

    // 1. qkv GEMM: q -> d_out (fp32), k,v -> ws (bf16)
    if (precast) {
        cast_f32_bf16<<<(unsigned)(KV_ELEMS / 1024), 256, 0, stream>>>(x, xb);
        mfma_qkv_bf<<<(M_ROWS / 128) * 12, 256, 0, stream>>>(
            xb, qkv_wb, out, kbuf, vbuf);
    } else {
        mfma_qkv<<<dim3(M_ROWS / 128, 12), 256, 0, stream>>>(
            x, qkv_wb, out, kbuf, vbuf);
    }

    // 2. agent = 7x7 pool of q
    pool_q<<<B_SZ * AGENT_NUM * 2, 256, 0, stream>>>(out, agent);

    // 3. agent attention (MFMA split + combine) -> agent_v
    agent_attn_mfma<<<B_SZ * 8 * N_SPLIT, 256, 0, stream>>>(
        kbuf, vbuf, agent, macc, mpart, lpart);
    agent_attn_combine<<<B_SZ * 8, 256, 0, stream>>>(macc, mpart, lpart, agent_v);

    // 4. q attention, in-place on d_out
    q_attn<<<dim3((N_TOK + 255) / 256, 8, B_SZ), 256, 0, stream>>>(out, agent, agent_v);

    // 5. fused dwc + attn-add + bf16 cast -> kbuf (k dead now)
    dwc_fuse<<<(unsigned)((long)M_ROWS * 64 / 256), 256, 0, stream>>>(
        vbuf, dwc_w, dwc_b, out, kbuf);

    // 6. final projection (bf16 MFMA, fp32 epilogue + bias)
    mfma_proj<<<(M_ROWS / 128) * 4, 256, 0, stream>>>(kbuf, proj_wb, proj_b, out);
}

// Round 5
// 1144.743 us; speedup vs baseline: 1.7792x; 1.1098x over previous
//
#include <hip/hip_runtime.h>

#define B_SZ 32
#define N_TOK 3136
#define C_DIM 512
#define H_IMG 56
#define NUM_HEADS 8
#define HEAD_DIM 64
#define AGENT_NUM 49
#define SCALE 0.125f
#define M_ROWS (B_SZ * N_TOK)        // 100352
#define N_SPLIT 7                    // agent-attn n-splits (448 tokens each)

typedef __bf16 bf16x8 __attribute__((ext_vector_type(8)));
typedef float f32x4 __attribute__((ext_vector_type(4)));
typedef unsigned short u16x8 __attribute__((ext_vector_type(8)));
typedef unsigned int u32x4 __attribute__((ext_vector_type(4)));

static __device__ __forceinline__ unsigned short f2bf(float f) {
    unsigned int u = __float_as_uint(f);
    unsigned int r = (u + 0x7fffu + ((u >> 16) & 1u)) >> 16;   // RNE
    return (unsigned short)r;
}
static __device__ __forceinline__ float bf2f(unsigned short u) {
    return __uint_as_float(((unsigned int)u) << 16);
}
// async global->LDS, 16B per lane; lds dest must be wave-uniform (HW: base + lane*16)
static __device__ __forceinline__ void load_lds16(const unsigned short* g, unsigned short* l) {
    __builtin_amdgcn_global_load_lds(
        (const __attribute__((address_space(1))) unsigned int*)g,
        (__attribute__((address_space(3))) unsigned int*)l, 16, 0, 0);
}

// generic fp32 -> bf16 cast, count must be multiple of 1024
__global__ __launch_bounds__(256) void cast_f32_bf16(
    const float* __restrict__ in, unsigned short* __restrict__ out)
{
    long i = (long)blockIdx.x * 256 + threadIdx.x;   // float4 index
    float4 f = ((const float4*)in)[i];
    ushort4 u;
    u.x = f2bf(f.x); u.y = f2bf(f.y); u.z = f2bf(f.z); u.w = f2bf(f.w);
    ((ushort4*)out)[i] = u;
}

// ---------------------------------------------------------------------------
// QKV MFMA GEMM (bf16): [M,1536] = xb[M,512] @ qkv_wb[1536,512]^T
// 128x128 tile, BK=32, 4 waves. 1D grid 9408 with bijective XCD swizzle so
// the 12 n-blocks sharing an A-tile run on ONE XCD (A fetched ~once).
// T3-min double-buffer: stage(next) -> compute(cur) -> one barrier per step.
// q (cols 0:512) -> fp32 d_out;  k,v -> bf16 ws.
// ---------------------------------------------------------------------------
__global__ __launch_bounds__(256) void mfma_qkv_bf(
    const unsigned short* __restrict__ Ab, const unsigned short* __restrict__ Wb,
    float* __restrict__ qO, unsigned short* __restrict__ kO,
    unsigned short* __restrict__ vO)
{
    __shared__ __align__(16) unsigned short Asm[2][128 * 32];
    __shared__ __align__(16) unsigned short Bsm[2][128 * 32];

    const int NWG  = (M_ROWS / 128) * 12;   // 9408, % 8 == 0
    const int PERX = NWG >> 3;              // 1176 (= 98 full A-tile groups)
    const int bid = blockIdx.x;
    const int l = (bid & 7) * PERX + (bid >> 3);   // bijective XCD swizzle
    const int m0 = (l / 12) * 128, n0 = (l % 12) * 128;

    const int tid = threadIdx.x;
    const int lane = tid & 63, wave = tid >> 6;
    const int wm = wave >> 1, wn = wave & 1;

    f32x4 acc[4][4];
#pragma unroll
    for (int i = 0; i < 4; i++)
#pragma unroll
        for (int j = 0; j < 4; j++) {
            f32x4 z = {0.f, 0.f, 0.f, 0.f};
            acc[i][j] = z;
        }

    const unsigned short* aP0 = Ab + (long)(m0 + (tid >> 2)) * 512 + (tid & 3) * 8;
    const unsigned short* aP1 = aP0 + (long)64 * 512;
    const unsigned short* bP0 = Wb + (long)(n0 + (tid >> 2)) * 512 + (tid & 3) * 8;
    const unsigned short* bP1 = bP0 + (long)64 * 512;
    const int stA0 = wave * 512;            // wave-uniform stage offsets
    const int stA1 = wave * 512 + 2048;

    const int fr = lane & 15, fq = lane >> 4;
    const int fOff = fq * 8;

    // prologue: stage K-step 0 into buf 0
    load_lds16(aP0, Asm[0] + stA0);
    load_lds16(aP1, Asm[0] + stA1);
    load_lds16(bP0, Bsm[0] + stA0);
    load_lds16(bP1, Bsm[0] + stA1);
    __syncthreads();

    int cur = 0;
    for (int step = 0; step < 16; ++step) {
        if (step < 15) {                    // issue next tile early (flies under MFMA)
            const int k0 = (step + 1) * 32;
            load_lds16(aP0 + k0, Asm[cur ^ 1] + stA0);
            load_lds16(aP1 + k0, Asm[cur ^ 1] + stA1);
            load_lds16(bP0 + k0, Bsm[cur ^ 1] + stA0);
            load_lds16(bP1 + k0, Bsm[cur ^ 1] + stA1);
        }
        const unsigned short* aF = Asm[cur] + (wm * 64 + fr) * 32 + fOff;
        const unsigned short* bF = Bsm[cur] + (wn * 64 + fr) * 32 + fOff;
        bf16x8 af[4], bfr[4];
#pragma unroll
        for (int i = 0; i < 4; i++) af[i]  = *(const bf16x8*)(aF + i * 16 * 32);
#pragma unroll
        for (int j = 0; j < 4; j++) bfr[j] = *(const bf16x8*)(bF + j * 16 * 32);
#pragma unroll
        for (int i = 0; i < 4; i++)
#pragma unroll
            for (int j = 0; j < 4; j++)
                acc[i][j] = __builtin_amdgcn_mfma_f32_16x16x32_bf16(
                    af[i], bfr[j], acc[i][j], 0, 0, 0);
        __syncthreads();                    // drains vmcnt(0)+lgkmcnt(0): next buf ready
        cur ^= 1;
    }

    // epilogue: C/D layout col=lane&15, row=(lane>>4)*4+reg
    const int seg = n0 >> 9;   // 0=q,1=k,2=v (block never straddles: 128|512)
#pragma unroll
    for (int i = 0; i < 4; i++) {
        int rbase = m0 + wm * 64 + i * 16 + fq * 4;
#pragma unroll
        for (int j = 0; j < 4; j++) {
            int col  = n0 + wn * 64 + j * 16 + fr;
            int nloc = col - seg * 512;
#pragma unroll
            for (int r = 0; r < 4; r++) {
                long m = rbase + r;
                float val = acc[i][j][r];
                if (seg == 0)      qO[m * 512 + nloc] = val;
                else if (seg == 1) kO[m * 512 + nloc] = f2bf(val);
                else               vO[m * 512 + nloc] = f2bf(val);
            }
        }
    }
}

// ---------------------------------------------------------------------------
// Fallback QKV GEMM (fp32 A, cast in staging) — used if workspace too small
// for the bf16 x copy.
// ---------------------------------------------------------------------------
__global__ __launch_bounds__(256) void mfma_qkv(
    const float* __restrict__ A, const unsigned short* __restrict__ Wb,
    float* __restrict__ qO, unsigned short* __restrict__ kO,
    unsigned short* __restrict__ vO)
{
    __shared__ __align__(16) unsigned short Asm[128 * 32];
    __shared__ __align__(16) unsigned short Bsm[128 * 32];

    const int m0 = blockIdx.x * 128, n0 = blockIdx.y * 128;
    const int tid = threadIdx.x;
    const int lane = tid & 63, wave = tid >> 6;
    const int wm = wave >> 1, wn = wave & 1;

    f32x4 acc[4][4];
#pragma unroll
    for (int i = 0; i < 4; i++)
#pragma unroll
        for (int j = 0; j < 4; j++) {
            f32x4 z = {0.f, 0.f, 0.f, 0.f};
            acc[i][j] = z;
        }

    const int arow = tid >> 1, acol = (tid & 1) * 16;
    const float* aP = A + (long)(m0 + arow) * 512 + acol;
    unsigned short* aD = Asm + arow * 32 + acol;

    const unsigned short* bP0 = Wb + (long)(n0 + (tid >> 2)) * 512 + (tid & 3) * 8;
    const unsigned short* bP1 = bP0 + (long)64 * 512;
    unsigned short* bD0 = Bsm + (tid >> 6) * 512;
    unsigned short* bD1 = bD0 + 4 * 512;

    const int fr = lane & 15, fq = lane >> 4;
    const unsigned short* aF = Asm + (wm * 64 + fr) * 32 + fq * 8;
    const unsigned short* bF = Bsm + (wn * 64 + fr) * 32 + fq * 8;

    for (int k0 = 0; k0 < 512; k0 += 32) {
        load_lds16(bP0 + k0, bD0);
        load_lds16(bP1 + k0, bD1);
        float4 f0 = *(const float4*)(aP + k0 + 0);
        float4 f1 = *(const float4*)(aP + k0 + 4);
        float4 f2 = *(const float4*)(aP + k0 + 8);
        float4 f3 = *(const float4*)(aP + k0 + 12);
        ushort4 u0, u1, u2, u3;
        u0.x = f2bf(f0.x); u0.y = f2bf(f0.y); u0.z = f2bf(f0.z); u0.w = f2bf(f0.w);
        u1.x = f2bf(f1.x); u1.y = f2bf(f1.y); u1.z = f2bf(f1.z); u1.w = f2bf(f1.w);
        u2.x = f2bf(f2.x); u2.y = f2bf(f2.y); u2.z = f2bf(f2.z); u2.w = f2bf(f2.w);
        u3.x = f2bf(f3.x); u3.y = f2bf(f3.y); u3.z = f2bf(f3.z); u3.w = f2bf(f3.w);
        *(ushort4*)(aD + 0)  = u0;
        *(ushort4*)(aD + 4)  = u1;
        *(ushort4*)(aD + 8)  = u2;
        *(ushort4*)(aD + 12) = u3;
        __syncthreads();

        bf16x8 af[4], bfr[4];
#pragma unroll
        for (int i = 0; i < 4; i++) af[i]  = *(const bf16x8*)(aF + i * 16 * 32);
#pragma unroll
        for (int j = 0; j < 4; j++) bfr[j] = *(const bf16x8*)(bF + j * 16 * 32);
#pragma unroll
        for (int i = 0; i < 4; i++)
#pragma unroll
            for (int j = 0; j < 4; j++)
                acc[i][j] = __builtin_amdgcn_mfma_f32_16x16x32_bf16(
                    af[i], bfr[j], acc[i][j], 0, 0, 0);
        __syncthreads();
    }

    const int seg = n0 >> 9;
#pragma unroll
    for (int i = 0; i < 4; i++) {
        int rbase = m0 + wm * 64 + i * 16 + fq * 4;
#pragma unroll
        for (int j = 0; j < 4; j++) {
            int col  = n0 + wn * 64 + j * 16 + fr;
            int nloc = col - seg * 512;
#pragma unroll
            for (int r = 0; r < 4; r++) {
                long m = rbase + r;
                float val = acc[i][j][r];
                if (seg == 0)      qO[m * 512 + nloc] = val;
                else if (seg == 1) kO[m * 512 + nloc] = f2bf(val);
                else               vO[m * 512 + nloc] = f2bf(val);
            }
        }
    }
}

// ---------------------------------------------------------------------------
// Proj MFMA GEMM: d_out[M,512] = Ab[M,512](bf16) @ proj_wb[512,512]^T + bias
// 1D grid 3136 with XCD swizzle; T3-min double-buffer, one barrier per step.
// ---------------------------------------------------------------------------
__global__ __launch_bounds__(256) void mfma_proj(
    const unsigned short* __restrict__ Ab, const unsigned short* __restrict__ Wb,
    const float* __restrict__ bias, float* __restrict__ C)
{
    __shared__ __align__(16) unsigned short Asm[2][128 * 32];
    __shared__ __align__(16) unsigned short Bsm[2][128 * 32];

    const int NWG  = (M_ROWS / 128) * 4;    // 3136, % 8 == 0
    const int PERX = NWG >> 3;              // 392 (= 98 full A-tile groups)
    const int bid = blockIdx.x;
    const int l = (bid & 7) * PERX + (bid >> 3);
    const int m0 = (l >> 2) * 128, n0 = (l & 3) * 128;

    const int tid = threadIdx.x;
    const int lane = tid & 63, wave = tid >> 6;
    const int wm = wave >> 1, wn = wave & 1;

    f32x4 acc[4][4];
#pragma unroll
    for (int i = 0; i < 4; i++)
#pragma unroll
        for (int j = 0; j < 4; j++) {
            f32x4 z = {0.f, 0.f, 0.f, 0.f};
            acc[i][j] = z;
        }

    const unsigned short* aP0 = Ab + (long)(m0 + (tid >> 2)) * 512 + (tid & 3) * 8;
    const unsigned short* aP1 = aP0 + (long)64 * 512;
    const unsigned short* bP0 = Wb + (long)(n0 + (tid >> 2)) * 512 + (tid & 3) * 8;
    const unsigned short* bP1 = bP0 + (long)64 * 512;
    const int stA0 = wave * 512;
    const int stA1 = wave * 512 + 2048;

    const int fr = lane & 15, fq = lane >> 4;
    const int fOff = fq * 8;

    load_lds16(aP0, Asm[0] + stA0);
    load_lds16(aP1, Asm[0] + stA1);
    load_lds16(bP0, Bsm[0] + stA0);
    load_lds16(bP1, Bsm[0] + stA1);
    __syncthreads();

    int cur = 0;
    for (int step = 0; step < 16; ++step) {
        if (step < 15) {
            const int k0 = (step + 1) * 32;
            load_lds16(aP0 + k0, Asm[cur ^ 1] + stA0);
            load_lds16(aP1 + k0, Asm[cur ^ 1] + stA1);
            load_lds16(bP0 + k0, Bsm[cur ^ 1] + stA0);
            load_lds16(bP1 + k0, Bsm[cur ^ 1] + stA1);
        }
        const unsigned short* aF = Asm[cur] + (wm * 64 + fr) * 32 + fOff;
        const unsigned short* bF = Bsm[cur] + (wn * 64 + fr) * 32 + fOff;
        bf16x8 af[4], bfr[4];
#pragma unroll
        for (int i = 0; i < 4; i++) af[i]  = *(const bf16x8*)(aF + i * 16 * 32);
#pragma unroll
        for (int j = 0; j < 4; j++) bfr[j] = *(const bf16x8*)(bF + j * 16 * 32);
#pragma unroll
        for (int i = 0; i < 4; i++)
#pragma unroll
            for (int j = 0; j < 4; j++)
                acc[i][j] = __builtin_amdgcn_mfma_f32_16x16x32_bf16(
                    af[i], bfr[j], acc[i][j], 0, 0, 0);
        __syncthreads();
        cur ^= 1;
    }

#pragma unroll
    for (int i = 0; i < 4; i++) {
        int rbase = m0 + wm * 64 + i * 16 + fq * 4;
#pragma unroll
        for (int j = 0; j < 4; j++) {
            int col = n0 + wn * 64 + j * 16 + fr;
            float bv = bias[col];
#pragma unroll
            for (int r = 0; r < 4; r++)
                C[(long)(rbase + r) * 512 + col] = acc[i][j][r] + bv;
        }
    }
}

// ---------------------------------------------------------------------------
// agent[b,a,c] = mean over 8x8 spatial block of q (q fp32, stride 512)
// ---------------------------------------------------------------------------
__global__ __launch_bounds__(256) void pool_q(
    const float* __restrict__ q, float* __restrict__ agent)
{
    int blk = blockIdx.x;
    int half = blk & 1;
    int a = (blk >> 1) % AGENT_NUM;
    int b = blk / (2 * AGENT_NUM);
    int c = half * 256 + threadIdx.x;
    int pa = a / 7, pb = a % 7;
    const float* base = q + (long)b * N_TOK * 512 + c;
    float s = 0.f;
#pragma unroll
    for (int i = 0; i < 8; i++) {
        int rowbase = (pa * 8 + i) * H_IMG + pb * 8;
#pragma unroll
        for (int j = 0; j < 8; j++)
            s += base[(long)(rowbase + j) * 512];
    }
    agent[((long)b * AGENT_NUM + a) * 512 + c] = s * (1.f / 64.f);
}

// ---------------------------------------------------------------------------
// Agent attention via MFMA, split over n (7 x 448 tokens), flash-style.
// ---------------------------------------------------------------------------
__global__ __launch_bounds__(256) void agent_attn_mfma(
    const unsigned short* __restrict__ kO, const unsigned short* __restrict__ vO,
    const float* __restrict__ agent,
    float* __restrict__ macc, float* __restrict__ mpart, float* __restrict__ lpart)
{
    __shared__ __align__(16) unsigned short Ksm[64 * 64];
    __shared__ __align__(16) unsigned short Vsm[64 * 64];
    __shared__ __align__(16) unsigned short Psm[4 * 16 * 64];

    const int blk = blockIdx.x;            // (b*8+h)*7 + s
    const int s = blk % N_SPLIT;
    const int bh = blk / N_SPLIT;
    const int b = bh >> 3, h = bh & 7;
    const int tid = threadIdx.x;
    const int lane = tid & 63, w = tid >> 6;
    const int fr = lane & 15, fq = lane >> 4;

    // A-fragment in registers: agents 16w+fr (zero-padded), scale folded in.
    bf16x8 afA[2];
    {
        int a = w * 16 + fr;
#pragma unroll
        for (int kk = 0; kk < 2; kk++) {
            union { bf16x8 v; unsigned short u[8]; } cv;
#pragma unroll
            for (int e = 0; e < 8; e++) cv.u[e] = 0;
            if (a < AGENT_NUM) {
                const float* ap = agent + ((long)b * AGENT_NUM + a) * 512 + h * 64 + fq * 8;
                float4 f0 = *(const float4*)(ap + kk * 32);
                float4 f1 = *(const float4*)(ap + kk * 32 + 4);
                cv.u[0] = f2bf(f0.x * SCALE); cv.u[1] = f2bf(f0.y * SCALE);
                cv.u[2] = f2bf(f0.z * SCALE); cv.u[3] = f2bf(f0.w * SCALE);
                cv.u[4] = f2bf(f1.x * SCALE); cv.u[5] = f2bf(f1.y * SCALE);
                cv.u[6] = f2bf(f1.z * SCALE); cv.u[7] = f2bf(f1.w * SCALE);
            }
            afA[kk] = cv.v;
        }
    }

    // staging addresses
    const unsigned short* kg = kO + (long)b * N_TOK * 512 + h * 64;
    const unsigned short* vg = vO + (long)b * N_TOK * 512 + h * 64;
    const int krow = tid >> 2, kcc = tid & 3;
    char* kdst0 = (char*)Ksm + krow * 128 + (((kcc * 2)     ^ (krow & 7)) * 16);
    char* kdst1 = (char*)Ksm + krow * 128 + (((kcc * 2 + 1) ^ (krow & 7)) * 16);
    const int vtp = tid & 31, vd0 = (tid >> 5) * 8;

    // fragment-read swizzled chunk offsets (chunk = kk*4+fq, XOR fr&7)
    const int cs0 = ((fq)     ^ (fr & 7)) * 16;
    const int cs1 = ((4 + fq) ^ (fr & 7)) * 16;
    char* plb = (char*)Psm + w * 2048;     // per-wave P region [16][64] bf16

    f32x4 accO[4];
#pragma unroll
    for (int dj = 0; dj < 4; dj++) {
        f32x4 z = {0.f, 0.f, 0.f, 0.f};
        accO[dj] = z;
    }
    float m_a = -1e30f, l_a = 0.f;

    const int nstart = s * (N_TOK / N_SPLIT);
    for (int t = 0; t < 7; t++) {
        const int n0 = nstart + t * 64;
        __syncthreads();   // previous tile fully consumed
        {   // stage K: [64 tok][64 d], swizzled chunks
            const unsigned short* src = kg + (long)(n0 + krow) * 512 + kcc * 16;
            u32x4 d0 = *(const u32x4*)(src);
            u32x4 d1 = *(const u32x4*)(src + 8);
            *(u32x4*)kdst0 = d0;
            *(u32x4*)kdst1 = d1;
        }
        {   // stage V transposed: Vt[d][tok], b32 holds tok pair (2tp,2tp+1)
            const unsigned short* sv = vg + (long)(n0 + vtp * 2) * 512 + vd0;
            u16x8 v0 = *(const u16x8*)(sv);
            u16x8 v1 = *(const u16x8*)(sv + 512);
#pragma unroll
            for (int j = 0; j < 8; j++) {
                unsigned int val = (unsigned int)v0[j] | ((unsigned int)v1[j] << 16);
                *(unsigned int*)((char*)Vsm + (vd0 + j) * 128
                                 + (((vtp >> 2) ^ j) * 16) + (vtp & 3) * 4) = val;
            }
        }
        __syncthreads();

        // S^T = K·A^T : rows = toks (it*16 + fq*4 + r), col = agent 16w+fr
        f32x4 sacc[4];
#pragma unroll
        for (int it = 0; it < 4; it++) {
            f32x4 z = {0.f, 0.f, 0.f, 0.f};
            sacc[it] = z;
        }
#pragma unroll
        for (int it = 0; it < 4; it++) {
            bf16x8 kf0 = *(const bf16x8*)((char*)Ksm + it * 2048 + fr * 128 + cs0);
            bf16x8 kf1 = *(const bf16x8*)((char*)Ksm + it * 2048 + fr * 128 + cs1);
            sacc[it] = __builtin_amdgcn_mfma_f32_16x16x32_bf16(kf0, afA[0], sacc[it], 0, 0, 0);
            sacc[it] = __builtin_amdgcn_mfma_f32_16x16x32_bf16(kf1, afA[1], sacc[it], 0, 0, 0);
        }

        // online softmax per agent (lane-local col; reduce across fq groups)
        float mloc = -1e30f;
#pragma unroll
        for (int it = 0; it < 4; it++)
#pragma unroll
            for (int r = 0; r < 4; r++) mloc = fmaxf(mloc, sacc[it][r]);
        mloc = fmaxf(mloc, __shfl_xor(mloc, 16));
        mloc = fmaxf(mloc, __shfl_xor(mloc, 32));
        float mnew = fmaxf(m_a, mloc);
        float alpha = __expf(m_a - mnew);
        float p[4][4];
        float ss = 0.f;
#pragma unroll
        for (int it = 0; it < 4; it++)
#pragma unroll
            for (int r = 0; r < 4; r++) {
                float pv = __expf(sacc[it][r] - mnew);
                p[it][r] = pv;
                ss += pv;
            }
        ss += __shfl_xor(ss, 16);
        ss += __shfl_xor(ss, 32);
        l_a = l_a * alpha + ss;
        m_a = mnew;

        // P^T -> bf16 per-wave LDS: row = agent fr, tok = it*16 + fq*4 + 2pr+{0,1}
#pragma unroll
        for (int it = 0; it < 4; it++)
#pragma unroll
            for (int pr = 0; pr < 2; pr++) {
                unsigned int u = (unsigned int)f2bf(p[it][pr * 2])
                               | ((unsigned int)f2bf(p[it][pr * 2 + 1]) << 16);
                *(unsigned int*)(plb + fr * 128
                    + (((it * 2 + (fq >> 1)) ^ (fr & 7)) * 16)
                    + (fq & 1) * 8 + pr * 4) = u;
            }

        // rescale O: O rows are agents fq*4+r; alpha lives at lane fr=fq*4+r
        float alr[4];
#pragma unroll
        for (int r = 0; r < 4; r++)
            alr[r] = __shfl(alpha, ((lane >> 4) << 2) + r);
#pragma unroll
        for (int dj = 0; dj < 4; dj++)
#pragma unroll
            for (int r = 0; r < 4; r++) accO[dj][r] *= alr[r];

        // PV: O[agent, d] += P[agent, tok] · Vt[d, tok]
        bf16x8 pf0 = *(const bf16x8*)(plb + fr * 128 + cs0);
        bf16x8 pf1 = *(const bf16x8*)(plb + fr * 128 + cs1);
#pragma unroll
        for (int dj = 0; dj < 4; dj++) {
            bf16x8 vf0 = *(const bf16x8*)((char*)Vsm + dj * 2048 + fr * 128 + cs0);
            bf16x8 vf1 = *(const bf16x8*)((char*)Vsm + dj * 2048 + fr * 128 + cs1);
            accO[dj] = __builtin_amdgcn_mfma_f32_16x16x32_bf16(pf0, vf0, accO[dj], 0, 0, 0);
            accO[dj] = __builtin_amdgcn_mfma_f32_16x16x32_bf16(pf1, vf1, accO[dj], 0, 0, 0);
        }
    }

    // epilogue: partials (unnormalized acc + m,l per agent)
    float* mob = macc + (long)blk * (AGENT_NUM * 64);
#pragma unroll
    for (int dj = 0; dj < 4; dj++)
#pragma unroll
        for (int r = 0; r < 4; r++) {
            int a = w * 16 + fq * 4 + r;
            if (a < AGENT_NUM)
                mob[a * 64 + dj * 16 + fr] = accO[dj][r];
        }
    if (fq == 0) {
        int a = w * 16 + fr;
        if (a < AGENT_NUM) {
            mpart[(long)blk * AGENT_NUM + a] = m_a;
            lpart[(long)blk * AGENT_NUM + a] = l_a;
        }
    }
}

// Combine the N_SPLIT partials -> agent_v[b,h,a,d]
__global__ __launch_bounds__(256) void agent_attn_combine(
    const float* __restrict__ macc, const float* __restrict__ mpart,
    const float* __restrict__ lpart, float* __restrict__ agent_v)
{
    int bh = blockIdx.x;               // 0..255
    int tid = threadIdx.x;
    __shared__ float E[AGENT_NUM * N_SPLIT];
    __shared__ float Linv[AGENT_NUM];

    if (tid < AGENT_NUM) {
        float mx = -1e30f;
        for (int s = 0; s < N_SPLIT; s++)
            mx = fmaxf(mx, mpart[((long)bh * N_SPLIT + s) * AGENT_NUM + tid]);
        float l = 0.f;
        for (int s = 0; s < N_SPLIT; s++) {
            float e = __expf(mpart[((long)bh * N_SPLIT + s) * AGENT_NUM + tid] - mx);
            E[tid * N_SPLIT + s] = e;
            l += e * lpart[((long)bh * N_SPLIT + s) * AGENT_NUM + tid];
        }
        Linv[tid] = 1.f / l;
    }
    __syncthreads();

    for (int idx = tid; idx < AGENT_NUM * 64; idx += 256) {
        int a = idx >> 6;
        float acc = 0.f;
        for (int s = 0; s < N_SPLIT; s++)
            acc += E[a * N_SPLIT + s] *
                   macc[((long)bh * N_SPLIT + s) * (AGENT_NUM * 64) + idx];
        agent_v[(long)bh * (AGENT_NUM * 64) + idx] = acc * Linv[a];
    }
}

// ---------------------------------------------------------------------------
// q attention via MFMA, IN-PLACE on d_out (q fp32). 1 wave = 64 queries.
// Swapped S^T = Agent·Q^T so softmax over agents is lane-local per query
// (col = lane&15). Agents padded 49->64 (rows masked to -1e30 -> p = 0).
// P[query][agent] bf16 in 8KB swizzled LDS (same-wave write/read, no barrier);
// O = P·AV via MFMA, stored in-place fp32.
// ---------------------------------------------------------------------------
__global__ __launch_bounds__(64) void q_attn_mfma(
    float* __restrict__ q, const float* __restrict__ agent,
    const float* __restrict__ agent_v)
{
    __shared__ __align__(16) unsigned short Psm[64 * 64];   // 8 KB

    const int blk = blockIdx.x;            // bh*49 + c  (consecutive c share tables)
    const int c = blk % 49;
    const int bh = blk / 49;
    const int b = bh >> 3, h = bh & 7;
    const int lane = threadIdx.x;
    const int fr = lane & 15, fq = lane >> 4;
    const int q0 = c * 64;

    // agent A-frags: row = agent i*16+fr (zero pad >=49), k = d = kk*32+fq*8, xSCALE
    bf16x8 agA[4][2];
#pragma unroll
    for (int i = 0; i < 4; i++) {
        int a = i * 16 + fr;
#pragma unroll
        for (int kk = 0; kk < 2; kk++) {
            union { bf16x8 v; unsigned short u[8]; } cv;
#pragma unroll
            for (int e = 0; e < 8; e++) cv.u[e] = 0;
            if (a < AGENT_NUM) {
                const float* ap = agent + ((long)b * AGENT_NUM + a) * 512 + h * 64 + fq * 8;
                float4 f0 = *(const float4*)(ap + kk * 32);
                float4 f1 = *(const float4*)(ap + kk * 32 + 4);
                cv.u[0] = f2bf(f0.x * SCALE); cv.u[1] = f2bf(f0.y * SCALE);
                cv.u[2] = f2bf(f0.z * SCALE); cv.u[3] = f2bf(f0.w * SCALE);
                cv.u[4] = f2bf(f1.x * SCALE); cv.u[5] = f2bf(f1.y * SCALE);
                cv.u[6] = f2bf(f1.z * SCALE); cv.u[7] = f2bf(f1.w * SCALE);
            }
            agA[i][kk] = cv.v;
        }
    }

    // Q B-frags: row (= output col) = query q0+jq*16+fr, k = d = kk*32+fq*8
    bf16x8 qB[4][2];
#pragma unroll
    for (int jq = 0; jq < 4; jq++) {
        const float* qp = q + ((long)b * N_TOK + q0 + jq * 16 + fr) * 512
                        + h * 64 + fq * 8;
#pragma unroll
        for (int kk = 0; kk < 2; kk++) {
            float4 f0 = *(const float4*)(qp + kk * 32);
            float4 f1 = *(const float4*)(qp + kk * 32 + 4);
            union { bf16x8 v; unsigned short u[8]; } cv;
            cv.u[0] = f2bf(f0.x); cv.u[1] = f2bf(f0.y);
            cv.u[2] = f2bf(f0.z); cv.u[3] = f2bf(f0.w);
            cv.u[4] = f2bf(f1.x); cv.u[5] = f2bf(f1.y);
            cv.u[6] = f2bf(f1.z); cv.u[7] = f2bf(f1.w);
            qB[jq][kk] = cv.v;
        }
    }

    // S^T MFMAs: sacc[i][jq], rows = agents i*16+fq*4+r, col = query jq*16+fr
    f32x4 sacc[4][4];
#pragma unroll
    for (int i = 0; i < 4; i++)
#pragma unroll
        for (int jq = 0; jq < 4; jq++) {
            f32x4 z = {0.f, 0.f, 0.f, 0.f};
            sacc[i][jq] = z;
        }
#pragma unroll
    for (int i = 0; i < 4; i++)
#pragma unroll
        for (int jq = 0; jq < 4; jq++) {
            sacc[i][jq] = __builtin_amdgcn_mfma_f32_16x16x32_bf16(
                agA[i][0], qB[jq][0], sacc[i][jq], 0, 0, 0);
            sacc[i][jq] = __builtin_amdgcn_mfma_f32_16x16x32_bf16(
                agA[i][1], qB[jq][1], sacc[i][jq], 0, 0, 0);
        }

    // mask padded agents (a = 48 + fq*4 + r >= 49 <=> fq*4+r >= 1)
#pragma unroll
    for (int jq = 0; jq < 4; jq++)
#pragma unroll
        for (int r = 0; r < 4; r++)
            if ((fq << 2) + r > 0) sacc[3][jq][r] = -1e30f;

    // exact softmax per query (values spread over i,r regs + fq lane groups)
#pragma unroll
    for (int jq = 0; jq < 4; jq++) {
        float mx = -1e30f;
#pragma unroll
        for (int i = 0; i < 4; i++)
#pragma unroll
            for (int r = 0; r < 4; r++) mx = fmaxf(mx, sacc[i][jq][r]);
        mx = fmaxf(mx, __shfl_xor(mx, 16));
        mx = fmaxf(mx, __shfl_xor(mx, 32));
        float ss = 0.f;
#pragma unroll
        for (int i = 0; i < 4; i++)
#pragma unroll
            for (int r = 0; r < 4; r++) {
                float pv = __expf(sacc[i][jq][r] - mx);
                sacc[i][jq][r] = pv;
                ss += pv;
            }
        ss += __shfl_xor(ss, 16);
        ss += __shfl_xor(ss, 32);
        float inv = 1.f / ss;
#pragma unroll
        for (int i = 0; i < 4; i++)
#pragma unroll
            for (int r = 0; r < 4; r++) sacc[i][jq][r] *= inv;
    }

    // write P[query][agent] bf16 to swizzled LDS (pairs of consecutive agents)
#pragma unroll
    for (int jq = 0; jq < 4; jq++) {
        char* prow = (char*)Psm + (jq * 16 + fr) * 128;
#pragma unroll
        for (int i = 0; i < 4; i++)
#pragma unroll
            for (int pr = 0; pr < 2; pr++) {
                unsigned int u = (unsigned int)f2bf(sacc[i][jq][pr * 2])
                               | ((unsigned int)f2bf(sacc[i][jq][pr * 2 + 1]) << 16);
                *(unsigned int*)(prow
                    + (((i * 2 + (fq >> 1)) ^ (fr & 7)) * 16)
                    + (fq & 1) * 8 + pr * 4) = u;
            }
    }

    // AV B-frags: col = d = jd*16+fr, k = agent = kk*32+fq*8+e (zero pad)
    const float* avb = agent_v + (long)bh * (AGENT_NUM * 64);
    bf16x8 avB[4][2];
#pragma unroll
    for (int jd = 0; jd < 4; jd++)
#pragma unroll
        for (int kk = 0; kk < 2; kk++) {
            union { bf16x8 v; unsigned short u[8]; } cv;
#pragma unroll
            for (int e = 0; e < 8; e++) {
                int a = kk * 32 + fq * 8 + e;
                cv.u[e] = (a < AGENT_NUM) ? f2bf(avb[a * 64 + jd * 16 + fr]) : 0;
            }
            avB[jd][kk] = cv.v;
        }

    // O = P·AV ; swizzled read chunks kk*4+fq ^ (fr&7)
    const int cs0 = ((fq)     ^ (fr & 7)) * 16;
    const int cs1 = ((4 + fq) ^ (fr & 7)) * 16;
#pragma unroll
    for (int iq = 0; iq < 4; iq++) {
        char* prow = (char*)Psm + (iq * 16 + fr) * 128;
        bf16x8 pf0 = *(const bf16x8*)(prow + cs0);
        bf16x8 pf1 = *(const bf16x8*)(prow + cs1);
        float* orow = q + ((long)b * N_TOK + q0 + iq * 16 + fq * 4) * 512 + h * 64;
#pragma unroll
        for (int jd = 0; jd < 4; jd++) {
            f32x4 o = {0.f, 0.f, 0.f, 0.f};
            o = __builtin_amdgcn_mfma_f32_16x16x32_bf16(pf0, avB[jd][0], o, 0, 0, 0);
            o = __builtin_amdgcn_mfma_f32_16x16x32_bf16(pf1, avB[jd][1], o, 0, 0, 0);
#pragma unroll
            for (int r = 0; r < 4; r++)
                orow[(long)r * 512 + jd * 16 + fr] = o[r];
        }
    }
}

// ---------------------------------------------------------------------------
// Fused: depthwise 3x3 conv on v (bf16) + bias + attn(d_out fp32) add,
// RNE-cast to bf16 proj input. One thread = 8 contiguous channels.
// ---------------------------------------------------------------------------
__global__ __launch_bounds__(256) void dwc_fuse(
    const unsigned short* __restrict__ vO, const float* __restrict__ w,
    const float* __restrict__ bias, const float* __restrict__ attn,
    unsigned short* __restrict__ outb)
{
    __shared__ float ws2[64 * 73];
    for (int i = threadIdx.x; i < 512 * 9; i += 256) {
        int c = i / 9, k = i - c * 9;
        ws2[(c >> 3) * 73 + k * 8 + (c & 7)] = w[i];
    }
    __syncthreads();

    long flat = (long)blockIdx.x * 256 + threadIdx.x;  // over M_ROWS*64
    int cg = (int)(flat & 63);
    int c8 = cg << 3;
    long row = flat >> 6;                              // b*N_TOK + n
    int n = (int)(row % N_TOK);
    int b = (int)(row / N_TOK);
    int y = n / H_IMG, x = n - y * H_IMG;

    const unsigned short* vb = vO + (long)b * N_TOK * 512 + c8;
    const float* wb = ws2 + cg * 73;

    float acc[8];
    float4 bv0 = *(const float4*)(bias + c8);
    float4 bv1 = *(const float4*)(bias + c8 + 4);
    acc[0] = bv0.x; acc[1] = bv0.y; acc[2] = bv0.z; acc[3] = bv0.w;
    acc[4] = bv1.x; acc[5] = bv1.y; acc[6] = bv1.z; acc[7] = bv1.w;

#pragma unroll
    for (int dy = 0; dy < 3; dy++) {
        int yy = y + dy - 1;
        if (yy < 0 || yy >= H_IMG) continue;
#pragma unroll
        for (int dx = 0; dx < 3; dx++) {
            int xx = x + dx - 1;
            if (xx < 0 || xx >= H_IMG) continue;
            const unsigned short* vp = vb + (long)(yy * H_IMG + xx) * 512;
            ushort4 u0 = *(const ushort4*)(vp);
            ushort4 u1 = *(const ushort4*)(vp + 4);
            const float* wk = wb + (dy * 3 + dx) * 8;
            acc[0] += wk[0] * bf2f(u0.x);
            acc[1] += wk[1] * bf2f(u0.y);
            acc[2] += wk[2] * bf2f(u0.z);
            acc[3] += wk[3] * bf2f(u0.w);
            acc[4] += wk[4] * bf2f(u1.x);
            acc[5] += wk[5] * bf2f(u1.y);
            acc[6] += wk[6] * bf2f(u1.z);
            acc[7] += wk[7] * bf2f(u1.w);
        }
    }

    const float* ap = attn + row * 512 + c8;
    float4 a0 = *(const float4*)(ap);
    float4 a1 = *(const float4*)(ap + 4);
    ushort4 o0, o1;
    o0.x = f2bf(a0.x + acc[0]); o0.y = f2bf(a0.y + acc[1]);
    o0.z = f2bf(a0.z + acc[2]); o0.w = f2bf(a0.w + acc[3]);
    o1.x = f2bf(a1.x + acc[4]); o1.y = f2bf(a1.y + acc[5]);
    o1.z = f2bf(a1.z + acc[6]); o1.w = f2bf(a1.w + acc[7]);

    unsigned short* op = outb + row * 512 + c8;
    *(ushort4*)(op)     = o0;
    *(ushort4*)(op + 4) = o1;
}

// ---------------------------------------------------------------------------
extern "C" void kernel_launch(void* const* d_in, const int* in_sizes, int n_in,
                              void* d_out, int out_size, void* d_ws, size_t ws_size,
                              hipStream_t stream)
{
    const float* x      = (const float*)d_in[0];
    const float* qkv_w  = (const float*)d_in[1];
    const float* proj_w = (const float*)d_in[2];
    const float* proj_b = (const float*)d_in[3];
    const float* dwc_w  = (const float*)d_in[4];
    const float* dwc_b  = (const float*)d_in[5];
    float* out = (float*)d_out;

    const long KV_ELEMS    = (long)M_ROWS * 512;                  // 51,380,224
    const long QKVW_ELEMS  = 1536L * 512;                         // 786,432
    const long PROJW_ELEMS = 512L * 512;                          // 262,144
    const long AGENT_ELEMS = (long)B_SZ * AGENT_NUM * 512;
    const long AV_ELEMS    = (long)B_SZ * 8 * AGENT_NUM * 64;
    const long MACC_ELEMS  = (long)B_SZ * 8 * N_SPLIT * AGENT_NUM * 64;
    const long ML_ELEMS    = (long)B_SZ * 8 * N_SPLIT * AGENT_NUM;

    unsigned short* kbuf    = (unsigned short*)d_ws;   // reused as proj-A later
    unsigned short* vbuf    = kbuf + KV_ELEMS;
    unsigned short* qkv_wb  = vbuf + KV_ELEMS;
    unsigned short* proj_wb = qkv_wb + QKVW_ELEMS;
    float* agent   = (float*)(proj_wb + PROJW_ELEMS);
    float* agent_v = agent + AGENT_ELEMS;
    float* macc    = agent_v + AV_ELEMS;
    float* mpart   = macc + MACC_ELEMS;
    float* lpart   = mpart + ML_ELEMS;
    unsigned short* xb = (unsigned short*)(lpart + ML_ELEMS);   // bf16 copy of x

    size_t need_old = (size_t)(2 * KV_ELEMS + QKVW_ELEMS + PROJW_ELEMS) * 2
                    + (size_t)(AGENT_ELEMS + AV_ELEMS + MACC_ELEMS + 2 * ML_ELEMS) * 4;
    size_t need_new = need_old + (size_t)KV_ELEMS * 2;
    if (ws_size < need_old) return;
    const bool precast = (ws_size >= need_new);

    // 0. cast weights to bf16
    cast_f32_bf16<<<(unsigned)(QKVW_ELEMS / 1024), 256, 0, stream>>>(qkv_w, qkv_wb);
    cast_f32_bf16<<<(unsigned)(PROJW_ELEMS / 1024), 256, 0, stream>>>(proj_w, proj_wb);

    // 1. qkv GEMM: q -> d_out (fp32), k,v -> ws (bf16)
    if (precast) {
        cast_f32_bf16<<<(unsigned)(KV_ELEMS / 1024), 256, 0, stream>>>(x, xb);
        mfma_qkv_bf<<<(M_ROWS / 128) * 12, 256, 0, stream>>>(
            xb, qkv_wb, out, kbuf, vbuf);
    } else {
        mfma_qkv<<<dim3(M_ROWS / 128, 12), 256, 0, stream>>>(
            x, qkv_wb, out, kbuf, vbuf);
    }

    // 2. agent = 7x7 pool of q
    pool_q<<<B_SZ * AGENT_NUM * 2, 256, 0, stream>>>(out, agent);

    // 3. agent attention (MFMA split + combine) -> agent_v
    agent_attn_mfma<<<B_SZ * 8 * N_SPLIT, 256, 0, stream>>>(
        kbuf, vbuf, agent, macc, mpart, lpart);
    agent_attn_combine<<<B_SZ * 8, 256, 0, stream>>>(macc, mpart, lpart, agent_v);

    // 4. q attention via MFMA, in-place on d_out (1 wave = 64 queries)
    q_attn_mfma<<<B_SZ * 8 * 49, 64, 0, stream>>>(out, agent, agent_v);

    // 5. fused dwc + attn-add + bf16 cast -> kbuf (k dead now)
    dwc_fuse<<<(unsigned)((long)M_ROWS * 64 / 256), 256, 0, stream>>>(
        vbuf, dwc_w, dwc_b, out, kbuf);

    // 6. final projection (bf16 MFMA, fp32 epilogue + bias)
    mfma_proj<<<(M_ROWS / 128) * 4, 256, 0, stream>>>(kbuf, proj_wb, proj_b, out);
}

// Round 6
// 1140.693 us; speedup vs baseline: 1.7856x; 1.0036x over previous
//
#include <hip/hip_runtime.h>

#define B_SZ 32
#define N_TOK 3136
#define C_DIM 512
#define H_IMG 56
#define NUM_HEADS 8
#define HEAD_DIM 64
#define AGENT_NUM 49
#define SCALE 0.125f
#define M_ROWS (B_SZ * N_TOK)        // 100352
#define N_SPLIT 7                    // agent-attn n-splits (448 tokens each)

typedef __bf16 bf16x8 __attribute__((ext_vector_type(8)));
typedef float f32x4 __attribute__((ext_vector_type(4)));
typedef unsigned short u16x8 __attribute__((ext_vector_type(8)));
typedef unsigned int u32x4 __attribute__((ext_vector_type(4)));

static __device__ __forceinline__ unsigned short f2bf(float f) {
    unsigned int u = __float_as_uint(f);
    unsigned int r = (u + 0x7fffu + ((u >> 16) & 1u)) >> 16;   // RNE
    return (unsigned short)r;
}
static __device__ __forceinline__ float bf2f(unsigned short u) {
    return __uint_as_float(((unsigned int)u) << 16);
}
// async global->LDS, 16B per lane; lds dest must be wave-uniform (HW: base + lane*16)
static __device__ __forceinline__ void load_lds16(const unsigned short* g, unsigned short* l) {
    __builtin_amdgcn_global_load_lds(
        (const __attribute__((address_space(1))) unsigned int*)g,
        (__attribute__((address_space(3))) unsigned int*)l, 16, 0, 0);
}

// generic fp32 -> bf16 cast, count must be multiple of 1024
__global__ __launch_bounds__(256) void cast_f32_bf16(
    const float* __restrict__ in, unsigned short* __restrict__ out)
{
    long i = (long)blockIdx.x * 256 + threadIdx.x;   // float4 index
    float4 f = ((const float4*)in)[i];
    ushort4 u;
    u.x = f2bf(f.x); u.y = f2bf(f.y); u.z = f2bf(f.z); u.w = f2bf(f.w);
    ((ushort4*)out)[i] = u;
}

// ---------------------------------------------------------------------------
// QKV MFMA GEMM (bf16): [M,1536] = xb[M,512] @ qkv_wb[1536,512]^T
// 128x128 tile, BK=32, 4 waves, XCD swizzle, T3-min double buffer.
// LDS chunk swizzle (T2): [row][32] tile, 16B chunk' = chunk ^ ((row>>1)&3),
// applied via pre-swizzled GLOBAL source (gload_lds writes linearly) and the
// matching fragment-read offset. Kills the 8-way quarter-wave conflict on
// ds_read_b128 (bank set was 16*(fr&1)+4*fq only).
// q (cols 0:512) -> fp32 d_out;  k,v -> bf16 ws.
// ---------------------------------------------------------------------------
__global__ __launch_bounds__(256) void mfma_qkv_bf(
    const unsigned short* __restrict__ Ab, const unsigned short* __restrict__ Wb,
    float* __restrict__ qO, unsigned short* __restrict__ kO,
    unsigned short* __restrict__ vO)
{
    __shared__ __align__(16) unsigned short Asm[2][128 * 32];
    __shared__ __align__(16) unsigned short Bsm[2][128 * 32];

    const int NWG  = (M_ROWS / 128) * 12;   // 9408, % 8 == 0
    const int PERX = NWG >> 3;              // 1176 (= 98 full A-tile groups)
    const int bid = blockIdx.x;
    const int l = (bid & 7) * PERX + (bid >> 3);   // bijective XCD swizzle
    const int m0 = (l / 12) * 128, n0 = (l % 12) * 128;

    const int tid = threadIdx.x;
    const int lane = tid & 63, wave = tid >> 6;
    const int wm = wave >> 1, wn = wave & 1;

    f32x4 acc[4][4];
#pragma unroll
    for (int i = 0; i < 4; i++)
#pragma unroll
        for (int j = 0; j < 4; j++) {
            f32x4 z = {0.f, 0.f, 0.f, 0.f};
            acc[i][j] = z;
        }

    // staged row = wave*16 + (lane>>2) (+64); (row>>1)&3 == (tid>>3)&3
    const int scol = ((tid & 3) ^ ((tid >> 3) & 3)) * 8;   // pre-swizzled source chunk
    const unsigned short* aP0 = Ab + (long)(m0 + (tid >> 2)) * 512 + scol;
    const unsigned short* aP1 = aP0 + (long)64 * 512;
    const unsigned short* bP0 = Wb + (long)(n0 + (tid >> 2)) * 512 + scol;
    const unsigned short* bP1 = bP0 + (long)64 * 512;
    const int stA0 = wave * 512;            // wave-uniform stage offsets
    const int stA1 = wave * 512 + 2048;

    const int fr = lane & 15, fq = lane >> 4;
    // fragment row = (wm|wn)*64 + i*16 + fr -> (row>>1)&3 == (fr>>1)&3 for all i
    const int fOff = (fq ^ ((fr >> 1) & 3)) * 8;

    // prologue: stage K-step 0 into buf 0
    load_lds16(aP0, Asm[0] + stA0);
    load_lds16(aP1, Asm[0] + stA1);
    load_lds16(bP0, Bsm[0] + stA0);
    load_lds16(bP1, Bsm[0] + stA1);
    __syncthreads();

    int cur = 0;
    for (int step = 0; step < 16; ++step) {
        if (step < 15) {                    // issue next tile early (flies under MFMA)
            const int k0 = (step + 1) * 32;
            load_lds16(aP0 + k0, Asm[cur ^ 1] + stA0);
            load_lds16(aP1 + k0, Asm[cur ^ 1] + stA1);
            load_lds16(bP0 + k0, Bsm[cur ^ 1] + stA0);
            load_lds16(bP1 + k0, Bsm[cur ^ 1] + stA1);
        }
        const unsigned short* aF = Asm[cur] + (wm * 64 + fr) * 32 + fOff;
        const unsigned short* bF = Bsm[cur] + (wn * 64 + fr) * 32 + fOff;
        bf16x8 af[4], bfr[4];
#pragma unroll
        for (int i = 0; i < 4; i++) af[i]  = *(const bf16x8*)(aF + i * 16 * 32);
#pragma unroll
        for (int j = 0; j < 4; j++) bfr[j] = *(const bf16x8*)(bF + j * 16 * 32);
#pragma unroll
        for (int i = 0; i < 4; i++)
#pragma unroll
            for (int j = 0; j < 4; j++)
                acc[i][j] = __builtin_amdgcn_mfma_f32_16x16x32_bf16(
                    af[i], bfr[j], acc[i][j], 0, 0, 0);
        __syncthreads();                    // drains vmcnt(0)+lgkmcnt(0): next buf ready
        cur ^= 1;
    }

    // epilogue: C/D layout col=lane&15, row=(lane>>4)*4+reg
    const int seg = n0 >> 9;   // 0=q,1=k,2=v (block never straddles: 128|512)
#pragma unroll
    for (int i = 0; i < 4; i++) {
        int rbase = m0 + wm * 64 + i * 16 + fq * 4;
#pragma unroll
        for (int j = 0; j < 4; j++) {
            int col  = n0 + wn * 64 + j * 16 + fr;
            int nloc = col - seg * 512;
#pragma unroll
            for (int r = 0; r < 4; r++) {
                long m = rbase + r;
                float val = acc[i][j][r];
                if (seg == 0)      qO[m * 512 + nloc] = val;
                else if (seg == 1) kO[m * 512 + nloc] = f2bf(val);
                else               vO[m * 512 + nloc] = f2bf(val);
            }
        }
    }
}

// ---------------------------------------------------------------------------
// Fallback QKV GEMM (fp32 A, cast in staging) — used if workspace too small
// for the bf16 x copy. (Unswizzled; internally consistent.)
// ---------------------------------------------------------------------------
__global__ __launch_bounds__(256) void mfma_qkv(
    const float* __restrict__ A, const unsigned short* __restrict__ Wb,
    float* __restrict__ qO, unsigned short* __restrict__ kO,
    unsigned short* __restrict__ vO)
{
    __shared__ __align__(16) unsigned short Asm[128 * 32];
    __shared__ __align__(16) unsigned short Bsm[128 * 32];

    const int m0 = blockIdx.x * 128, n0 = blockIdx.y * 128;
    const int tid = threadIdx.x;
    const int lane = tid & 63, wave = tid >> 6;
    const int wm = wave >> 1, wn = wave & 1;

    f32x4 acc[4][4];
#pragma unroll
    for (int i = 0; i < 4; i++)
#pragma unroll
        for (int j = 0; j < 4; j++) {
            f32x4 z = {0.f, 0.f, 0.f, 0.f};
            acc[i][j] = z;
        }

    const int arow = tid >> 1, acol = (tid & 1) * 16;
    const float* aP = A + (long)(m0 + arow) * 512 + acol;
    unsigned short* aD = Asm + arow * 32 + acol;

    const unsigned short* bP0 = Wb + (long)(n0 + (tid >> 2)) * 512 + (tid & 3) * 8;
    const unsigned short* bP1 = bP0 + (long)64 * 512;
    unsigned short* bD0 = Bsm + (tid >> 6) * 512;
    unsigned short* bD1 = bD0 + 4 * 512;

    const int fr = lane & 15, fq = lane >> 4;
    const unsigned short* aF = Asm + (wm * 64 + fr) * 32 + fq * 8;
    const unsigned short* bF = Bsm + (wn * 64 + fr) * 32 + fq * 8;

    for (int k0 = 0; k0 < 512; k0 += 32) {
        load_lds16(bP0 + k0, bD0);
        load_lds16(bP1 + k0, bD1);
        float4 f0 = *(const float4*)(aP + k0 + 0);
        float4 f1 = *(const float4*)(aP + k0 + 4);
        float4 f2 = *(const float4*)(aP + k0 + 8);
        float4 f3 = *(const float4*)(aP + k0 + 12);
        ushort4 u0, u1, u2, u3;
        u0.x = f2bf(f0.x); u0.y = f2bf(f0.y); u0.z = f2bf(f0.z); u0.w = f2bf(f0.w);
        u1.x = f2bf(f1.x); u1.y = f2bf(f1.y); u1.z = f2bf(f1.z); u1.w = f2bf(f1.w);
        u2.x = f2bf(f2.x); u2.y = f2bf(f2.y); u2.z = f2bf(f2.z); u2.w = f2bf(f2.w);
        u3.x = f2bf(f3.x); u3.y = f2bf(f3.y); u3.z = f2bf(f3.z); u3.w = f2bf(f3.w);
        *(ushort4*)(aD + 0)  = u0;
        *(ushort4*)(aD + 4)  = u1;
        *(ushort4*)(aD + 8)  = u2;
        *(ushort4*)(aD + 12) = u3;
        __syncthreads();

        bf16x8 af[4], bfr[4];
#pragma unroll
        for (int i = 0; i < 4; i++) af[i]  = *(const bf16x8*)(aF + i * 16 * 32);
#pragma unroll
        for (int j = 0; j < 4; j++) bfr[j] = *(const bf16x8*)(bF + j * 16 * 32);
#pragma unroll
        for (int i = 0; i < 4; i++)
#pragma unroll
            for (int j = 0; j < 4; j++)
                acc[i][j] = __builtin_amdgcn_mfma_f32_16x16x32_bf16(
                    af[i], bfr[j], acc[i][j], 0, 0, 0);
        __syncthreads();
    }

    const int seg = n0 >> 9;
#pragma unroll
    for (int i = 0; i < 4; i++) {
        int rbase = m0 + wm * 64 + i * 16 + fq * 4;
#pragma unroll
        for (int j = 0; j < 4; j++) {
            int col  = n0 + wn * 64 + j * 16 + fr;
            int nloc = col - seg * 512;
#pragma unroll
            for (int r = 0; r < 4; r++) {
                long m = rbase + r;
                float val = acc[i][j][r];
                if (seg == 0)      qO[m * 512 + nloc] = val;
                else if (seg == 1) kO[m * 512 + nloc] = f2bf(val);
                else               vO[m * 512 + nloc] = f2bf(val);
            }
        }
    }
}

// ---------------------------------------------------------------------------
// Proj MFMA GEMM: d_out[M,512] = Ab[M,512](bf16) @ proj_wb[512,512]^T + bias
// XCD swizzle; T3-min double-buffer; T2 chunk swizzle (same as qkv).
// ---------------------------------------------------------------------------
__global__ __launch_bounds__(256) void mfma_proj(
    const unsigned short* __restrict__ Ab, const unsigned short* __restrict__ Wb,
    const float* __restrict__ bias, float* __restrict__ C)
{
    __shared__ __align__(16) unsigned short Asm[2][128 * 32];
    __shared__ __align__(16) unsigned short Bsm[2][128 * 32];

    const int NWG  = (M_ROWS / 128) * 4;    // 3136, % 8 == 0
    const int PERX = NWG >> 3;              // 392 (= 98 full A-tile groups)
    const int bid = blockIdx.x;
    const int l = (bid & 7) * PERX + (bid >> 3);
    const int m0 = (l >> 2) * 128, n0 = (l & 3) * 128;

    const int tid = threadIdx.x;
    const int lane = tid & 63, wave = tid >> 6;
    const int wm = wave >> 1, wn = wave & 1;

    f32x4 acc[4][4];
#pragma unroll
    for (int i = 0; i < 4; i++)
#pragma unroll
        for (int j = 0; j < 4; j++) {
            f32x4 z = {0.f, 0.f, 0.f, 0.f};
            acc[i][j] = z;
        }

    const int scol = ((tid & 3) ^ ((tid >> 3) & 3)) * 8;   // pre-swizzled source chunk
    const unsigned short* aP0 = Ab + (long)(m0 + (tid >> 2)) * 512 + scol;
    const unsigned short* aP1 = aP0 + (long)64 * 512;
    const unsigned short* bP0 = Wb + (long)(n0 + (tid >> 2)) * 512 + scol;
    const unsigned short* bP1 = bP0 + (long)64 * 512;
    const int stA0 = wave * 512;
    const int stA1 = wave * 512 + 2048;

    const int fr = lane & 15, fq = lane >> 4;
    const int fOff = (fq ^ ((fr >> 1) & 3)) * 8;

    load_lds16(aP0, Asm[0] + stA0);
    load_lds16(aP1, Asm[0] + stA1);
    load_lds16(bP0, Bsm[0] + stA0);
    load_lds16(bP1, Bsm[0] + stA1);
    __syncthreads();

    int cur = 0;
    for (int step = 0; step < 16; ++step) {
        if (step < 15) {
            const int k0 = (step + 1) * 32;
            load_lds16(aP0 + k0, Asm[cur ^ 1] + stA0);
            load_lds16(aP1 + k0, Asm[cur ^ 1] + stA1);
            load_lds16(bP0 + k0, Bsm[cur ^ 1] + stA0);
            load_lds16(bP1 + k0, Bsm[cur ^ 1] + stA1);
        }
        const unsigned short* aF = Asm[cur] + (wm * 64 + fr) * 32 + fOff;
        const unsigned short* bF = Bsm[cur] + (wn * 64 + fr) * 32 + fOff;
        bf16x8 af[4], bfr[4];
#pragma unroll
        for (int i = 0; i < 4; i++) af[i]  = *(const bf16x8*)(aF + i * 16 * 32);
#pragma unroll
        for (int j = 0; j < 4; j++) bfr[j] = *(const bf16x8*)(bF + j * 16 * 32);
#pragma unroll
        for (int i = 0; i < 4; i++)
#pragma unroll
            for (int j = 0; j < 4; j++)
                acc[i][j] = __builtin_amdgcn_mfma_f32_16x16x32_bf16(
                    af[i], bfr[j], acc[i][j], 0, 0, 0);
        __syncthreads();
        cur ^= 1;
    }

#pragma unroll
    for (int i = 0; i < 4; i++) {
        int rbase = m0 + wm * 64 + i * 16 + fq * 4;
#pragma unroll
        for (int j = 0; j < 4; j++) {
            int col = n0 + wn * 64 + j * 16 + fr;
            float bv = bias[col];
#pragma unroll
            for (int r = 0; r < 4; r++)
                C[(long)(rbase + r) * 512 + col] = acc[i][j][r] + bv;
        }
    }
}

// ---------------------------------------------------------------------------
// agent[b,a,c] = mean over 8x8 spatial block of q (q fp32, stride 512)
// ---------------------------------------------------------------------------
__global__ __launch_bounds__(256) void pool_q(
    const float* __restrict__ q, float* __restrict__ agent)
{
    int blk = blockIdx.x;
    int half = blk & 1;
    int a = (blk >> 1) % AGENT_NUM;
    int b = blk / (2 * AGENT_NUM);
    int c = half * 256 + threadIdx.x;
    int pa = a / 7, pb = a % 7;
    const float* base = q + (long)b * N_TOK * 512 + c;
    float s = 0.f;
#pragma unroll
    for (int i = 0; i < 8; i++) {
        int rowbase = (pa * 8 + i) * H_IMG + pb * 8;
#pragma unroll
        for (int j = 0; j < 8; j++)
            s += base[(long)(rowbase + j) * 512];
    }
    agent[((long)b * AGENT_NUM + a) * 512 + c] = s * (1.f / 64.f);
}

// ---------------------------------------------------------------------------
// Agent attention via MFMA, split over n (7 x 448 tokens), flash-style.
// ---------------------------------------------------------------------------
__global__ __launch_bounds__(256) void agent_attn_mfma(
    const unsigned short* __restrict__ kO, const unsigned short* __restrict__ vO,
    const float* __restrict__ agent,
    float* __restrict__ macc, float* __restrict__ mpart, float* __restrict__ lpart)
{
    __shared__ __align__(16) unsigned short Ksm[64 * 64];
    __shared__ __align__(16) unsigned short Vsm[64 * 64];
    __shared__ __align__(16) unsigned short Psm[4 * 16 * 64];

    const int blk = blockIdx.x;            // (b*8+h)*7 + s
    const int s = blk % N_SPLIT;
    const int bh = blk / N_SPLIT;
    const int b = bh >> 3, h = bh & 7;
    const int tid = threadIdx.x;
    const int lane = tid & 63, w = tid >> 6;
    const int fr = lane & 15, fq = lane >> 4;

    // A-fragment in registers: agents 16w+fr (zero-padded), scale folded in.
    bf16x8 afA[2];
    {
        int a = w * 16 + fr;
#pragma unroll
        for (int kk = 0; kk < 2; kk++) {
            union { bf16x8 v; unsigned short u[8]; } cv;
#pragma unroll
            for (int e = 0; e < 8; e++) cv.u[e] = 0;
            if (a < AGENT_NUM) {
                const float* ap = agent + ((long)b * AGENT_NUM + a) * 512 + h * 64 + fq * 8;
                float4 f0 = *(const float4*)(ap + kk * 32);
                float4 f1 = *(const float4*)(ap + kk * 32 + 4);
                cv.u[0] = f2bf(f0.x * SCALE); cv.u[1] = f2bf(f0.y * SCALE);
                cv.u[2] = f2bf(f0.z * SCALE); cv.u[3] = f2bf(f0.w * SCALE);
                cv.u[4] = f2bf(f1.x * SCALE); cv.u[5] = f2bf(f1.y * SCALE);
                cv.u[6] = f2bf(f1.z * SCALE); cv.u[7] = f2bf(f1.w * SCALE);
            }
            afA[kk] = cv.v;
        }
    }

    // staging addresses
    const unsigned short* kg = kO + (long)b * N_TOK * 512 + h * 64;
    const unsigned short* vg = vO + (long)b * N_TOK * 512 + h * 64;
    const int krow = tid >> 2, kcc = tid & 3;
    char* kdst0 = (char*)Ksm + krow * 128 + (((kcc * 2)     ^ (krow & 7)) * 16);
    char* kdst1 = (char*)Ksm + krow * 128 + (((kcc * 2 + 1) ^ (krow & 7)) * 16);
    const int vtp = tid & 31, vd0 = (tid >> 5) * 8;

    // fragment-read swizzled chunk offsets (chunk = kk*4+fq, XOR fr&7)
    const int cs0 = ((fq)     ^ (fr & 7)) * 16;
    const int cs1 = ((4 + fq) ^ (fr & 7)) * 16;
    char* plb = (char*)Psm + w * 2048;     // per-wave P region [16][64] bf16

    f32x4 accO[4];
#pragma unroll
    for (int dj = 0; dj < 4; dj++) {
        f32x4 z = {0.f, 0.f, 0.f, 0.f};
        accO[dj] = z;
    }
    float m_a = -1e30f, l_a = 0.f;

    const int nstart = s * (N_TOK / N_SPLIT);
    for (int t = 0; t < 7; t++) {
        const int n0 = nstart + t * 64;
        __syncthreads();   // previous tile fully consumed
        {   // stage K: [64 tok][64 d], swizzled chunks
            const unsigned short* src = kg + (long)(n0 + krow) * 512 + kcc * 16;
            u32x4 d0 = *(const u32x4*)(src);
            u32x4 d1 = *(const u32x4*)(src + 8);
            *(u32x4*)kdst0 = d0;
            *(u32x4*)kdst1 = d1;
        }
        {   // stage V transposed: Vt[d][tok], b32 holds tok pair (2tp,2tp+1)
            const unsigned short* sv = vg + (long)(n0 + vtp * 2) * 512 + vd0;
            u16x8 v0 = *(const u16x8*)(sv);
            u16x8 v1 = *(const u16x8*)(sv + 512);
#pragma unroll
            for (int j = 0; j < 8; j++) {
                unsigned int val = (unsigned int)v0[j] | ((unsigned int)v1[j] << 16);
                *(unsigned int*)((char*)Vsm + (vd0 + j) * 128
                                 + (((vtp >> 2) ^ j) * 16) + (vtp & 3) * 4) = val;
            }
        }
        __syncthreads();

        // S^T = K·A^T : rows = toks (it*16 + fq*4 + r), col = agent 16w+fr
        f32x4 sacc[4];
#pragma unroll
        for (int it = 0; it < 4; it++) {
            f32x4 z = {0.f, 0.f, 0.f, 0.f};
            sacc[it] = z;
        }
#pragma unroll
        for (int it = 0; it < 4; it++) {
            bf16x8 kf0 = *(const bf16x8*)((char*)Ksm + it * 2048 + fr * 128 + cs0);
            bf16x8 kf1 = *(const bf16x8*)((char*)Ksm + it * 2048 + fr * 128 + cs1);
            sacc[it] = __builtin_amdgcn_mfma_f32_16x16x32_bf16(kf0, afA[0], sacc[it], 0, 0, 0);
            sacc[it] = __builtin_amdgcn_mfma_f32_16x16x32_bf16(kf1, afA[1], sacc[it], 0, 0, 0);
        }

        // online softmax per agent (lane-local col; reduce across fq groups)
        float mloc = -1e30f;
#pragma unroll
        for (int it = 0; it < 4; it++)
#pragma unroll
            for (int r = 0; r < 4; r++) mloc = fmaxf(mloc, sacc[it][r]);
        mloc = fmaxf(mloc, __shfl_xor(mloc, 16));
        mloc = fmaxf(mloc, __shfl_xor(mloc, 32));
        float mnew = fmaxf(m_a, mloc);
        float alpha = __expf(m_a - mnew);
        float p[4][4];
        float ss = 0.f;
#pragma unroll
        for (int it = 0; it < 4; it++)
#pragma unroll
            for (int r = 0; r < 4; r++) {
                float pv = __expf(sacc[it][r] - mnew);
                p[it][r] = pv;
                ss += pv;
            }
        ss += __shfl_xor(ss, 16);
        ss += __shfl_xor(ss, 32);
        l_a = l_a * alpha + ss;
        m_a = mnew;

        // P^T -> bf16 per-wave LDS: row = agent fr, tok = it*16 + fq*4 + 2pr+{0,1}
#pragma unroll
        for (int it = 0; it < 4; it++)
#pragma unroll
            for (int pr = 0; pr < 2; pr++) {
                unsigned int u = (unsigned int)f2bf(p[it][pr * 2])
                               | ((unsigned int)f2bf(p[it][pr * 2 + 1]) << 16);
                *(unsigned int*)(plb + fr * 128
                    + (((it * 2 + (fq >> 1)) ^ (fr & 7)) * 16)
                    + (fq & 1) * 8 + pr * 4) = u;
            }

        // rescale O: O rows are agents fq*4+r; alpha lives at lane fr=fq*4+r
        float alr[4];
#pragma unroll
        for (int r = 0; r < 4; r++)
            alr[r] = __shfl(alpha, ((lane >> 4) << 2) + r);
#pragma unroll
        for (int dj = 0; dj < 4; dj++)
#pragma unroll
            for (int r = 0; r < 4; r++) accO[dj][r] *= alr[r];

        // PV: O[agent, d] += P[agent, tok] · Vt[d, tok]
        bf16x8 pf0 = *(const bf16x8*)(plb + fr * 128 + cs0);
        bf16x8 pf1 = *(const bf16x8*)(plb + fr * 128 + cs1);
#pragma unroll
        for (int dj = 0; dj < 4; dj++) {
            bf16x8 vf0 = *(const bf16x8*)((char*)Vsm + dj * 2048 + fr * 128 + cs0);
            bf16x8 vf1 = *(const bf16x8*)((char*)Vsm + dj * 2048 + fr * 128 + cs1);
            accO[dj] = __builtin_amdgcn_mfma_f32_16x16x32_bf16(pf0, vf0, accO[dj], 0, 0, 0);
            accO[dj] = __builtin_amdgcn_mfma_f32_16x16x32_bf16(pf1, vf1, accO[dj], 0, 0, 0);
        }
    }

    // epilogue: partials (unnormalized acc + m,l per agent)
    float* mob = macc + (long)blk * (AGENT_NUM * 64);
#pragma unroll
    for (int dj = 0; dj < 4; dj++)
#pragma unroll
        for (int r = 0; r < 4; r++) {
            int a = w * 16 + fq * 4 + r;
            if (a < AGENT_NUM)
                mob[a * 64 + dj * 16 + fr] = accO[dj][r];
        }
    if (fq == 0) {
        int a = w * 16 + fr;
        if (a < AGENT_NUM) {
            mpart[(long)blk * AGENT_NUM + a] = m_a;
            lpart[(long)blk * AGENT_NUM + a] = l_a;
        }
    }
}

// Combine the N_SPLIT partials -> agent_v[b,h,a,d]
__global__ __launch_bounds__(256) void agent_attn_combine(
    const float* __restrict__ macc, const float* __restrict__ mpart,
    const float* __restrict__ lpart, float* __restrict__ agent_v)
{
    int bh = blockIdx.x;               // 0..255
    int tid = threadIdx.x;
    __shared__ float E[AGENT_NUM * N_SPLIT];
    __shared__ float Linv[AGENT_NUM];

    if (tid < AGENT_NUM) {
        float mx = -1e30f;
        for (int s = 0; s < N_SPLIT; s++)
            mx = fmaxf(mx, mpart[((long)bh * N_SPLIT + s) * AGENT_NUM + tid]);
        float l = 0.f;
        for (int s = 0; s < N_SPLIT; s++) {
            float e = __expf(mpart[((long)bh * N_SPLIT + s) * AGENT_NUM + tid] - mx);
            E[tid * N_SPLIT + s] = e;
            l += e * lpart[((long)bh * N_SPLIT + s) * AGENT_NUM + tid];
        }
        Linv[tid] = 1.f / l;
    }
    __syncthreads();

    for (int idx = tid; idx < AGENT_NUM * 64; idx += 256) {
        int a = idx >> 6;
        float acc = 0.f;
        for (int s = 0; s < N_SPLIT; s++)
            acc += E[a * N_SPLIT + s] *
                   macc[((long)bh * N_SPLIT + s) * (AGENT_NUM * 64) + idx];
        agent_v[(long)bh * (AGENT_NUM * 64) + idx] = acc * Linv[a];
    }
}

// ---------------------------------------------------------------------------
// q attention via MFMA, IN-PLACE on d_out (q fp32). 1 wave = 64 queries.
// ---------------------------------------------------------------------------
__global__ __launch_bounds__(64) void q_attn_mfma(
    float* __restrict__ q, const float* __restrict__ agent,
    const float* __restrict__ agent_v)
{
    __shared__ __align__(16) unsigned short Psm[64 * 64];   // 8 KB

    const int blk = blockIdx.x;            // bh*49 + c  (consecutive c share tables)
    const int c = blk % 49;
    const int bh = blk / 49;
    const int b = bh >> 3, h = bh & 7;
    const int lane = threadIdx.x;
    const int fr = lane & 15, fq = lane >> 4;
    const int q0 = c * 64;

    // agent A-frags: row = agent i*16+fr (zero pad >=49), k = d = kk*32+fq*8, xSCALE
    bf16x8 agA[4][2];
#pragma unroll
    for (int i = 0; i < 4; i++) {
        int a = i * 16 + fr;
#pragma unroll
        for (int kk = 0; kk < 2; kk++) {
            union { bf16x8 v; unsigned short u[8]; } cv;
#pragma unroll
            for (int e = 0; e < 8; e++) cv.u[e] = 0;
            if (a < AGENT_NUM) {
                const float* ap = agent + ((long)b * AGENT_NUM + a) * 512 + h * 64 + fq * 8;
                float4 f0 = *(const float4*)(ap + kk * 32);
                float4 f1 = *(const float4*)(ap + kk * 32 + 4);
                cv.u[0] = f2bf(f0.x * SCALE); cv.u[1] = f2bf(f0.y * SCALE);
                cv.u[2] = f2bf(f0.z * SCALE); cv.u[3] = f2bf(f0.w * SCALE);
                cv.u[4] = f2bf(f1.x * SCALE); cv.u[5] = f2bf(f1.y * SCALE);
                cv.u[6] = f2bf(f1.z * SCALE); cv.u[7] = f2bf(f1.w * SCALE);
            }
            agA[i][kk] = cv.v;
        }
    }

    // Q B-frags: row (= output col) = query q0+jq*16+fr, k = d = kk*32+fq*8
    bf16x8 qB[4][2];
#pragma unroll
    for (int jq = 0; jq < 4; jq++) {
        const float* qp = q + ((long)b * N_TOK + q0 + jq * 16 + fr) * 512
                        + h * 64 + fq * 8;
#pragma unroll
        for (int kk = 0; kk < 2; kk++) {
            float4 f0 = *(const float4*)(qp + kk * 32);
            float4 f1 = *(const float4*)(qp + kk * 32 + 4);
            union { bf16x8 v; unsigned short u[8]; } cv;
            cv.u[0] = f2bf(f0.x); cv.u[1] = f2bf(f0.y);
            cv.u[2] = f2bf(f0.z); cv.u[3] = f2bf(f0.w);
            cv.u[4] = f2bf(f1.x); cv.u[5] = f2bf(f1.y);
            cv.u[6] = f2bf(f1.z); cv.u[7] = f2bf(f1.w);
            qB[jq][kk] = cv.v;
        }
    }

    // S^T MFMAs: sacc[i][jq], rows = agents i*16+fq*4+r, col = query jq*16+fr
    f32x4 sacc[4][4];
#pragma unroll
    for (int i = 0; i < 4; i++)
#pragma unroll
        for (int jq = 0; jq < 4; jq++) {
            f32x4 z = {0.f, 0.f, 0.f, 0.f};
            sacc[i][jq] = z;
        }
#pragma unroll
    for (int i = 0; i < 4; i++)
#pragma unroll
        for (int jq = 0; jq < 4; jq++) {
            sacc[i][jq] = __builtin_amdgcn_mfma_f32_16x16x32_bf16(
                agA[i][0], qB[jq][0], sacc[i][jq], 0, 0, 0);
            sacc[i][jq] = __builtin_amdgcn_mfma_f32_16x16x32_bf16(
                agA[i][1], qB[jq][1], sacc[i][jq], 0, 0, 0);
        }

    // mask padded agents (a = 48 + fq*4 + r >= 49 <=> fq*4+r >= 1)
#pragma unroll
    for (int jq = 0; jq < 4; jq++)
#pragma unroll
        for (int r = 0; r < 4; r++)
            if ((fq << 2) + r > 0) sacc[3][jq][r] = -1e30f;

    // exact softmax per query (values spread over i,r regs + fq lane groups)
#pragma unroll
    for (int jq = 0; jq < 4; jq++) {
        float mx = -1e30f;
#pragma unroll
        for (int i = 0; i < 4; i++)
#pragma unroll
            for (int r = 0; r < 4; r++) mx = fmaxf(mx, sacc[i][jq][r]);
        mx = fmaxf(mx, __shfl_xor(mx, 16));
        mx = fmaxf(mx, __shfl_xor(mx, 32));
        float ss = 0.f;
#pragma unroll
        for (int i = 0; i < 4; i++)
#pragma unroll
            for (int r = 0; r < 4; r++) {
                float pv = __expf(sacc[i][jq][r] - mx);
                sacc[i][jq][r] = pv;
                ss += pv;
            }
        ss += __shfl_xor(ss, 16);
        ss += __shfl_xor(ss, 32);
        float inv = 1.f / ss;
#pragma unroll
        for (int i = 0; i < 4; i++)
#pragma unroll
            for (int r = 0; r < 4; r++) sacc[i][jq][r] *= inv;
    }

    // write P[query][agent] bf16 to swizzled LDS (pairs of consecutive agents)
#pragma unroll
    for (int jq = 0; jq < 4; jq++) {
        char* prow = (char*)Psm + (jq * 16 + fr) * 128;
#pragma unroll
        for (int i = 0; i < 4; i++)
#pragma unroll
            for (int pr = 0; pr < 2; pr++) {
                unsigned int u = (unsigned int)f2bf(sacc[i][jq][pr * 2])
                               | ((unsigned int)f2bf(sacc[i][jq][pr * 2 + 1]) << 16);
                *(unsigned int*)(prow
                    + (((i * 2 + (fq >> 1)) ^ (fr & 7)) * 16)
                    + (fq & 1) * 8 + pr * 4) = u;
            }
    }

    // AV B-frags: col = d = jd*16+fr, k = agent = kk*32+fq*8+e (zero pad)
    const float* avb = agent_v + (long)bh * (AGENT_NUM * 64);
    bf16x8 avB[4][2];
#pragma unroll
    for (int jd = 0; jd < 4; jd++)
#pragma unroll
        for (int kk = 0; kk < 2; kk++) {
            union { bf16x8 v; unsigned short u[8]; } cv;
#pragma unroll
            for (int e = 0; e < 8; e++) {
                int a = kk * 32 + fq * 8 + e;
                cv.u[e] = (a < AGENT_NUM) ? f2bf(avb[a * 64 + jd * 16 + fr]) : 0;
            }
            avB[jd][kk] = cv.v;
        }

    // O = P·AV ; swizzled read chunks kk*4+fq ^ (fr&7)
    const int cs0 = ((fq)     ^ (fr & 7)) * 16;
    const int cs1 = ((4 + fq) ^ (fr & 7)) * 16;
#pragma unroll
    for (int iq = 0; iq < 4; iq++) {
        char* prow = (char*)Psm + (iq * 16 + fr) * 128;
        bf16x8 pf0 = *(const bf16x8*)(prow + cs0);
        bf16x8 pf1 = *(const bf16x8*)(prow + cs1);
        float* orow = q + ((long)b * N_TOK + q0 + iq * 16 + fq * 4) * 512 + h * 64;
#pragma unroll
        for (int jd = 0; jd < 4; jd++) {
            f32x4 o = {0.f, 0.f, 0.f, 0.f};
            o = __builtin_amdgcn_mfma_f32_16x16x32_bf16(pf0, avB[jd][0], o, 0, 0, 0);
            o = __builtin_amdgcn_mfma_f32_16x16x32_bf16(pf1, avB[jd][1], o, 0, 0, 0);
#pragma unroll
            for (int r = 0; r < 4; r++)
                orow[(long)r * 512 + jd * 16 + fr] = o[r];
        }
    }
}

// ---------------------------------------------------------------------------
// Fused: depthwise 3x3 conv on v (bf16) + bias + attn(d_out fp32) add,
// RNE-cast to bf16 proj input. One thread = 8 contiguous channels.
// ---------------------------------------------------------------------------
__global__ __launch_bounds__(256) void dwc_fuse(
    const unsigned short* __restrict__ vO, const float* __restrict__ w,
    const float* __restrict__ bias, const float* __restrict__ attn,
    unsigned short* __restrict__ outb)
{
    __shared__ float ws2[64 * 73];
    for (int i = threadIdx.x; i < 512 * 9; i += 256) {
        int c = i / 9, k = i - c * 9;
        ws2[(c >> 3) * 73 + k * 8 + (c & 7)] = w[i];
    }
    __syncthreads();

    long flat = (long)blockIdx.x * 256 + threadIdx.x;  // over M_ROWS*64
    int cg = (int)(flat & 63);
    int c8 = cg << 3;
    long row = flat >> 6;                              // b*N_TOK + n
    int n = (int)(row % N_TOK);
    int b = (int)(row / N_TOK);
    int y = n / H_IMG, x = n - y * H_IMG;

    const unsigned short* vb = vO + (long)b * N_TOK * 512 + c8;
    const float* wb = ws2 + cg * 73;

    float acc[8];
    float4 bv0 = *(const float4*)(bias + c8);
    float4 bv1 = *(const float4*)(bias + c8 + 4);
    acc[0] = bv0.x; acc[1] = bv0.y; acc[2] = bv0.z; acc[3] = bv0.w;
    acc[4] = bv1.x; acc[5] = bv1.y; acc[6] = bv1.z; acc[7] = bv1.w;

#pragma unroll
    for (int dy = 0; dy < 3; dy++) {
        int yy = y + dy - 1;
        if (yy < 0 || yy >= H_IMG) continue;
#pragma unroll
        for (int dx = 0; dx < 3; dx++) {
            int xx = x + dx - 1;
            if (xx < 0 || xx >= H_IMG) continue;
            const unsigned short* vp = vb + (long)(yy * H_IMG + xx) * 512;
            ushort4 u0 = *(const ushort4*)(vp);
            ushort4 u1 = *(const ushort4*)(vp + 4);
            const float* wk = wb + (dy * 3 + dx) * 8;
            acc[0] += wk[0] * bf2f(u0.x);
            acc[1] += wk[1] * bf2f(u0.y);
            acc[2] += wk[2] * bf2f(u0.z);
            acc[3] += wk[3] * bf2f(u0.w);
            acc[4] += wk[4] * bf2f(u1.x);
            acc[5] += wk[5] * bf2f(u1.y);
            acc[6] += wk[6] * bf2f(u1.z);
            acc[7] += wk[7] * bf2f(u1.w);
        }
    }

    const float* ap = attn + row * 512 + c8;
    float4 a0 = *(const float4*)(ap);
    float4 a1 = *(const float4*)(ap + 4);
    ushort4 o0, o1;
    o0.x = f2bf(a0.x + acc[0]); o0.y = f2bf(a0.y + acc[1]);
    o0.z = f2bf(a0.z + acc[2]); o0.w = f2bf(a0.w + acc[3]);
    o1.x = f2bf(a1.x + acc[4]); o1.y = f2bf(a1.y + acc[5]);
    o1.z = f2bf(a1.z + acc[6]); o1.w = f2bf(a1.w + acc[7]);

    unsigned short* op = outb + row * 512 + c8;
    *(ushort4*)(op)     = o0;
    *(ushort4*)(op + 4) = o1;
}

// ---------------------------------------------------------------------------
extern "C" void kernel_launch(void* const* d_in, const int* in_sizes, int n_in,
                              void* d_out, int out_size, void* d_ws, size_t ws_size,
                              hipStream_t stream)
{
    const float* x      = (const float*)d_in[0];
    const float* qkv_w  = (const float*)d_in[1];
    const float* proj_w = (const float*)d_in[2];
    const float* proj_b = (const float*)d_in[3];
    const float* dwc_w  = (const float*)d_in[4];
    const float* dwc_b  = (const float*)d_in[5];
    float* out = (float*)d_out;

    const long KV_ELEMS    = (long)M_ROWS * 512;                  // 51,380,224
    const long QKVW_ELEMS  = 1536L * 512;                         // 786,432
    const long PROJW_ELEMS = 512L * 512;                          // 262,144
    const long AGENT_ELEMS = (long)B_SZ * AGENT_NUM * 512;
    const long AV_ELEMS    = (long)B_SZ * 8 * AGENT_NUM * 64;
    const long MACC_ELEMS  = (long)B_SZ * 8 * N_SPLIT * AGENT_NUM * 64;
    const long ML_ELEMS    = (long)B_SZ * 8 * N_SPLIT * AGENT_NUM;

    unsigned short* kbuf    = (unsigned short*)d_ws;   // reused as proj-A later
    unsigned short* vbuf    = kbuf + KV_ELEMS;
    unsigned short* qkv_wb  = vbuf + KV_ELEMS;
    unsigned short* proj_wb = qkv_wb + QKVW_ELEMS;
    float* agent   = (float*)(proj_wb + PROJW_ELEMS);
    float* agent_v = agent + AGENT_ELEMS;
    float* macc    = agent_v + AV_ELEMS;
    float* mpart   = macc + MACC_ELEMS;
    float* lpart   = mpart + ML_ELEMS;
    unsigned short* xb = (unsigned short*)(lpart + ML_ELEMS);   // bf16 copy of x

    size_t need_old = (size_t)(2 * KV_ELEMS + QKVW_ELEMS + PROJW_ELEMS) * 2
                    + (size_t)(AGENT_ELEMS + AV_ELEMS + MACC_ELEMS + 2 * ML_ELEMS) * 4;
    size_t need_new = need_old + (size_t)KV_ELEMS * 2;
    if (ws_size < need_old) return;
    const bool precast = (ws_size >= need_new);

    // 0. cast weights to bf16
    cast_f32_bf16<<<(unsigned)(QKVW_ELEMS / 1024), 256, 0, stream>>>(qkv_w, qkv_wb);
    cast_f32_bf16<<<(unsigned)(PROJW_ELEMS / 1024), 256, 0, stream>>>(proj_w, proj_wb);

    // 1. qkv GEMM: q -> d_out (fp32), k,v -> ws (bf16)
    if (precast) {
        cast_f32_bf16<<<(unsigned)(KV_ELEMS / 1024), 256, 0, stream>>>(x, xb);
        mfma_qkv_bf<<<(M_ROWS / 128) * 12, 256, 0, stream>>>(
            xb, qkv_wb, out, kbuf, vbuf);
    } else {
        mfma_qkv<<<dim3(M_ROWS / 128, 12), 256, 0, stream>>>(
            x, qkv_wb, out, kbuf, vbuf);
    }

    // 2. agent = 7x7 pool of q
    pool_q<<<B_SZ * AGENT_NUM * 2, 256, 0, stream>>>(out, agent);

    // 3. agent attention (MFMA split + combine) -> agent_v
    agent_attn_mfma<<<B_SZ * 8 * N_SPLIT, 256, 0, stream>>>(
        kbuf, vbuf, agent, macc, mpart, lpart);
    agent_attn_combine<<<B_SZ * 8, 256, 0, stream>>>(macc, mpart, lpart, agent_v);

    // 4. q attention via MFMA, in-place on d_out (1 wave = 64 queries)
    q_attn_mfma<<<B_SZ * 8 * 49, 64, 0, stream>>>(out, agent, agent_v);

    // 5. fused dwc + attn-add + bf16 cast -> kbuf (k dead now)
    dwc_fuse<<<(unsigned)((long)M_ROWS * 64 / 256), 256, 0, stream>>>(
        vbuf, dwc_w, dwc_b, out, kbuf);

    // 6. final projection (bf16 MFMA, fp32 epilogue + bias)
    mfma_proj<<<(M_ROWS / 128) * 4, 256, 0, stream>>>(kbuf, proj_wb, proj_b, out);
}

// Round 7
// 1076.122 us; speedup vs baseline: 1.8927x; 1.0600x over previous
//
#include <hip/hip_runtime.h>

#define B_SZ 32
#define N_TOK 3136
#define C_DIM 512
#define H_IMG 56
#define NUM_HEADS 8
#define HEAD_DIM 64
#define AGENT_NUM 49
#define SCALE 0.125f
#define M_ROWS (B_SZ * N_TOK)        // 100352
#define N_SPLIT 7                    // agent-attn n-splits (448 tokens each)

typedef __bf16 bf16x8 __attribute__((ext_vector_type(8)));
typedef float f32x4 __attribute__((ext_vector_type(4)));
typedef unsigned short u16x8 __attribute__((ext_vector_type(8)));
typedef unsigned int u32x4 __attribute__((ext_vector_type(4)));

static __device__ __forceinline__ unsigned short f2bf(float f) {
    unsigned int u = __float_as_uint(f);
    unsigned int r = (u + 0x7fffu + ((u >> 16) & 1u)) >> 16;   // RNE
    return (unsigned short)r;
}
static __device__ __forceinline__ float bf2f(unsigned short u) {
    return __uint_as_float(((unsigned int)u) << 16);
}
// async global->LDS, 16B per lane; lds dest must be wave-uniform (HW: base + lane*16)
static __device__ __forceinline__ void load_lds16(const unsigned short* g, unsigned short* l) {
    __builtin_amdgcn_global_load_lds(
        (const __attribute__((address_space(1))) unsigned int*)g,
        (__attribute__((address_space(3))) unsigned int*)l, 16, 0, 0);
}

// generic fp32 -> bf16 cast, count must be multiple of 1024
__global__ __launch_bounds__(256) void cast_f32_bf16(
    const float* __restrict__ in, unsigned short* __restrict__ out)
{
    long i = (long)blockIdx.x * 256 + threadIdx.x;   // float4 index
    float4 f = ((const float4*)in)[i];
    ushort4 u;
    u.x = f2bf(f.x); u.y = f2bf(f.y); u.z = f2bf(f.z); u.w = f2bf(f.w);
    ((ushort4*)out)[i] = u;
}

// ---------------------------------------------------------------------------
// QKV MFMA GEMM (bf16): [M,1536] = xb[M,512] @ qkv_wb[1536,512]^T
// 128x128 tile, BK=32, 4 waves, XCD swizzle, T3-min double buffer,
// T2 chunk swizzle (conflict-free ds_read_b128, verified R6: conflicts -> 0).
// q (cols 0:512) -> fp32 d_out;  k,v -> bf16 ws.
// ---------------------------------------------------------------------------
__global__ __launch_bounds__(256) void mfma_qkv_bf(
    const unsigned short* __restrict__ Ab, const unsigned short* __restrict__ Wb,
    float* __restrict__ qO, unsigned short* __restrict__ kO,
    unsigned short* __restrict__ vO)
{
    __shared__ __align__(16) unsigned short Asm[2][128 * 32];
    __shared__ __align__(16) unsigned short Bsm[2][128 * 32];

    const int NWG  = (M_ROWS / 128) * 12;   // 9408, % 8 == 0
    const int PERX = NWG >> 3;              // 1176 (= 98 full A-tile groups)
    const int bid = blockIdx.x;
    const int l = (bid & 7) * PERX + (bid >> 3);   // bijective XCD swizzle
    const int m0 = (l / 12) * 128, n0 = (l % 12) * 128;

    const int tid = threadIdx.x;
    const int lane = tid & 63, wave = tid >> 6;
    const int wm = wave >> 1, wn = wave & 1;

    f32x4 acc[4][4];
#pragma unroll
    for (int i = 0; i < 4; i++)
#pragma unroll
        for (int j = 0; j < 4; j++) {
            f32x4 z = {0.f, 0.f, 0.f, 0.f};
            acc[i][j] = z;
        }

    // staged row = wave*16 + (lane>>2) (+64); (row>>1)&3 == (tid>>3)&3
    const int scol = ((tid & 3) ^ ((tid >> 3) & 3)) * 8;   // pre-swizzled source chunk
    const unsigned short* aP0 = Ab + (long)(m0 + (tid >> 2)) * 512 + scol;
    const unsigned short* aP1 = aP0 + (long)64 * 512;
    const unsigned short* bP0 = Wb + (long)(n0 + (tid >> 2)) * 512 + scol;
    const unsigned short* bP1 = bP0 + (long)64 * 512;
    const int stA0 = wave * 512;            // wave-uniform stage offsets
    const int stA1 = wave * 512 + 2048;

    const int fr = lane & 15, fq = lane >> 4;
    const int fOff = (fq ^ ((fr >> 1) & 3)) * 8;

    // prologue: stage K-step 0 into buf 0
    load_lds16(aP0, Asm[0] + stA0);
    load_lds16(aP1, Asm[0] + stA1);
    load_lds16(bP0, Bsm[0] + stA0);
    load_lds16(bP1, Bsm[0] + stA1);
    __syncthreads();

    int cur = 0;
    for (int step = 0; step < 16; ++step) {
        if (step < 15) {                    // issue next tile early (flies under MFMA)
            const int k0 = (step + 1) * 32;
            load_lds16(aP0 + k0, Asm[cur ^ 1] + stA0);
            load_lds16(aP1 + k0, Asm[cur ^ 1] + stA1);
            load_lds16(bP0 + k0, Bsm[cur ^ 1] + stA0);
            load_lds16(bP1 + k0, Bsm[cur ^ 1] + stA1);
        }
        const unsigned short* aF = Asm[cur] + (wm * 64 + fr) * 32 + fOff;
        const unsigned short* bF = Bsm[cur] + (wn * 64 + fr) * 32 + fOff;
        bf16x8 af[4], bfr[4];
#pragma unroll
        for (int i = 0; i < 4; i++) af[i]  = *(const bf16x8*)(aF + i * 16 * 32);
#pragma unroll
        for (int j = 0; j < 4; j++) bfr[j] = *(const bf16x8*)(bF + j * 16 * 32);
#pragma unroll
        for (int i = 0; i < 4; i++)
#pragma unroll
            for (int j = 0; j < 4; j++)
                acc[i][j] = __builtin_amdgcn_mfma_f32_16x16x32_bf16(
                    af[i], bfr[j], acc[i][j], 0, 0, 0);
        __syncthreads();                    // drains vmcnt(0)+lgkmcnt(0): next buf ready
        cur ^= 1;
    }

    // epilogue: C/D layout col=lane&15, row=(lane>>4)*4+reg
    const int seg = n0 >> 9;   // 0=q,1=k,2=v (block never straddles: 128|512)
#pragma unroll
    for (int i = 0; i < 4; i++) {
        int rbase = m0 + wm * 64 + i * 16 + fq * 4;
#pragma unroll
        for (int j = 0; j < 4; j++) {
            int col  = n0 + wn * 64 + j * 16 + fr;
            int nloc = col - seg * 512;
#pragma unroll
            for (int r = 0; r < 4; r++) {
                long m = rbase + r;
                float val = acc[i][j][r];
                if (seg == 0)      qO[m * 512 + nloc] = val;
                else if (seg == 1) kO[m * 512 + nloc] = f2bf(val);
                else               vO[m * 512 + nloc] = f2bf(val);
            }
        }
    }
}

// ---------------------------------------------------------------------------
// Fallback QKV GEMM (fp32 A, cast in staging) — used if workspace too small
// for the bf16 x copy. (Unswizzled; internally consistent.)
// ---------------------------------------------------------------------------
__global__ __launch_bounds__(256) void mfma_qkv(
    const float* __restrict__ A, const unsigned short* __restrict__ Wb,
    float* __restrict__ qO, unsigned short* __restrict__ kO,
    unsigned short* __restrict__ vO)
{
    __shared__ __align__(16) unsigned short Asm[128 * 32];
    __shared__ __align__(16) unsigned short Bsm[128 * 32];

    const int m0 = blockIdx.x * 128, n0 = blockIdx.y * 128;
    const int tid = threadIdx.x;
    const int lane = tid & 63, wave = tid >> 6;
    const int wm = wave >> 1, wn = wave & 1;

    f32x4 acc[4][4];
#pragma unroll
    for (int i = 0; i < 4; i++)
#pragma unroll
        for (int j = 0; j < 4; j++) {
            f32x4 z = {0.f, 0.f, 0.f, 0.f};
            acc[i][j] = z;
        }

    const int arow = tid >> 1, acol = (tid & 1) * 16;
    const float* aP = A + (long)(m0 + arow) * 512 + acol;
    unsigned short* aD = Asm + arow * 32 + acol;

    const unsigned short* bP0 = Wb + (long)(n0 + (tid >> 2)) * 512 + (tid & 3) * 8;
    const unsigned short* bP1 = bP0 + (long)64 * 512;
    unsigned short* bD0 = Bsm + (tid >> 6) * 512;
    unsigned short* bD1 = bD0 + 4 * 512;

    const int fr = lane & 15, fq = lane >> 4;
    const unsigned short* aF = Asm + (wm * 64 + fr) * 32 + fq * 8;
    const unsigned short* bF = Bsm + (wn * 64 + fr) * 32 + fq * 8;

    for (int k0 = 0; k0 < 512; k0 += 32) {
        load_lds16(bP0 + k0, bD0);
        load_lds16(bP1 + k0, bD1);
        float4 f0 = *(const float4*)(aP + k0 + 0);
        float4 f1 = *(const float4*)(aP + k0 + 4);
        float4 f2 = *(const float4*)(aP + k0 + 8);
        float4 f3 = *(const float4*)(aP + k0 + 12);
        ushort4 u0, u1, u2, u3;
        u0.x = f2bf(f0.x); u0.y = f2bf(f0.y); u0.z = f2bf(f0.z); u0.w = f2bf(f0.w);
        u1.x = f2bf(f1.x); u1.y = f2bf(f1.y); u1.z = f2bf(f1.z); u1.w = f2bf(f1.w);
        u2.x = f2bf(f2.x); u2.y = f2bf(f2.y); u2.z = f2bf(f2.z); u2.w = f2bf(f2.w);
        u3.x = f2bf(f3.x); u3.y = f2bf(f3.y); u3.z = f2bf(f3.z); u3.w = f2bf(f3.w);
        *(ushort4*)(aD + 0)  = u0;
        *(ushort4*)(aD + 4)  = u1;
        *(ushort4*)(aD + 8)  = u2;
        *(ushort4*)(aD + 12) = u3;
        __syncthreads();

        bf16x8 af[4], bfr[4];
#pragma unroll
        for (int i = 0; i < 4; i++) af[i]  = *(const bf16x8*)(aF + i * 16 * 32);
#pragma unroll
        for (int j = 0; j < 4; j++) bfr[j] = *(const bf16x8*)(bF + j * 16 * 32);
#pragma unroll
        for (int i = 0; i < 4; i++)
#pragma unroll
            for (int j = 0; j < 4; j++)
                acc[i][j] = __builtin_amdgcn_mfma_f32_16x16x32_bf16(
                    af[i], bfr[j], acc[i][j], 0, 0, 0);
        __syncthreads();
    }

    const int seg = n0 >> 9;
#pragma unroll
    for (int i = 0; i < 4; i++) {
        int rbase = m0 + wm * 64 + i * 16 + fq * 4;
#pragma unroll
        for (int j = 0; j < 4; j++) {
            int col  = n0 + wn * 64 + j * 16 + fr;
            int nloc = col - seg * 512;
#pragma unroll
            for (int r = 0; r < 4; r++) {
                long m = rbase + r;
                float val = acc[i][j][r];
                if (seg == 0)      qO[m * 512 + nloc] = val;
                else if (seg == 1) kO[m * 512 + nloc] = f2bf(val);
                else               vO[m * 512 + nloc] = f2bf(val);
            }
        }
    }
}

// ---------------------------------------------------------------------------
// Proj MFMA GEMM: d_out[M,512] = Ab[M,512](bf16) @ proj_wb[512,512]^T + bias
// XCD swizzle; T3-min double-buffer; T2 chunk swizzle (same as qkv).
// ---------------------------------------------------------------------------
__global__ __launch_bounds__(256) void mfma_proj(
    const unsigned short* __restrict__ Ab, const unsigned short* __restrict__ Wb,
    const float* __restrict__ bias, float* __restrict__ C)
{
    __shared__ __align__(16) unsigned short Asm[2][128 * 32];
    __shared__ __align__(16) unsigned short Bsm[2][128 * 32];

    const int NWG  = (M_ROWS / 128) * 4;    // 3136, % 8 == 0
    const int PERX = NWG >> 3;              // 392 (= 98 full A-tile groups)
    const int bid = blockIdx.x;
    const int l = (bid & 7) * PERX + (bid >> 3);
    const int m0 = (l >> 2) * 128, n0 = (l & 3) * 128;

    const int tid = threadIdx.x;
    const int lane = tid & 63, wave = tid >> 6;
    const int wm = wave >> 1, wn = wave & 1;

    f32x4 acc[4][4];
#pragma unroll
    for (int i = 0; i < 4; i++)
#pragma unroll
        for (int j = 0; j < 4; j++) {
            f32x4 z = {0.f, 0.f, 0.f, 0.f};
            acc[i][j] = z;
        }

    const int scol = ((tid & 3) ^ ((tid >> 3) & 3)) * 8;   // pre-swizzled source chunk
    const unsigned short* aP0 = Ab + (long)(m0 + (tid >> 2)) * 512 + scol;
    const unsigned short* aP1 = aP0 + (long)64 * 512;
    const unsigned short* bP0 = Wb + (long)(n0 + (tid >> 2)) * 512 + scol;
    const unsigned short* bP1 = bP0 + (long)64 * 512;
    const int stA0 = wave * 512;
    const int stA1 = wave * 512 + 2048;

    const int fr = lane & 15, fq = lane >> 4;
    const int fOff = (fq ^ ((fr >> 1) & 3)) * 8;

    load_lds16(aP0, Asm[0] + stA0);
    load_lds16(aP1, Asm[0] + stA1);
    load_lds16(bP0, Bsm[0] + stA0);
    load_lds16(bP1, Bsm[0] + stA1);
    __syncthreads();

    int cur = 0;
    for (int step = 0; step < 16; ++step) {
        if (step < 15) {
            const int k0 = (step + 1) * 32;
            load_lds16(aP0 + k0, Asm[cur ^ 1] + stA0);
            load_lds16(aP1 + k0, Asm[cur ^ 1] + stA1);
            load_lds16(bP0 + k0, Bsm[cur ^ 1] + stA0);
            load_lds16(bP1 + k0, Bsm[cur ^ 1] + stA1);
        }
        const unsigned short* aF = Asm[cur] + (wm * 64 + fr) * 32 + fOff;
        const unsigned short* bF = Bsm[cur] + (wn * 64 + fr) * 32 + fOff;
        bf16x8 af[4], bfr[4];
#pragma unroll
        for (int i = 0; i < 4; i++) af[i]  = *(const bf16x8*)(aF + i * 16 * 32);
#pragma unroll
        for (int j = 0; j < 4; j++) bfr[j] = *(const bf16x8*)(bF + j * 16 * 32);
#pragma unroll
        for (int i = 0; i < 4; i++)
#pragma unroll
            for (int j = 0; j < 4; j++)
                acc[i][j] = __builtin_amdgcn_mfma_f32_16x16x32_bf16(
                    af[i], bfr[j], acc[i][j], 0, 0, 0);
        __syncthreads();
        cur ^= 1;
    }

#pragma unroll
    for (int i = 0; i < 4; i++) {
        int rbase = m0 + wm * 64 + i * 16 + fq * 4;
#pragma unroll
        for (int j = 0; j < 4; j++) {
            int col = n0 + wn * 64 + j * 16 + fr;
            float bv = bias[col];
#pragma unroll
            for (int r = 0; r < 4; r++)
                C[(long)(rbase + r) * 512 + col] = acc[i][j][r] + bv;
        }
    }
}

// ---------------------------------------------------------------------------
// agent[b,a,c] = mean over 8x8 spatial block of q (q fp32, stride 512)
// ---------------------------------------------------------------------------
__global__ __launch_bounds__(256) void pool_q(
    const float* __restrict__ q, float* __restrict__ agent)
{
    int blk = blockIdx.x;
    int half = blk & 1;
    int a = (blk >> 1) % AGENT_NUM;
    int b = blk / (2 * AGENT_NUM);
    int c = half * 256 + threadIdx.x;
    int pa = a / 7, pb = a % 7;
    const float* base = q + (long)b * N_TOK * 512 + c;
    float s = 0.f;
#pragma unroll
    for (int i = 0; i < 8; i++) {
        int rowbase = (pa * 8 + i) * H_IMG + pb * 8;
#pragma unroll
        for (int j = 0; j < 8; j++)
            s += base[(long)(rowbase + j) * 512];
    }
    agent[((long)b * AGENT_NUM + a) * 512 + c] = s * (1.f / 64.f);
}

// ---------------------------------------------------------------------------
// Agent attention via MFMA, split over n (7 x 448 tokens), flash-style.
// ---------------------------------------------------------------------------
__global__ __launch_bounds__(256) void agent_attn_mfma(
    const unsigned short* __restrict__ kO, const unsigned short* __restrict__ vO,
    const float* __restrict__ agent,
    float* __restrict__ macc, float* __restrict__ mpart, float* __restrict__ lpart)
{
    __shared__ __align__(16) unsigned short Ksm[64 * 64];
    __shared__ __align__(16) unsigned short Vsm[64 * 64];
    __shared__ __align__(16) unsigned short Psm[4 * 16 * 64];

    const int blk = blockIdx.x;            // (b*8+h)*7 + s
    const int s = blk % N_SPLIT;
    const int bh = blk / N_SPLIT;
    const int b = bh >> 3, h = bh & 7;
    const int tid = threadIdx.x;
    const int lane = tid & 63, w = tid >> 6;
    const int fr = lane & 15, fq = lane >> 4;

    // A-fragment in registers: agents 16w+fr (zero-padded), scale folded in.
    bf16x8 afA[2];
    {
        int a = w * 16 + fr;
#pragma unroll
        for (int kk = 0; kk < 2; kk++) {
            union { bf16x8 v; unsigned short u[8]; } cv;
#pragma unroll
            for (int e = 0; e < 8; e++) cv.u[e] = 0;
            if (a < AGENT_NUM) {
                const float* ap = agent + ((long)b * AGENT_NUM + a) * 512 + h * 64 + fq * 8;
                float4 f0 = *(const float4*)(ap + kk * 32);
                float4 f1 = *(const float4*)(ap + kk * 32 + 4);
                cv.u[0] = f2bf(f0.x * SCALE); cv.u[1] = f2bf(f0.y * SCALE);
                cv.u[2] = f2bf(f0.z * SCALE); cv.u[3] = f2bf(f0.w * SCALE);
                cv.u[4] = f2bf(f1.x * SCALE); cv.u[5] = f2bf(f1.y * SCALE);
                cv.u[6] = f2bf(f1.z * SCALE); cv.u[7] = f2bf(f1.w * SCALE);
            }
            afA[kk] = cv.v;
        }
    }

    // staging addresses
    const unsigned short* kg = kO + (long)b * N_TOK * 512 + h * 64;
    const unsigned short* vg = vO + (long)b * N_TOK * 512 + h * 64;
    const int krow = tid >> 2, kcc = tid & 3;
    char* kdst0 = (char*)Ksm + krow * 128 + (((kcc * 2)     ^ (krow & 7)) * 16);
    char* kdst1 = (char*)Ksm + krow * 128 + (((kcc * 2 + 1) ^ (krow & 7)) * 16);
    const int vtp = tid & 31, vd0 = (tid >> 5) * 8;

    // fragment-read swizzled chunk offsets (chunk = kk*4+fq, XOR fr&7)
    const int cs0 = ((fq)     ^ (fr & 7)) * 16;
    const int cs1 = ((4 + fq) ^ (fr & 7)) * 16;
    char* plb = (char*)Psm + w * 2048;     // per-wave P region [16][64] bf16

    f32x4 accO[4];
#pragma unroll
    for (int dj = 0; dj < 4; dj++) {
        f32x4 z = {0.f, 0.f, 0.f, 0.f};
        accO[dj] = z;
    }
    float m_a = -1e30f, l_a = 0.f;

    const int nstart = s * (N_TOK / N_SPLIT);
    for (int t = 0; t < 7; t++) {
        const int n0 = nstart + t * 64;
        __syncthreads();   // previous tile fully consumed
        {   // stage K: [64 tok][64 d], swizzled chunks
            const unsigned short* src = kg + (long)(n0 + krow) * 512 + kcc * 16;
            u32x4 d0 = *(const u32x4*)(src);
            u32x4 d1 = *(const u32x4*)(src + 8);
            *(u32x4*)kdst0 = d0;
            *(u32x4*)kdst1 = d1;
        }
        {   // stage V transposed: Vt[d][tok], b32 holds tok pair (2tp,2tp+1)
            const unsigned short* sv = vg + (long)(n0 + vtp * 2) * 512 + vd0;
            u16x8 v0 = *(const u16x8*)(sv);
            u16x8 v1 = *(const u16x8*)(sv + 512);
#pragma unroll
            for (int j = 0; j < 8; j++) {
                unsigned int val = (unsigned int)v0[j] | ((unsigned int)v1[j] << 16);
                *(unsigned int*)((char*)Vsm + (vd0 + j) * 128
                                 + (((vtp >> 2) ^ j) * 16) + (vtp & 3) * 4) = val;
            }
        }
        __syncthreads();

        // S^T = K·A^T : rows = toks (it*16 + fq*4 + r), col = agent 16w+fr
        f32x4 sacc[4];
#pragma unroll
        for (int it = 0; it < 4; it++) {
            f32x4 z = {0.f, 0.f, 0.f, 0.f};
            sacc[it] = z;
        }
#pragma unroll
        for (int it = 0; it < 4; it++) {
            bf16x8 kf0 = *(const bf16x8*)((char*)Ksm + it * 2048 + fr * 128 + cs0);
            bf16x8 kf1 = *(const bf16x8*)((char*)Ksm + it * 2048 + fr * 128 + cs1);
            sacc[it] = __builtin_amdgcn_mfma_f32_16x16x32_bf16(kf0, afA[0], sacc[it], 0, 0, 0);
            sacc[it] = __builtin_amdgcn_mfma_f32_16x16x32_bf16(kf1, afA[1], sacc[it], 0, 0, 0);
        }

        // online softmax per agent (lane-local col; reduce across fq groups)
        float mloc = -1e30f;
#pragma unroll
        for (int it = 0; it < 4; it++)
#pragma unroll
            for (int r = 0; r < 4; r++) mloc = fmaxf(mloc, sacc[it][r]);
        mloc = fmaxf(mloc, __shfl_xor(mloc, 16));
        mloc = fmaxf(mloc, __shfl_xor(mloc, 32));
        float mnew = fmaxf(m_a, mloc);
        float alpha = __expf(m_a - mnew);
        float p[4][4];
        float ss = 0.f;
#pragma unroll
        for (int it = 0; it < 4; it++)
#pragma unroll
            for (int r = 0; r < 4; r++) {
                float pv = __expf(sacc[it][r] - mnew);
                p[it][r] = pv;
                ss += pv;
            }
        ss += __shfl_xor(ss, 16);
        ss += __shfl_xor(ss, 32);
        l_a = l_a * alpha + ss;
        m_a = mnew;

        // P^T -> bf16 per-wave LDS: row = agent fr, tok = it*16 + fq*4 + 2pr+{0,1}
#pragma unroll
        for (int it = 0; it < 4; it++)
#pragma unroll
            for (int pr = 0; pr < 2; pr++) {
                unsigned int u = (unsigned int)f2bf(p[it][pr * 2])
                               | ((unsigned int)f2bf(p[it][pr * 2 + 1]) << 16);
                *(unsigned int*)(plb + fr * 128
                    + (((it * 2 + (fq >> 1)) ^ (fr & 7)) * 16)
                    + (fq & 1) * 8 + pr * 4) = u;
            }

        // rescale O: O rows are agents fq*4+r; alpha lives at lane fr=fq*4+r
        float alr[4];
#pragma unroll
        for (int r = 0; r < 4; r++)
            alr[r] = __shfl(alpha, ((lane >> 4) << 2) + r);
#pragma unroll
        for (int dj = 0; dj < 4; dj++)
#pragma unroll
            for (int r = 0; r < 4; r++) accO[dj][r] *= alr[r];

        // PV: O[agent, d] += P[agent, tok] · Vt[d, tok]
        bf16x8 pf0 = *(const bf16x8*)(plb + fr * 128 + cs0);
        bf16x8 pf1 = *(const bf16x8*)(plb + fr * 128 + cs1);
#pragma unroll
        for (int dj = 0; dj < 4; dj++) {
            bf16x8 vf0 = *(const bf16x8*)((char*)Vsm + dj * 2048 + fr * 128 + cs0);
            bf16x8 vf1 = *(const bf16x8*)((char*)Vsm + dj * 2048 + fr * 128 + cs1);
            accO[dj] = __builtin_amdgcn_mfma_f32_16x16x32_bf16(pf0, vf0, accO[dj], 0, 0, 0);
            accO[dj] = __builtin_amdgcn_mfma_f32_16x16x32_bf16(pf1, vf1, accO[dj], 0, 0, 0);
        }
    }

    // epilogue: partials (unnormalized acc + m,l per agent)
    float* mob = macc + (long)blk * (AGENT_NUM * 64);
#pragma unroll
    for (int dj = 0; dj < 4; dj++)
#pragma unroll
        for (int r = 0; r < 4; r++) {
            int a = w * 16 + fq * 4 + r;
            if (a < AGENT_NUM)
                mob[a * 64 + dj * 16 + fr] = accO[dj][r];
        }
    if (fq == 0) {
        int a = w * 16 + fr;
        if (a < AGENT_NUM) {
            mpart[(long)blk * AGENT_NUM + a] = m_a;
            lpart[(long)blk * AGENT_NUM + a] = l_a;
        }
    }
}

// Combine the N_SPLIT partials -> agent_v[b,h,a,d]
__global__ __launch_bounds__(256) void agent_attn_combine(
    const float* __restrict__ macc, const float* __restrict__ mpart,
    const float* __restrict__ lpart, float* __restrict__ agent_v)
{
    int bh = blockIdx.x;               // 0..255
    int tid = threadIdx.x;
    __shared__ float E[AGENT_NUM * N_SPLIT];
    __shared__ float Linv[AGENT_NUM];

    if (tid < AGENT_NUM) {
        float mx = -1e30f;
        for (int s = 0; s < N_SPLIT; s++)
            mx = fmaxf(mx, mpart[((long)bh * N_SPLIT + s) * AGENT_NUM + tid]);
        float l = 0.f;
        for (int s = 0; s < N_SPLIT; s++) {
            float e = __expf(mpart[((long)bh * N_SPLIT + s) * AGENT_NUM + tid] - mx);
            E[tid * N_SPLIT + s] = e;
            l += e * lpart[((long)bh * N_SPLIT + s) * AGENT_NUM + tid];
        }
        Linv[tid] = 1.f / l;
    }
    __syncthreads();

    for (int idx = tid; idx < AGENT_NUM * 64; idx += 256) {
        int a = idx >> 6;
        float acc = 0.f;
        for (int s = 0; s < N_SPLIT; s++)
            acc += E[a * N_SPLIT + s] *
                   macc[((long)bh * N_SPLIT + s) * (AGENT_NUM * 64) + idx];
        agent_v[(long)bh * (AGENT_NUM * 64) + idx] = acc * Linv[a];
    }
}

// ---------------------------------------------------------------------------
// q attention via MFMA, IN-PLACE on d_out (q fp32). 1 wave = 64 queries.
// AV staged TRANSPOSED in LDS (AVsm[d][agent-pair], Vsm-pattern pair-pack +
// XOR-chunk swizzle) -> PV B-frags are single 16B swizzled LDS reads instead
// of 64 uncoalesced scalar global loads per lane. Staging issued before the
// S MFMAs so HBM latency hides under compute (T14).
// ---------------------------------------------------------------------------
__global__ __launch_bounds__(64) void q_attn_mfma(
    float* __restrict__ q, const float* __restrict__ agent,
    const float* __restrict__ agent_v)
{
    __shared__ __align__(16) unsigned short Psm[64 * 64];    // 8 KB
    __shared__ __align__(16) unsigned short AVsm[64 * 64];   // 8 KB, [d][agent]

    const int blk = blockIdx.x;            // bh*49 + c  (consecutive c share tables)
    const int c = blk % 49;
    const int bh = blk / 49;
    const int b = bh >> 3, h = bh & 7;
    const int lane = threadIdx.x;
    const int fr = lane & 15, fq = lane >> 4;
    const int q0 = c * 64;

    // ---- stage AV transposed into LDS (issued first; flies under S/softmax)
    // lane covers agent-pair vtp = lane&31, d-groups d0 = (lane>>5)*8 + g*16
    {
        const float* avb = agent_v + (long)bh * (AGENT_NUM * 64);
        const int vtp = lane & 31;
        const int a0 = vtp * 2, a1 = a0 + 1;
#pragma unroll
        for (int g = 0; g < 4; g++) {
            const int d0 = (lane >> 5) * 8 + g * 16;
            float4 f00 = {0.f,0.f,0.f,0.f}, f01 = {0.f,0.f,0.f,0.f};
            float4 f10 = {0.f,0.f,0.f,0.f}, f11 = {0.f,0.f,0.f,0.f};
            if (a0 < AGENT_NUM) {
                f00 = *(const float4*)(avb + a0 * 64 + d0);
                f01 = *(const float4*)(avb + a0 * 64 + d0 + 4);
            }
            if (a1 < AGENT_NUM) {
                f10 = *(const float4*)(avb + a1 * 64 + d0);
                f11 = *(const float4*)(avb + a1 * 64 + d0 + 4);
            }
            float v0[8] = {f00.x, f00.y, f00.z, f00.w, f01.x, f01.y, f01.z, f01.w};
            float v1[8] = {f10.x, f10.y, f10.z, f10.w, f11.x, f11.y, f11.z, f11.w};
#pragma unroll
            for (int j = 0; j < 8; j++) {
                unsigned int val = (unsigned int)f2bf(v0[j])
                                 | ((unsigned int)f2bf(v1[j]) << 16);
                *(unsigned int*)((char*)AVsm + (d0 + j) * 128
                                 + (((vtp >> 2) ^ j) * 16) + (vtp & 3) * 4) = val;
            }
        }
    }

    // agent A-frags: row = agent i*16+fr (zero pad >=49), k = d = kk*32+fq*8, xSCALE
    bf16x8 agA[4][2];
#pragma unroll
    for (int i = 0; i < 4; i++) {
        int a = i * 16 + fr;
#pragma unroll
        for (int kk = 0; kk < 2; kk++) {
            union { bf16x8 v; unsigned short u[8]; } cv;
#pragma unroll
            for (int e = 0; e < 8; e++) cv.u[e] = 0;
            if (a < AGENT_NUM) {
                const float* ap = agent + ((long)b * AGENT_NUM + a) * 512 + h * 64 + fq * 8;
                float4 f0 = *(const float4*)(ap + kk * 32);
                float4 f1 = *(const float4*)(ap + kk * 32 + 4);
                cv.u[0] = f2bf(f0.x * SCALE); cv.u[1] = f2bf(f0.y * SCALE);
                cv.u[2] = f2bf(f0.z * SCALE); cv.u[3] = f2bf(f0.w * SCALE);
                cv.u[4] = f2bf(f1.x * SCALE); cv.u[5] = f2bf(f1.y * SCALE);
                cv.u[6] = f2bf(f1.z * SCALE); cv.u[7] = f2bf(f1.w * SCALE);
            }
            agA[i][kk] = cv.v;
        }
    }

    // Q B-frags: row (= output col) = query q0+jq*16+fr, k = d = kk*32+fq*8
    bf16x8 qB[4][2];
#pragma unroll
    for (int jq = 0; jq < 4; jq++) {
        const float* qp = q + ((long)b * N_TOK + q0 + jq * 16 + fr) * 512
                        + h * 64 + fq * 8;
#pragma unroll
        for (int kk = 0; kk < 2; kk++) {
            float4 f0 = *(const float4*)(qp + kk * 32);
            float4 f1 = *(const float4*)(qp + kk * 32 + 4);
            union { bf16x8 v; unsigned short u[8]; } cv;
            cv.u[0] = f2bf(f0.x); cv.u[1] = f2bf(f0.y);
            cv.u[2] = f2bf(f0.z); cv.u[3] = f2bf(f0.w);
            cv.u[4] = f2bf(f1.x); cv.u[5] = f2bf(f1.y);
            cv.u[6] = f2bf(f1.z); cv.u[7] = f2bf(f1.w);
            qB[jq][kk] = cv.v;
        }
    }

    // S^T MFMAs: sacc[i][jq], rows = agents i*16+fq*4+r, col = query jq*16+fr
    f32x4 sacc[4][4];
#pragma unroll
    for (int i = 0; i < 4; i++)
#pragma unroll
        for (int jq = 0; jq < 4; jq++) {
            f32x4 z = {0.f, 0.f, 0.f, 0.f};
            sacc[i][jq] = z;
        }
#pragma unroll
    for (int i = 0; i < 4; i++)
#pragma unroll
        for (int jq = 0; jq < 4; jq++) {
            sacc[i][jq] = __builtin_amdgcn_mfma_f32_16x16x32_bf16(
                agA[i][0], qB[jq][0], sacc[i][jq], 0, 0, 0);
            sacc[i][jq] = __builtin_amdgcn_mfma_f32_16x16x32_bf16(
                agA[i][1], qB[jq][1], sacc[i][jq], 0, 0, 0);
        }

    // mask padded agents (a = 48 + fq*4 + r >= 49 <=> fq*4+r >= 1)
#pragma unroll
    for (int jq = 0; jq < 4; jq++)
#pragma unroll
        for (int r = 0; r < 4; r++)
            if ((fq << 2) + r > 0) sacc[3][jq][r] = -1e30f;

    // exact softmax per query (values spread over i,r regs + fq lane groups)
#pragma unroll
    for (int jq = 0; jq < 4; jq++) {
        float mx = -1e30f;
#pragma unroll
        for (int i = 0; i < 4; i++)
#pragma unroll
            for (int r = 0; r < 4; r++) mx = fmaxf(mx, sacc[i][jq][r]);
        mx = fmaxf(mx, __shfl_xor(mx, 16));
        mx = fmaxf(mx, __shfl_xor(mx, 32));
        float ss = 0.f;
#pragma unroll
        for (int i = 0; i < 4; i++)
#pragma unroll
            for (int r = 0; r < 4; r++) {
                float pv = __expf(sacc[i][jq][r] - mx);
                sacc[i][jq][r] = pv;
                ss += pv;
            }
        ss += __shfl_xor(ss, 16);
        ss += __shfl_xor(ss, 32);
        float inv = 1.f / ss;
#pragma unroll
        for (int i = 0; i < 4; i++)
#pragma unroll
            for (int r = 0; r < 4; r++) sacc[i][jq][r] *= inv;
    }

    // write P[query][agent] bf16 to swizzled LDS (pairs of consecutive agents)
#pragma unroll
    for (int jq = 0; jq < 4; jq++) {
        char* prow = (char*)Psm + (jq * 16 + fr) * 128;
#pragma unroll
        for (int i = 0; i < 4; i++)
#pragma unroll
            for (int pr = 0; pr < 2; pr++) {
                unsigned int u = (unsigned int)f2bf(sacc[i][jq][pr * 2])
                               | ((unsigned int)f2bf(sacc[i][jq][pr * 2 + 1]) << 16);
                *(unsigned int*)(prow
                    + (((i * 2 + (fq >> 1)) ^ (fr & 7)) * 16)
                    + (fq & 1) * 8 + pr * 4) = u;
            }
    }

    // O = P·AV ; swizzled read chunks kk*4+fq ^ (fr&7); AV B-frags from AVsm
    const int cs0 = ((fq)     ^ (fr & 7)) * 16;
    const int cs1 = ((4 + fq) ^ (fr & 7)) * 16;
#pragma unroll
    for (int iq = 0; iq < 4; iq++) {
        char* prow = (char*)Psm + (iq * 16 + fr) * 128;
        bf16x8 pf0 = *(const bf16x8*)(prow + cs0);
        bf16x8 pf1 = *(const bf16x8*)(prow + cs1);
        float* orow = q + ((long)b * N_TOK + q0 + iq * 16 + fq * 4) * 512 + h * 64;
#pragma unroll
        for (int jd = 0; jd < 4; jd++) {
            bf16x8 vf0 = *(const bf16x8*)((char*)AVsm + (jd * 16 + fr) * 128 + cs0);
            bf16x8 vf1 = *(const bf16x8*)((char*)AVsm + (jd * 16 + fr) * 128 + cs1);
            f32x4 o = {0.f, 0.f, 0.f, 0.f};
            o = __builtin_amdgcn_mfma_f32_16x16x32_bf16(pf0, vf0, o, 0, 0, 0);
            o = __builtin_amdgcn_mfma_f32_16x16x32_bf16(pf1, vf1, o, 0, 0, 0);
#pragma unroll
            for (int r = 0; r < 4; r++)
                orow[(long)r * 512 + jd * 16 + fr] = o[r];
        }
    }
}

// ---------------------------------------------------------------------------
// Fused: depthwise 3x3 conv on v (bf16) + bias + attn(d_out fp32) add,
// RNE-cast to bf16 proj input. One thread = 8 contiguous channels.
// ---------------------------------------------------------------------------
__global__ __launch_bounds__(256) void dwc_fuse(
    const unsigned short* __restrict__ vO, const float* __restrict__ w,
    const float* __restrict__ bias, const float* __restrict__ attn,
    unsigned short* __restrict__ outb)
{
    __shared__ float ws2[64 * 73];
    for (int i = threadIdx.x; i < 512 * 9; i += 256) {
        int c = i / 9, k = i - c * 9;
        ws2[(c >> 3) * 73 + k * 8 + (c & 7)] = w[i];
    }
    __syncthreads();

    long flat = (long)blockIdx.x * 256 + threadIdx.x;  // over M_ROWS*64
    int cg = (int)(flat & 63);
    int c8 = cg << 3;
    long row = flat >> 6;                              // b*N_TOK + n
    int n = (int)(row % N_TOK);
    int b = (int)(row / N_TOK);
    int y = n / H_IMG, x = n - y * H_IMG;

    const unsigned short* vb = vO + (long)b * N_TOK * 512 + c8;
    const float* wb = ws2 + cg * 73;

    float acc[8];
    float4 bv0 = *(const float4*)(bias + c8);
    float4 bv1 = *(const float4*)(bias + c8 + 4);
    acc[0] = bv0.x; acc[1] = bv0.y; acc[2] = bv0.z; acc[3] = bv0.w;
    acc[4] = bv1.x; acc[5] = bv1.y; acc[6] = bv1.z; acc[7] = bv1.w;

#pragma unroll
    for (int dy = 0; dy < 3; dy++) {
        int yy = y + dy - 1;
        if (yy < 0 || yy >= H_IMG) continue;
#pragma unroll
        for (int dx = 0; dx < 3; dx++) {
            int xx = x + dx - 1;
            if (xx < 0 || xx >= H_IMG) continue;
            const unsigned short* vp = vb + (long)(yy * H_IMG + xx) * 512;
            ushort4 u0 = *(const ushort4*)(vp);
            ushort4 u1 = *(const ushort4*)(vp + 4);
            const float* wk = wb + (dy * 3 + dx) * 8;
            acc[0] += wk[0] * bf2f(u0.x);
            acc[1] += wk[1] * bf2f(u0.y);
            acc[2] += wk[2] * bf2f(u0.z);
            acc[3] += wk[3] * bf2f(u0.w);
            acc[4] += wk[4] * bf2f(u1.x);
            acc[5] += wk[5] * bf2f(u1.y);
            acc[6] += wk[6] * bf2f(u1.z);
            acc[7] += wk[7] * bf2f(u1.w);
        }
    }

    const float* ap = attn + row * 512 + c8;
    float4 a0 = *(const float4*)(ap);
    float4 a1 = *(const float4*)(ap + 4);
    ushort4 o0, o1;
    o0.x = f2bf(a0.x + acc[0]); o0.y = f2bf(a0.y + acc[1]);
    o0.z = f2bf(a0.z + acc[2]); o0.w = f2bf(a0.w + acc[3]);
    o1.x = f2bf(a1.x + acc[4]); o1.y = f2bf(a1.y + acc[5]);
    o1.z = f2bf(a1.z + acc[6]); o1.w = f2bf(a1.w + acc[7]);

    unsigned short* op = outb + row * 512 + c8;
    *(ushort4*)(op)     = o0;
    *(ushort4*)(op + 4) = o1;
}

// ---------------------------------------------------------------------------
extern "C" void kernel_launch(void* const* d_in, const int* in_sizes, int n_in,
                              void* d_out, int out_size, void* d_ws, size_t ws_size,
                              hipStream_t stream)
{
    const float* x      = (const float*)d_in[0];
    const float* qkv_w  = (const float*)d_in[1];
    const float* proj_w = (const float*)d_in[2];
    const float* proj_b = (const float*)d_in[3];
    const float* dwc_w  = (const float*)d_in[4];
    const float* dwc_b  = (const float*)d_in[5];
    float* out = (float*)d_out;

    const long KV_ELEMS    = (long)M_ROWS * 512;                  // 51,380,224
    const long QKVW_ELEMS  = 1536L * 512;                         // 786,432
    const long PROJW_ELEMS = 512L * 512;                          // 262,144
    const long AGENT_ELEMS = (long)B_SZ * AGENT_NUM * 512;
    const long AV_ELEMS    = (long)B_SZ * 8 * AGENT_NUM * 64;
    const long MACC_ELEMS  = (long)B_SZ * 8 * N_SPLIT * AGENT_NUM * 64;
    const long ML_ELEMS    = (long)B_SZ * 8 * N_SPLIT * AGENT_NUM;

    unsigned short* kbuf    = (unsigned short*)d_ws;   // reused as proj-A later
    unsigned short* vbuf    = kbuf + KV_ELEMS;
    unsigned short* qkv_wb  = vbuf + KV_ELEMS;
    unsigned short* proj_wb = qkv_wb + QKVW_ELEMS;
    float* agent   = (float*)(proj_wb + PROJW_ELEMS);
    float* agent_v = agent + AGENT_ELEMS;
    float* macc    = agent_v + AV_ELEMS;
    float* mpart   = macc + MACC_ELEMS;
    float* lpart   = mpart + ML_ELEMS;
    unsigned short* xb = (unsigned short*)(lpart + ML_ELEMS);   // bf16 copy of x

    size_t need_old = (size_t)(2 * KV_ELEMS + QKVW_ELEMS + PROJW_ELEMS) * 2
                    + (size_t)(AGENT_ELEMS + AV_ELEMS + MACC_ELEMS + 2 * ML_ELEMS) * 4;
    size_t need_new = need_old + (size_t)KV_ELEMS * 2;
    if (ws_size < need_old) return;
    const bool precast = (ws_size >= need_new);

    // 0. cast weights to bf16
    cast_f32_bf16<<<(unsigned)(QKVW_ELEMS / 1024), 256, 0, stream>>>(qkv_w, qkv_wb);
    cast_f32_bf16<<<(unsigned)(PROJW_ELEMS / 1024), 256, 0, stream>>>(proj_w, proj_wb);

    // 1. qkv GEMM: q -> d_out (fp32), k,v -> ws (bf16)
    if (precast) {
        cast_f32_bf16<<<(unsigned)(KV_ELEMS / 1024), 256, 0, stream>>>(x, xb);
        mfma_qkv_bf<<<(M_ROWS / 128) * 12, 256, 0, stream>>>(
            xb, qkv_wb, out, kbuf, vbuf);
    } else {
        mfma_qkv<<<dim3(M_ROWS / 128, 12), 256, 0, stream>>>(
            x, qkv_wb, out, kbuf, vbuf);
    }

    // 2. agent = 7x7 pool of q
    pool_q<<<B_SZ * AGENT_NUM * 2, 256, 0, stream>>>(out, agent);

    // 3. agent attention (MFMA split + combine) -> agent_v
    agent_attn_mfma<<<B_SZ * 8 * N_SPLIT, 256, 0, stream>>>(
        kbuf, vbuf, agent, macc, mpart, lpart);
    agent_attn_combine<<<B_SZ * 8, 256, 0, stream>>>(macc, mpart, lpart, agent_v);

    // 4. q attention via MFMA, in-place on d_out (1 wave = 64 queries)
    q_attn_mfma<<<B_SZ * 8 * 49, 64, 0, stream>>>(out, agent, agent_v);

    // 5. fused dwc + attn-add + bf16 cast -> kbuf (k dead now)
    dwc_fuse<<<(unsigned)((long)M_ROWS * 64 / 256), 256, 0, stream>>>(
        vbuf, dwc_w, dwc_b, out, kbuf);

    // 6. final projection (bf16 MFMA, fp32 epilogue + bias)
    mfma_proj<<<(M_ROWS / 128) * 4, 256, 0, stream>>>(kbuf, proj_wb, proj_b, out);
}